// Round 5
// baseline (3586.449 us; speedup 1.0000x reference)
//
#include <hip/hip_runtime.h>

typedef unsigned short dg35_u16;
typedef unsigned int   dg35_u32;

constexpr int dgN  = 50000;
constexpr int dgE  = 400000;
constexpr int dgG  = 1024;
constexpr int dgC  = 128;
constexpr int dgC2 = 256;

__device__ __forceinline__ float dg35_bf2f(dg35_u16 u){
  return __uint_as_float(((dg35_u32)u) << 16);
}
__device__ __forceinline__ dg35_u16 dg35_f2bf(float f){
  dg35_u32 u = __float_as_uint(f);
  u += 0x7FFFu + ((u >> 16) & 1u);
  return (dg35_u16)(u >> 16);
}
// dual-precision big-buffer accessors: af=1 -> float, af=0 -> bf16(u16)
__device__ __forceinline__ float dg35_ldx(const void* p, size_t i, int af){
  return af ? ((const float*)p)[i] : dg35_bf2f(((const dg35_u16*)p)[i]);
}
__device__ __forceinline__ void dg35_stx(void* p, size_t i, int af, float v){
  if (af) ((float*)p)[i] = v; else ((dg35_u16*)p)[i] = dg35_f2bf(v);
}

// Symbol from the harness template; kept but never launched.
__global__ void DeeperGCN_35820027248884_kernel(){}

// ---------------- CSR build ----------------
__global__ void dg35_count(const int* __restrict__ dst, int* __restrict__ deg, int e){
  int j = blockIdx.x*256 + threadIdx.x;
  if (j < e) atomicAdd(&deg[dst[j]], 1);
}

__global__ void dg35_scan(const int* __restrict__ deg, int* __restrict__ off,
                          int* __restrict__ cur, int n){
  __shared__ int sm[1024];
  int tid = threadIdx.x;
  int per = (n + 1023) >> 10;
  int s0 = tid * per; if (s0 > n) s0 = n;
  int s1 = s0 + per;  if (s1 > n) s1 = n;
  int loc = 0;
  for (int i = s0; i < s1; ++i) loc += deg[i];
  sm[tid] = loc;
  __syncthreads();
  for (int s = 1; s < 1024; s <<= 1){
    int t = (tid >= s) ? sm[tid - s] : 0;
    __syncthreads();
    sm[tid] += t;
    __syncthreads();
  }
  int run = sm[tid] - loc;
  for (int i = s0; i < s1; ++i){
    off[i] = run; cur[i] = run; run += deg[i];
  }
  if (tid == 1023) off[n] = run;
}

__global__ void dg35_scatter(const int* __restrict__ ei, const int* __restrict__ ea,
                             int* __restrict__ cur, dg35_u32* __restrict__ packed, int e){
  int j = blockIdx.x*256 + threadIdx.x;
  if (j >= e) return;
  int s = ei[j], d = ei[e + j];
  dg35_u32 a0 = (dg35_u32)ea[3*j], a1 = (dg35_u32)ea[3*j+1], a2 = (dg35_u32)ea[3*j+2];
  int pos = atomicAdd(&cur[d], 1);
  packed[pos] = (dg35_u32)s | (a0<<17) | (a1<<20) | (a2<<23);
}

__global__ void dg35_gstart(const int* __restrict__ batch, int* __restrict__ gs, int n, int g){
  int i = blockIdx.x*256 + threadIdx.x;
  if (i > g) return;
  if (i == g){ gs[i] = n; return; }
  int lo = 0, hi = n;
  while (lo < hi){ int mid = (lo+hi)>>1; if (batch[mid] < i) lo = mid+1; else hi = mid; }
  gs[i] = lo;
}

// ---------------- encoders ----------------
__global__ __launch_bounds__(128)
void dg35_atom(const int* __restrict__ x, const float* __restrict__ aemb,
               const float* __restrict__ vne, void* __restrict__ h, int af){
  int i = blockIdx.x, c = threadIdx.x;
  float acc = vne[c];
  #pragma unroll
  for (int f = 0; f < 9; ++f){
    int idx = x[i*9 + f];
    acc += aemb[(f*128 + idx)*dgC + c];
  }
  dg35_stx(h, (size_t)i*dgC + c, af, acc);
}

__global__ void dg35_vninit(const float* __restrict__ vne, float* __restrict__ vn){
  int i = blockIdx.x*256 + threadIdx.x;
  if (i < dgG*dgC) vn[i] = vne[i & (dgC-1)];
}

__global__ void dg35_zero(float* a, float* b, float* c_, float* d){
  int t = threadIdx.x;
  if (t < 512) a[t] = 0.f;
  if (t < 256){ b[t]=0.f; c_[t]=0.f; d[t]=0.f; }
}

// ------------- GENConv softmax aggregation (exact 2-pass over CSR) -------------
__global__ __launch_bounds__(128)
void dg35_gb(const void* __restrict__ hin, const dg35_u32* __restrict__ packed,
             const int* __restrict__ off, const float* __restrict__ bemb,
             void* __restrict__ hh, int af){
  int i = blockIdx.x, c = threadIdx.x;
  int b0 = off[i], b1 = off[i+1];
  float m = -3.0e38f;
  for (int p = b0; p < b1; ++p){
    dg35_u32 pk = packed[p];
    int src = (int)(pk & 0x1FFFFu);
    float e = bemb[((pk>>17)&7)*dgC + c] + bemb[(8+((pk>>20)&7))*dgC + c]
            + bemb[(16+((pk>>23)&7))*dgC + c];
    float msg = fmaxf(dg35_ldx(hin, (size_t)src*dgC + c, af) + e, 0.f) + 1e-7f;
    m = fmaxf(m, msg);
  }
  float s = 0.f, w = 0.f;
  for (int p = b0; p < b1; ++p){
    dg35_u32 pk = packed[p];
    int src = (int)(pk & 0x1FFFFu);
    float e = bemb[((pk>>17)&7)*dgC + c] + bemb[(8+((pk>>20)&7))*dgC + c]
            + bemb[(16+((pk>>23)&7))*dgC + c];
    float msg = fmaxf(dg35_ldx(hin, (size_t)src*dgC + c, af) + e, 0.f) + 1e-7f;
    float ez = expf(msg - m);
    s += ez;
    w += msg * ez;
  }
  float agg = (b1 > b0) ? (w / (s + 1e-16f)) : 0.f;
  float self = dg35_ldx(hin, (size_t)i*dgC + c, af);
  dg35_stx(hh, (size_t)i*dgC + c, af, self + agg);
}

// -------- GEMM: Cout = act(A) @ W + bias (+res); A/res/Cout dual-precision --------
__global__ __launch_bounds__(256)
void dg35_gemm_h(const void* __restrict__ A, const float* __restrict__ W,
                 const float* __restrict__ bias, const float* __restrict__ ab,
                 const void* __restrict__ res, void* __restrict__ Cout,
                 int M, int K, int NC, int trans, int addres, int af){
  __shared__ float At[32][65];
  __shared__ float Bt[32][64];
  int bm = blockIdx.x * 64;
  int bn = blockIdx.y * 64;
  int tid = threadIdx.x;
  int tx = tid & 15, ty = tid >> 4;
  float acc[4][4];
  #pragma unroll
  for (int i2 = 0; i2 < 4; ++i2)
    #pragma unroll
    for (int j2 = 0; j2 < 4; ++j2) acc[i2][j2] = 0.f;

  for (int k0 = 0; k0 < K; k0 += 32){
    int r = tid >> 3;
    int kq = (tid & 7) * 4;
    #pragma unroll
    for (int half = 0; half < 2; ++half){
      int rr = r + half*32;
      int grow = bm + rr;
      float vv[4] = {0.f, 0.f, 0.f, 0.f};
      if (grow < M){
        if (af){
          float4 v4 = *reinterpret_cast<const float4*>((const float*)A + (size_t)grow*K + k0 + kq);
          vv[0] = v4.x; vv[1] = v4.y; vv[2] = v4.z; vv[3] = v4.w;
        } else {
          ushort4 v4 = *reinterpret_cast<const ushort4*>((const dg35_u16*)A + (size_t)grow*K + k0 + kq);
          vv[0] = dg35_bf2f(v4.x); vv[1] = dg35_bf2f(v4.y);
          vv[2] = dg35_bf2f(v4.z); vv[3] = dg35_bf2f(v4.w);
        }
      }
      #pragma unroll
      for (int i2 = 0; i2 < 4; ++i2){
        float xv = vv[i2];
        if (trans){
          int kk = k0 + kq + i2;
          xv = fmaxf(xv*ab[kk] + ab[K + kk], 0.f);
        }
        At[kq + i2][rr] = xv;
      }
    }
    {
      int kr = tid >> 3;
      int cq = (tid & 7) * 8;
      const float* wp = W + (size_t)(k0 + kr)*NC + bn + cq;
      #pragma unroll
      for (int i2 = 0; i2 < 8; ++i2) Bt[kr][cq + i2] = wp[i2];
    }
    __syncthreads();
    #pragma unroll
    for (int kk = 0; kk < 32; ++kk){
      float a4[4], b4[4];
      #pragma unroll
      for (int i2 = 0; i2 < 4; ++i2) a4[i2] = At[kk][ty*4 + i2];
      #pragma unroll
      for (int j2 = 0; j2 < 4; ++j2) b4[j2] = Bt[kk][tx*4 + j2];
      #pragma unroll
      for (int i2 = 0; i2 < 4; ++i2)
        #pragma unroll
        for (int j2 = 0; j2 < 4; ++j2)
          acc[i2][j2] += a4[i2]*b4[j2];
    }
    __syncthreads();
  }
  #pragma unroll
  for (int i2 = 0; i2 < 4; ++i2){
    int rr = bm + ty*4 + i2;
    if (rr >= M) continue;
    #pragma unroll
    for (int j2 = 0; j2 < 4; ++j2){
      int cc = bn + tx*4 + j2;
      float v = acc[i2][j2] + bias[cc];
      size_t idx = (size_t)rr*NC + cc;
      if (addres) v += dg35_ldx(res, idx, af);
      dg35_stx(Cout, idx, af, v);
    }
  }
}

// -------- GEMM, A f32 [M,K], W f32, f32 out (virtual-node MLP, M=1024) --------
__global__ __launch_bounds__(256)
void dg35_gemm_v(const float* __restrict__ A, const float* __restrict__ W,
                 const float* __restrict__ bias, const float* __restrict__ ab,
                 float* __restrict__ Cout, int M, int K, int NC, int trans){
  __shared__ float At[32][65];
  __shared__ float Bt[32][64];
  int bm = blockIdx.x * 64;
  int bn = blockIdx.y * 64;
  int tid = threadIdx.x;
  int tx = tid & 15, ty = tid >> 4;
  float acc[4][4];
  #pragma unroll
  for (int i2 = 0; i2 < 4; ++i2)
    #pragma unroll
    for (int j2 = 0; j2 < 4; ++j2) acc[i2][j2] = 0.f;

  for (int k0 = 0; k0 < K; k0 += 32){
    int r = tid >> 3;
    int kq = (tid & 7) * 4;
    #pragma unroll
    for (int half = 0; half < 2; ++half){
      int rr = r + half*32;
      int grow = bm + rr;
      float vv[4] = {0.f, 0.f, 0.f, 0.f};
      if (grow < M){
        float4 v4 = *reinterpret_cast<const float4*>(A + (size_t)grow*K + k0 + kq);
        vv[0] = v4.x; vv[1] = v4.y; vv[2] = v4.z; vv[3] = v4.w;
      }
      #pragma unroll
      for (int i2 = 0; i2 < 4; ++i2){
        float xv = vv[i2];
        if (trans){
          int kk = k0 + kq + i2;
          xv = fmaxf(xv*ab[kk] + ab[K + kk], 0.f);
        }
        At[kq + i2][rr] = xv;
      }
    }
    {
      int kr = tid >> 3;
      int cq = (tid & 7) * 8;
      const float* wp = W + (size_t)(k0 + kr)*NC + bn + cq;
      #pragma unroll
      for (int i2 = 0; i2 < 8; ++i2) Bt[kr][cq + i2] = wp[i2];
    }
    __syncthreads();
    #pragma unroll
    for (int kk = 0; kk < 32; ++kk){
      float a4[4], b4[4];
      #pragma unroll
      for (int i2 = 0; i2 < 4; ++i2) a4[i2] = At[kk][ty*4 + i2];
      #pragma unroll
      for (int j2 = 0; j2 < 4; ++j2) b4[j2] = Bt[kk][tx*4 + j2];
      #pragma unroll
      for (int i2 = 0; i2 < 4; ++i2)
        #pragma unroll
        for (int j2 = 0; j2 < 4; ++j2)
          acc[i2][j2] += a4[i2]*b4[j2];
    }
    __syncthreads();
  }
  #pragma unroll
  for (int i2 = 0; i2 < 4; ++i2){
    int rr = bm + ty*4 + i2;
    if (rr >= M) continue;
    #pragma unroll
    for (int j2 = 0; j2 < 4; ++j2){
      int cc = bn + tx*4 + j2;
      Cout[(size_t)rr*NC + cc] = acc[i2][j2] + bias[cc];
    }
  }
}

// ---------------- BN statistics ----------------
__global__ void dg35_colstats(const void* __restrict__ Z, float* __restrict__ st,
                              int n, int ncols, int af){
  int tid = threadIdx.x;
  int c = tid & (ncols - 1);
  int rl = tid / ncols;
  int rpb = 256 / ncols;
  float s = 0.f, q = 0.f;
  for (int rr = blockIdx.x*rpb + rl; rr < n; rr += gridDim.x*rpb){
    float v = dg35_ldx(Z, (size_t)rr*ncols + c, af);
    s += v; q += v*v;
  }
  atomicAdd(&st[c], s);
  atomicAdd(&st[ncols + c], q);
}

__global__ void dg35_fin(const float* __restrict__ st, const float* __restrict__ g,
                         const float* __restrict__ b, float* __restrict__ ab,
                         float inv_n, int ncols){
  int c = threadIdx.x + blockIdx.x*256;
  if (c >= ncols) return;
  float m = st[c]*inv_n;
  float var = st[ncols + c]*inv_n - m*m;
  float rstd = rsqrtf(var + 1e-5f);
  float a = g[c]*rstd;
  ab[c] = a;
  ab[ncols + c] = b[c] - m*a;
}

// ---------------- elementwise / segment ops ----------------
__global__ void dg35_h2(const void* __restrict__ h, const float* __restrict__ ab,
                        void* __restrict__ h2, int af){
  int i = blockIdx.x*256 + threadIdx.x;
  int c = i & (dgC-1);
  dg35_stx(h2, i, af, fmaxf(dg35_ldx(h, i, af)*ab[c] + ab[dgC + c], 0.f));
}

__global__ __launch_bounds__(128)
void dg35_vt(const void* __restrict__ h2, const float* __restrict__ vn,
             const int* __restrict__ gs, float* __restrict__ vt, int af){
  int g = blockIdx.x, c = threadIdx.x;
  float s = 0.f;
  int r0 = gs[g], r1 = gs[g+1];
  for (int rr = r0; rr < r1; ++rr) s += dg35_ldx(h2, (size_t)rr*dgC + c, af);
  vt[g*dgC + c] = s + vn[g*dgC + c];
}

__global__ void dg35_vnfin(const float* __restrict__ z2, const float* __restrict__ ab,
                           float* __restrict__ vn){
  int i = blockIdx.x*256 + threadIdx.x;
  int c = i & (dgC-1);
  vn[i] = fmaxf(z2[i]*ab[c] + ab[dgC + c], 0.f);
}

__global__ __launch_bounds__(128)
void dg35_addvn(void* __restrict__ h2, const float* __restrict__ vn,
                const int* __restrict__ batch, int af){
  int i = blockIdx.x, c = threadIdx.x;
  size_t idx = (size_t)i*dgC + c;
  dg35_stx(h2, idx, af, dg35_ldx(h2, idx, af) + vn[batch[i]*dgC + c]);
}

__global__ __launch_bounds__(128)
void dg35_out(const void* __restrict__ h, const float* __restrict__ ab,
              const int* __restrict__ gs, float* __restrict__ out, int af){
  int g = blockIdx.x, c = threadIdx.x;
  float a = ab[c], b = ab[dgC + c];
  float s = 0.f;
  int r0 = gs[g], r1 = gs[g+1];
  for (int rr = r0; rr < r1; ++rr) s += dg35_ldx(h, (size_t)rr*dgC + c, af)*a + b;
  out[g*dgC + c] = s;
}

static inline size_t dg35_al(size_t x){ return (x + 255) & ~(size_t)255; }

extern "C" void kernel_launch(void* const* d_in, const int* in_sizes, int n_in,
                              void* d_out, int out_size, void* d_ws, size_t ws_size,
                              hipStream_t stream)
{
  const int*   x     = (const int*)d_in[0];
  const int*   eattr = (const int*)d_in[1];
  const int*   eidx  = (const int*)d_in[2];
  const int*   batch = (const int*)d_in[3];
  const float* aemb  = (const float*)d_in[4];
  const float* bemb  = (const float*)d_in[5];
  const float* vne   = (const float*)d_in[6];
  const float* cW1   = (const float*)d_in[7];
  const float* cb1   = (const float*)d_in[8];
  const float* cg1   = (const float*)d_in[9];
  const float* cbb1  = (const float*)d_in[10];
  const float* cW2   = (const float*)d_in[11];
  const float* cb2   = (const float*)d_in[12];
  const float* ng    = (const float*)d_in[13];
  const float* nb    = (const float*)d_in[14];
  const float* vW1   = (const float*)d_in[15];
  const float* vb1   = (const float*)d_in[16];
  const float* vg1   = (const float*)d_in[17];
  const float* vbb1  = (const float*)d_in[18];
  const float* vW2   = (const float*)d_in[19];
  const float* vb2   = (const float*)d_in[20];
  const float* vg2   = (const float*)d_in[21];
  const float* vbb2  = (const float*)d_in[22];
  float* out = (float*)d_out;

  // Fixed-size (precision-independent) tail: vn..packed
  const size_t fixed =
      dg35_al(dgG*dgC*4)*4 +                 // vn, vt, zv1, zv2
      dg35_al(2*dgC2*4)*2 +                  // st1, ab1
      dg35_al(2*dgC*4)*6 +                   // stH,stV1,stV2,abh,abv1,abv2
      dg35_al(dgN*4)*2 + dg35_al((dgN+1)*4) +// deg, cur, off
      dg35_al((dgG+1)*4) +                   // gs
      dg35_al((size_t)dgE*4);                // packed
  // choose precision tier for the big node buffers
  int af = 0;
  size_t esz = 2;
  {
    size_t bigf = dg35_al((size_t)dgN*dgC*4)*2 + dg35_al((size_t)dgN*dgC2*4);
    if (bigf + fixed <= ws_size){ af = 1; esz = 4; }
  }

  char* base = (char*)d_ws;
  size_t o = 0;
  void* h  = (void*)(base + o); o += dg35_al((size_t)dgN*dgC*esz);
  void* hh = (void*)(base + o); o += dg35_al((size_t)dgN*dgC*esz);
  void* zb = (void*)(base + o); o += dg35_al((size_t)dgN*dgC2*esz);
  float* vn   = (float*)(base + o); o += dg35_al(dgG*dgC*4);
  float* vt   = (float*)(base + o); o += dg35_al(dgG*dgC*4);
  float* zv1  = (float*)(base + o); o += dg35_al(dgG*dgC*4);
  float* zv2  = (float*)(base + o); o += dg35_al(dgG*dgC*4);
  float* st1  = (float*)(base + o); o += dg35_al(2*dgC2*4);
  float* ab1  = (float*)(base + o); o += dg35_al(2*dgC2*4);
  float* stH  = (float*)(base + o); o += dg35_al(2*dgC*4);
  float* stV1 = (float*)(base + o); o += dg35_al(2*dgC*4);
  float* stV2 = (float*)(base + o); o += dg35_al(2*dgC*4);
  float* abh  = (float*)(base + o); o += dg35_al(2*dgC*4);
  float* abv1 = (float*)(base + o); o += dg35_al(2*dgC*4);
  float* abv2 = (float*)(base + o); o += dg35_al(2*dgC*4);
  int* deg = (int*)(base + o); o += dg35_al(dgN*4);
  int* cur = (int*)(base + o); o += dg35_al(dgN*4);
  int* off = (int*)(base + o); o += dg35_al((dgN+1)*4);
  int* gs  = (int*)(base + o); o += dg35_al((dgG+1)*4);
  dg35_u32* packed = (dg35_u32*)(base + o); o += dg35_al((size_t)dgE*4);

  if (o > ws_size){
    // even bf16 tier doesn't fit: 0x7F7F7F7F ~ 3.4e38 sentinel
    hipMemsetAsync(d_out, 0x7F, (size_t)out_size*4, stream);
    return;
  }
  void* h2 = zb;   // [N, C]  — dead before z is written (same tier, fits in zb)
  void* z  = zb;   // [N, 2C]

  // diagnostic: if this survives, pipeline died before dg35_out (0x7D ~ 2.1e37)
  hipMemsetAsync(d_out, 0x7D, (size_t)out_size*4, stream);

  // ---- per-call setup: CSR by dst, graph ranges, encoders ----
  hipMemsetAsync(deg, 0, sizeof(int)*dgN, stream);
  dg35_count  <<<(dgE+255)/256, 256, 0, stream>>>(eidx + dgE, deg, dgE);
  dg35_scan   <<<1, 1024, 0, stream>>>(deg, off, cur, dgN);
  dg35_scatter<<<(dgE+255)/256, 256, 0, stream>>>(eidx, eattr, cur, packed, dgE);
  dg35_gstart <<<(dgG+256)/256, 256, 0, stream>>>(batch, gs, dgN, dgG);
  dg35_atom   <<<dgN, dgC, 0, stream>>>(x, aemb, vne, h, af);
  dg35_vninit <<<(dgG*dgC)/256, 256, 0, stream>>>(vne, vn);

  const int gx = (dgN + 63) / 64;  // 782
  for (int l = 0; l < 7; ++l){
    dg35_zero<<<1, 512, 0, stream>>>(st1, stH, stV1, stV2);
    const void* hin = h;
    if (l > 0){
      // h2 = relu(BN(h))
      dg35_colstats<<<128, 256, 0, stream>>>(h, stH, dgN, dgC, af);
      dg35_fin<<<1, 256, 0, stream>>>(stH, ng + (l-1)*dgC, nb + (l-1)*dgC,
                                      abh, 1.f/dgN, dgC);
      dg35_h2<<<(dgN*dgC)/256, 256, 0, stream>>>(h, abh, h2, af);
      // virtual node MLP
      dg35_vt<<<dgG, dgC, 0, stream>>>(h2, vn, gs, vt, af);
      dg35_gemm_v<<<dim3(16,2), 256, 0, stream>>>(vt, vW1 + (l-1)*dgC*dgC,
                                                  vb1 + (l-1)*dgC, (const float*)0,
                                                  zv1, dgG, dgC, dgC, 0);
      dg35_colstats<<<64, 256, 0, stream>>>(zv1, stV1, dgG, dgC, 1);
      dg35_fin<<<1, 256, 0, stream>>>(stV1, vg1 + (l-1)*dgC, vbb1 + (l-1)*dgC,
                                      abv1, 1.f/dgG, dgC);
      dg35_gemm_v<<<dim3(16,2), 256, 0, stream>>>(zv1, vW2 + (l-1)*dgC*dgC,
                                                  vb2 + (l-1)*dgC, abv1,
                                                  zv2, dgG, dgC, dgC, 1);
      dg35_colstats<<<64, 256, 0, stream>>>(zv2, stV2, dgG, dgC, 1);
      dg35_fin<<<1, 256, 0, stream>>>(stV2, vg2 + (l-1)*dgC, vbb2 + (l-1)*dgC,
                                      abv2, 1.f/dgG, dgC);
      dg35_vnfin<<<(dgG*dgC)/256, 256, 0, stream>>>(zv2, abv2, vn);
      dg35_addvn<<<dgN, dgC, 0, stream>>>(h2, vn, batch, af);
      hin = h2;
    }
    // GENConv: softmax-aggr + MLP [C -> 2C -> BN -> ReLU -> C] (+ residual l>0)
    dg35_gb<<<dgN, dgC, 0, stream>>>(hin, packed, off, bemb, hh, af);
    dg35_gemm_h<<<dim3(gx,4), 256, 0, stream>>>(hh, cW1 + l*dgC*dgC2,
                                                cb1 + l*dgC2, (const float*)0,
                                                (const void*)0, z,
                                                dgN, dgC, dgC2, 0, 0, af);
    dg35_colstats<<<128, 256, 0, stream>>>(z, st1, dgN, dgC2, af);
    dg35_fin<<<1, 256, 0, stream>>>(st1, cg1 + l*dgC2, cbb1 + l*dgC2,
                                    ab1, 1.f/dgN, dgC2);
    dg35_gemm_h<<<dim3(gx,2), 256, 0, stream>>>(z, cW2 + l*dgC2*dgC,
                                                cb2 + l*dgC, ab1, h, h,
                                                dgN, dgC2, dgC, 1, (l==0)?0:1, af);
  }
  // final BN + global_add_pool
  hipMemsetAsync(stH, 0, sizeof(float)*2*dgC, stream);
  dg35_colstats<<<128, 256, 0, stream>>>(h, stH, dgN, dgC, af);
  dg35_fin<<<1, 256, 0, stream>>>(stH, ng + 6*dgC, nb + 6*dgC, abh, 1.f/dgN, dgC);
  dg35_out<<<dgG, dgC, 0, stream>>>(h, abh, gs, out, af);
}

// Round 8
// 3318.521 us; speedup vs baseline: 1.0807x; 1.0807x over previous
//
#include <hip/hip_runtime.h>

typedef unsigned short dg35_u16;
typedef unsigned int   dg35_u32;

constexpr int dgN  = 50000;
constexpr int dgE  = 400000;
constexpr int dgG  = 1024;
constexpr int dgC  = 128;
constexpr int dgC2 = 256;

typedef __attribute__((ext_vector_type(8))) short dg35_s8v;   // 8 bf16 (4 VGPR)
typedef __attribute__((ext_vector_type(4))) float dg35_f4v;   // MFMA acc

__device__ __forceinline__ float dg35_bf2f(dg35_u16 u){
  return __uint_as_float(((dg35_u32)u) << 16);
}
__device__ __forceinline__ dg35_u16 dg35_f2bf(float f){
  dg35_u32 u = __float_as_uint(f);
  u += 0x7FFFu + ((u >> 16) & 1u);
  return (dg35_u16)(u >> 16);
}
// dual-precision big-buffer accessors: af=1 -> float, af=0 -> bf16(u16)
__device__ __forceinline__ float dg35_ldx(const void* p, size_t i, int af){
  return af ? ((const float*)p)[i] : dg35_bf2f(((const dg35_u16*)p)[i]);
}
__device__ __forceinline__ void dg35_stx(void* p, size_t i, int af, float v){
  if (af) ((float*)p)[i] = v; else ((dg35_u16*)p)[i] = dg35_f2bf(v);
}

// Symbol from the harness template; kept but never launched.
__global__ void DeeperGCN_35820027248884_kernel(){}

// ---------------- CSR build ----------------
__global__ void dg35_count(const int* __restrict__ dst, int* __restrict__ deg, int e){
  int j = blockIdx.x*256 + threadIdx.x;
  if (j < e) atomicAdd(&deg[dst[j]], 1);
}

// hierarchical scan: s1 block sums -> s2 scan of partials -> s3 local scan + fixup
__global__ void dg35_s1(const int* __restrict__ deg, int* __restrict__ bsum, int n){
  __shared__ int sm[256];
  int t = threadIdx.x, b = blockIdx.x;
  int idx = b*256 + t;
  sm[t] = (idx < n) ? deg[idx] : 0;
  __syncthreads();
  for (int s = 128; s > 0; s >>= 1){
    if (t < s) sm[t] += sm[t+s];
    __syncthreads();
  }
  if (t == 0) bsum[b] = sm[0];
}

__global__ void dg35_s2(const int* __restrict__ bsum, int* __restrict__ boff, int nb){
  __shared__ int sm[256];
  int t = threadIdx.x;
  int v = (t < nb) ? bsum[t] : 0;
  sm[t] = v;
  __syncthreads();
  for (int s = 1; s < 256; s <<= 1){
    int u = (t >= s) ? sm[t-s] : 0;
    __syncthreads();
    sm[t] += u;
    __syncthreads();
  }
  if (t < nb) boff[t] = sm[t] - v;   // exclusive
}

__global__ void dg35_s3(const int* __restrict__ deg, const int* __restrict__ boff,
                        int* __restrict__ off, int* __restrict__ cur, int n){
  __shared__ int sm[256];
  int t = threadIdx.x, b = blockIdx.x;
  int idx = b*256 + t;
  int v = (idx < n) ? deg[idx] : 0;
  sm[t] = v;
  __syncthreads();
  for (int s = 1; s < 256; s <<= 1){
    int u = (t >= s) ? sm[t-s] : 0;
    __syncthreads();
    sm[t] += u;
    __syncthreads();
  }
  if (idx < n){
    int e = boff[b] + sm[t] - v;
    off[idx] = e; cur[idx] = e;
  }
  if (idx == 0) off[n] = dgE;
}

__global__ void dg35_scatter(const int* __restrict__ ei, const int* __restrict__ ea,
                             int* __restrict__ cur, dg35_u32* __restrict__ packed, int e){
  int j = blockIdx.x*256 + threadIdx.x;
  if (j >= e) return;
  int s = ei[j], d = ei[e + j];
  dg35_u32 a0 = (dg35_u32)ea[3*j], a1 = (dg35_u32)ea[3*j+1], a2 = (dg35_u32)ea[3*j+2];
  int pos = atomicAdd(&cur[d], 1);
  packed[pos] = (dg35_u32)s | (a0<<17) | (a1<<20) | (a2<<23);
}

__global__ void dg35_gstart(const int* __restrict__ batch, int* __restrict__ gs, int n, int g){
  int i = blockIdx.x*256 + threadIdx.x;
  if (i > g) return;
  if (i == g){ gs[i] = n; return; }
  int lo = 0, hi = n;
  while (lo < hi){ int mid = (lo+hi)>>1; if (batch[mid] < i) lo = mid+1; else hi = mid; }
  gs[i] = lo;
}

// ---------------- encoders / weight prep ----------------
__global__ __launch_bounds__(128)
void dg35_atom(const int* __restrict__ x, const float* __restrict__ aemb,
               const float* __restrict__ vne, void* __restrict__ h, int af){
  int i = blockIdx.x, c = threadIdx.x;
  float acc = vne[c];
  #pragma unroll
  for (int f = 0; f < 9; ++f){
    int idx = x[i*9 + f];
    acc += aemb[(f*128 + idx)*dgC + c];
  }
  dg35_stx(h, (size_t)i*dgC + c, af, acc);
}

__global__ void dg35_vninit(const float* __restrict__ vne, float* __restrict__ vn){
  int i = blockIdx.x*256 + threadIdx.x;
  if (i < dgG*dgC) vn[i] = vne[i & (dgC-1)];
}

// transpose+convert conv weights to SPLIT bf16 (hi+lo) in [l][n][k] layout
__global__ void dg35_wconv(const float* __restrict__ W1, const float* __restrict__ W2,
                           short* __restrict__ Wt1h, short* __restrict__ Wt1l,
                           short* __restrict__ Wt2h, short* __restrict__ Wt2l){
  int i = blockIdx.x*256 + threadIdx.x;
  constexpr int per = 7*256*128;  // 229376
  float w;
  short* ph; short* pl; int oidx;
  if (i < per){
    int l = i >> 15;
    int rem = i & 32767;
    int n = rem >> 7;          // 0..255
    int k = rem & 127;         // 0..127
    w = W1[l*32768 + k*256 + n];   // W1[l][k=128][n=256]
    ph = Wt1h; pl = Wt1l; oidx = i;
  } else {
    int j = i - per;
    int l = j >> 15;
    int rem = j & 32767;
    int n = rem >> 8;          // 0..127
    int k = rem & 255;         // 0..255
    w = W2[l*32768 + k*128 + n];   // W2[l][k=256][n=128]
    ph = Wt2h; pl = Wt2l; oidx = j;
  }
  dg35_u16 hi = dg35_f2bf(w);
  float lo = w - dg35_bf2f(hi);
  ph[oidx] = (short)hi;
  pl[oidx] = (short)dg35_f2bf(lo);
}

__global__ void dg35_zero(float* a, float* b, float* c_, float* d){
  int t = threadIdx.x;
  if (t < 512) a[t] = 0.f;
  if (t < 256){ b[t]=0.f; c_[t]=0.f; d[t]=0.f; }
}

// ------------- GENConv softmax aggregation (online softmax, single pass) -------------
__global__ __launch_bounds__(128)
void dg35_gb(const void* __restrict__ hin, const dg35_u32* __restrict__ packed,
             const int* __restrict__ off, const float* __restrict__ bemb,
             void* __restrict__ hh, int af){
  int i = blockIdx.x, c = threadIdx.x;
  int b0 = off[i], b1 = off[i+1];
  float m = -3.0e38f, s = 0.f, w = 0.f;
  for (int p = b0; p < b1; ++p){
    dg35_u32 pk = packed[p];
    int src = (int)(pk & 0x1FFFFu);
    float e = bemb[((pk>>17)&7)*dgC + c] + bemb[(8+((pk>>20)&7))*dgC + c]
            + bemb[(16+((pk>>23)&7))*dgC + c];
    float msg = fmaxf(dg35_ldx(hin, (size_t)src*dgC + c, af) + e, 0.f) + 1e-7f;
    if (msg > m){
      float sc = expf(m - msg);
      s = s*sc + 1.f;
      w = w*sc + msg;
      m = msg;
    } else {
      float t2 = expf(msg - m);
      s += t2;
      w += msg*t2;
    }
  }
  float agg = (b1 > b0) ? (w / (s + 1e-16f)) : 0.f;
  float self = dg35_ldx(hin, (size_t)i*dgC + c, af);
  dg35_stx(hh, (size_t)i*dgC + c, af, self + agg);
}

// ---- split-bf16 MFMA GEMM: Cout(f32) = act(A f32) @ W(f32 via hi+lo bf16) + bias (+res)
// A = Ahi+Alo staged in XOR-swizzled LDS; product = Ahi*Bhi + Alo*Bhi + Ahi*Blo.
// 128x64 C-tile per block, 4 waves x (32x64), 16x16x32 bf16 MFMA, f32 accum.
__global__ __launch_bounds__(256)
void dg35_gemmx(const float* __restrict__ A, const short* __restrict__ Whi,
                const short* __restrict__ Wlo,
                const float* __restrict__ bias, const float* __restrict__ ab,
                const float* __restrict__ res, float* __restrict__ Cout,
                int M, int K, int NC, int trans, int addres){
  __shared__ short Ahi[128*64];   // 16 KB
  __shared__ short Alo[128*64];   // 16 KB
  int tid = threadIdx.x;
  int bm = blockIdx.x * 128;
  int bn = blockIdx.y * 64;
  int lane = tid & 63;
  int wv = tid >> 6;
  int l15 = lane & 15;
  int l4  = lane >> 4;
  dg35_f4v acc[2][4] = {};

  int r = tid >> 1;          // staging row 0..127
  int ch = tid & 1;          // col half (32 f32)
  int grow = bm + r;

  for (int k0 = 0; k0 < K; k0 += 64){
    // ---- stage A[bm..bm+128][k0..k0+64] as swizzled split-bf16 ----
    {
      float xv[32];
      if (grow < M){
        const float* ap = A + (size_t)grow*K + k0 + ch*32;
        #pragma unroll
        for (int q = 0; q < 8; ++q){
          float4 v = *reinterpret_cast<const float4*>(ap + q*4);
          xv[q*4+0]=v.x; xv[q*4+1]=v.y; xv[q*4+2]=v.z; xv[q*4+3]=v.w;
        }
      } else {
        #pragma unroll
        for (int q = 0; q < 32; ++q) xv[q] = 0.f;
      }
      if (trans){
        #pragma unroll
        for (int q = 0; q < 32; ++q){
          int kk = k0 + ch*32 + q;
          xv[q] = fmaxf(xv[q]*ab[kk] + ab[K + kk], 0.f);
        }
      }
      #pragma unroll
      for (int g = 0; g < 4; ++g){
        uint4 wh, wl;
        unsigned* hp = (unsigned*)&wh;
        unsigned* lp = (unsigned*)&wl;
        #pragma unroll
        for (int d = 0; d < 4; ++d){
          float f0 = xv[g*8 + d*2], f1 = xv[g*8 + d*2 + 1];
          dg35_u16 h0 = dg35_f2bf(f0), h1 = dg35_f2bf(f1);
          dg35_u16 l0 = dg35_f2bf(f0 - dg35_bf2f(h0));
          dg35_u16 l1 = dg35_f2bf(f1 - dg35_bf2f(h1));
          hp[d] = (dg35_u32)h0 | ((dg35_u32)h1 << 16);
          lp[d] = (dg35_u32)l0 | ((dg35_u32)l1 << 16);
        }
        int slot = (ch*4 + g) ^ (r & 7);
        *reinterpret_cast<uint4*>(&Ahi[r*64 + slot*8]) = wh;
        *reinterpret_cast<uint4*>(&Alo[r*64 + slot*8]) = wl;
      }
    }
    __syncthreads();
    // ---- 2 K-steps of 32 ----
    #pragma unroll
    for (int ks = 0; ks < 2; ++ks){
      dg35_s8v bh[4], bl[4];
      #pragma unroll
      for (int nf = 0; nf < 4; ++nf){
        int n = bn + nf*16 + l15;
        size_t wo = (size_t)n*K + k0 + ks*32 + l4*8;
        bh[nf] = *reinterpret_cast<const dg35_s8v*>(Whi + wo);
        bl[nf] = *reinterpret_cast<const dg35_s8v*>(Wlo + wo);
      }
      #pragma unroll
      for (int mf = 0; mf < 2; ++mf){
        int row = wv*32 + mf*16 + l15;
        int slot = (ks*4 + l4) ^ (row & 7);
        dg35_s8v ah = *reinterpret_cast<const dg35_s8v*>(&Ahi[row*64 + slot*8]);
        dg35_s8v al = *reinterpret_cast<const dg35_s8v*>(&Alo[row*64 + slot*8]);
        #pragma unroll
        for (int nf = 0; nf < 4; ++nf){
          acc[mf][nf] = __builtin_amdgcn_mfma_f32_16x16x32_bf16(ah, bh[nf], acc[mf][nf], 0, 0, 0);
          acc[mf][nf] = __builtin_amdgcn_mfma_f32_16x16x32_bf16(al, bh[nf], acc[mf][nf], 0, 0, 0);
          acc[mf][nf] = __builtin_amdgcn_mfma_f32_16x16x32_bf16(ah, bl[nf], acc[mf][nf], 0, 0, 0);
        }
      }
    }
    __syncthreads();
  }
  // ---- epilogue: C row=(l>>4)*4+e, col=l&15 (verified layout) ----
  #pragma unroll
  for (int mf = 0; mf < 2; ++mf){
    #pragma unroll
    for (int e = 0; e < 4; ++e){
      int rr = bm + wv*32 + mf*16 + l4*4 + e;
      if (rr >= M) continue;
      #pragma unroll
      for (int nf = 0; nf < 4; ++nf){
        int cc = bn + nf*16 + l15;
        float v = acc[mf][nf][e] + bias[cc];
        size_t idx = (size_t)rr*NC + cc;
        if (addres) v += res[idx];
        Cout[idx] = v;
      }
    }
  }
}

// -------- VALU GEMM (dual-precision) — tier-B fallback only --------
__global__ __launch_bounds__(256)
void dg35_gemm_h(const void* __restrict__ A, const float* __restrict__ W,
                 const float* __restrict__ bias, const float* __restrict__ ab,
                 const void* __restrict__ res, void* __restrict__ Cout,
                 int M, int K, int NC, int trans, int addres, int af){
  __shared__ float At[32][65];
  __shared__ float Bt[32][64];
  int bm = blockIdx.x * 64;
  int bn = blockIdx.y * 64;
  int tid = threadIdx.x;
  int tx = tid & 15, ty = tid >> 4;
  float acc[4][4];
  #pragma unroll
  for (int i2 = 0; i2 < 4; ++i2)
    #pragma unroll
    for (int j2 = 0; j2 < 4; ++j2) acc[i2][j2] = 0.f;

  for (int k0 = 0; k0 < K; k0 += 32){
    int r = tid >> 3;
    int kq = (tid & 7) * 4;
    #pragma unroll
    for (int half = 0; half < 2; ++half){
      int rr = r + half*32;
      int grow = bm + rr;
      float vv[4] = {0.f, 0.f, 0.f, 0.f};
      if (grow < M){
        if (af){
          float4 v4 = *reinterpret_cast<const float4*>((const float*)A + (size_t)grow*K + k0 + kq);
          vv[0] = v4.x; vv[1] = v4.y; vv[2] = v4.z; vv[3] = v4.w;
        } else {
          ushort4 v4 = *reinterpret_cast<const ushort4*>((const dg35_u16*)A + (size_t)grow*K + k0 + kq);
          vv[0] = dg35_bf2f(v4.x); vv[1] = dg35_bf2f(v4.y);
          vv[2] = dg35_bf2f(v4.z); vv[3] = dg35_bf2f(v4.w);
        }
      }
      #pragma unroll
      for (int i2 = 0; i2 < 4; ++i2){
        float xv = vv[i2];
        if (trans){
          int kk = k0 + kq + i2;
          xv = fmaxf(xv*ab[kk] + ab[K + kk], 0.f);
        }
        At[kq + i2][rr] = xv;
      }
    }
    {
      int kr = tid >> 3;
      int cq = (tid & 7) * 8;
      const float* wp = W + (size_t)(k0 + kr)*NC + bn + cq;
      #pragma unroll
      for (int i2 = 0; i2 < 8; ++i2) Bt[kr][cq + i2] = wp[i2];
    }
    __syncthreads();
    #pragma unroll
    for (int kk = 0; kk < 32; ++kk){
      float a4[4], b4[4];
      #pragma unroll
      for (int i2 = 0; i2 < 4; ++i2) a4[i2] = At[kk][ty*4 + i2];
      #pragma unroll
      for (int j2 = 0; j2 < 4; ++j2) b4[j2] = Bt[kk][tx*4 + j2];
      #pragma unroll
      for (int i2 = 0; i2 < 4; ++i2)
        #pragma unroll
        for (int j2 = 0; j2 < 4; ++j2)
          acc[i2][j2] += a4[i2]*b4[j2];
    }
    __syncthreads();
  }
  #pragma unroll
  for (int i2 = 0; i2 < 4; ++i2){
    int rr = bm + ty*4 + i2;
    if (rr >= M) continue;
    #pragma unroll
    for (int j2 = 0; j2 < 4; ++j2){
      int cc = bn + tx*4 + j2;
      float v = acc[i2][j2] + bias[cc];
      size_t idx = (size_t)rr*NC + cc;
      if (addres) v += dg35_ldx(res, idx, af);
      dg35_stx(Cout, idx, af, v);
    }
  }
}

// -------- GEMM, A f32, W f32, f32 out (virtual-node MLP, M=1024) --------
__global__ __launch_bounds__(256)
void dg35_gemm_v(const float* __restrict__ A, const float* __restrict__ W,
                 const float* __restrict__ bias, const float* __restrict__ ab,
                 float* __restrict__ Cout, int M, int K, int NC, int trans){
  __shared__ float At[32][65];
  __shared__ float Bt[32][64];
  int bm = blockIdx.x * 64;
  int bn = blockIdx.y * 64;
  int tid = threadIdx.x;
  int tx = tid & 15, ty = tid >> 4;
  float acc[4][4];
  #pragma unroll
  for (int i2 = 0; i2 < 4; ++i2)
    #pragma unroll
    for (int j2 = 0; j2 < 4; ++j2) acc[i2][j2] = 0.f;

  for (int k0 = 0; k0 < K; k0 += 32){
    int r = tid >> 3;
    int kq = (tid & 7) * 4;
    #pragma unroll
    for (int half = 0; half < 2; ++half){
      int rr = r + half*32;
      int grow = bm + rr;
      float vv[4] = {0.f, 0.f, 0.f, 0.f};
      if (grow < M){
        float4 v4 = *reinterpret_cast<const float4*>(A + (size_t)grow*K + k0 + kq);
        vv[0] = v4.x; vv[1] = v4.y; vv[2] = v4.z; vv[3] = v4.w;
      }
      #pragma unroll
      for (int i2 = 0; i2 < 4; ++i2){
        float xv = vv[i2];
        if (trans){
          int kk = k0 + kq + i2;
          xv = fmaxf(xv*ab[kk] + ab[K + kk], 0.f);
        }
        At[kq + i2][rr] = xv;
      }
    }
    {
      int kr = tid >> 3;
      int cq = (tid & 7) * 8;
      const float* wp = W + (size_t)(k0 + kr)*NC + bn + cq;
      #pragma unroll
      for (int i2 = 0; i2 < 8; ++i2) Bt[kr][cq + i2] = wp[i2];
    }
    __syncthreads();
    #pragma unroll
    for (int kk = 0; kk < 32; ++kk){
      float a4[4], b4[4];
      #pragma unroll
      for (int i2 = 0; i2 < 4; ++i2) a4[i2] = At[kk][ty*4 + i2];
      #pragma unroll
      for (int j2 = 0; j2 < 4; ++j2) b4[j2] = Bt[kk][tx*4 + j2];
      #pragma unroll
      for (int i2 = 0; i2 < 4; ++i2)
        #pragma unroll
        for (int j2 = 0; j2 < 4; ++j2)
          acc[i2][j2] += a4[i2]*b4[j2];
    }
    __syncthreads();
  }
  #pragma unroll
  for (int i2 = 0; i2 < 4; ++i2){
    int rr = bm + ty*4 + i2;
    if (rr >= M) continue;
    #pragma unroll
    for (int j2 = 0; j2 < 4; ++j2){
      int cc = bn + tx*4 + j2;
      Cout[(size_t)rr*NC + cc] = acc[i2][j2] + bias[cc];
    }
  }
}

// ---------------- BN statistics ----------------
__global__ void dg35_colstats(const void* __restrict__ Z, float* __restrict__ st,
                              int n, int ncols, int af){
  int tid = threadIdx.x;
  int c = tid & (ncols - 1);
  int rl = tid / ncols;
  int rpb = 256 / ncols;
  float s = 0.f, q = 0.f;
  for (int rr = blockIdx.x*rpb + rl; rr < n; rr += gridDim.x*rpb){
    float v = dg35_ldx(Z, (size_t)rr*ncols + c, af);
    s += v; q += v*v;
  }
  atomicAdd(&st[c], s);
  atomicAdd(&st[ncols + c], q);
}

__global__ void dg35_fin(const float* __restrict__ st, const float* __restrict__ g,
                         const float* __restrict__ b, float* __restrict__ ab,
                         float inv_n, int ncols){
  int c = threadIdx.x + blockIdx.x*256;
  if (c >= ncols) return;
  float m = st[c]*inv_n;
  float var = st[ncols + c]*inv_n - m*m;
  float rstd = rsqrtf(var + 1e-5f);
  float a = g[c]*rstd;
  ab[c] = a;
  ab[ncols + c] = b[c] - m*a;
}

// ---------------- elementwise / segment ops ----------------
__global__ void dg35_h2(const void* __restrict__ h, const float* __restrict__ ab,
                        void* __restrict__ h2, int af){
  int i = blockIdx.x*256 + threadIdx.x;
  int c = i & (dgC-1);
  dg35_stx(h2, i, af, fmaxf(dg35_ldx(h, i, af)*ab[c] + ab[dgC + c], 0.f));
}

__global__ __launch_bounds__(128)
void dg35_vt(const void* __restrict__ h2, const float* __restrict__ vn,
             const int* __restrict__ gs, float* __restrict__ vt, int af){
  int g = blockIdx.x, c = threadIdx.x;
  float s = 0.f;
  int r0 = gs[g], r1 = gs[g+1];
  for (int rr = r0; rr < r1; ++rr) s += dg35_ldx(h2, (size_t)rr*dgC + c, af);
  vt[g*dgC + c] = s + vn[g*dgC + c];
}

__global__ void dg35_vnfin(const float* __restrict__ z2, const float* __restrict__ ab,
                           float* __restrict__ vn){
  int i = blockIdx.x*256 + threadIdx.x;
  int c = i & (dgC-1);
  vn[i] = fmaxf(z2[i]*ab[c] + ab[dgC + c], 0.f);
}

__global__ __launch_bounds__(128)
void dg35_addvn(void* __restrict__ h2, const float* __restrict__ vn,
                const int* __restrict__ batch, int af){
  int i = blockIdx.x, c = threadIdx.x;
  size_t idx = (size_t)i*dgC + c;
  dg35_stx(h2, idx, af, dg35_ldx(h2, idx, af) + vn[batch[i]*dgC + c]);
}

__global__ __launch_bounds__(128)
void dg35_out(const void* __restrict__ h, const float* __restrict__ ab,
              const int* __restrict__ gs, float* __restrict__ out, int af){
  int g = blockIdx.x, c = threadIdx.x;
  float a = ab[c], b = ab[dgC + c];
  float s = 0.f;
  int r0 = gs[g], r1 = gs[g+1];
  for (int rr = r0; rr < r1; ++rr) s += dg35_ldx(h, (size_t)rr*dgC + c, af)*a + b;
  out[g*dgC + c] = s;
}

static inline size_t dg35_al(size_t x){ return (x + 255) & ~(size_t)255; }

extern "C" void kernel_launch(void* const* d_in, const int* in_sizes, int n_in,
                              void* d_out, int out_size, void* d_ws, size_t ws_size,
                              hipStream_t stream)
{
  const int*   x     = (const int*)d_in[0];
  const int*   eattr = (const int*)d_in[1];
  const int*   eidx  = (const int*)d_in[2];
  const int*   batch = (const int*)d_in[3];
  const float* aemb  = (const float*)d_in[4];
  const float* bemb  = (const float*)d_in[5];
  const float* vne   = (const float*)d_in[6];
  const float* cW1   = (const float*)d_in[7];
  const float* cb1   = (const float*)d_in[8];
  const float* cg1   = (const float*)d_in[9];
  const float* cbb1  = (const float*)d_in[10];
  const float* cW2   = (const float*)d_in[11];
  const float* cb2   = (const float*)d_in[12];
  const float* ng    = (const float*)d_in[13];
  const float* nb    = (const float*)d_in[14];
  const float* vW1   = (const float*)d_in[15];
  const float* vb1   = (const float*)d_in[16];
  const float* vg1   = (const float*)d_in[17];
  const float* vbb1  = (const float*)d_in[18];
  const float* vW2   = (const float*)d_in[19];
  const float* vb2   = (const float*)d_in[20];
  const float* vg2   = (const float*)d_in[21];
  const float* vbb2  = (const float*)d_in[22];
  float* out = (float*)d_out;

  const int nsb = (dgN + 255) / 256;   // 196 scan blocks

  // fixed-size tail (precision-independent)
  const size_t fixed =
      dg35_al(dgG*dgC*4)*4 +                    // vn, vt, zv1, zv2
      dg35_al(2*dgC2*4)*2 +                     // st1, ab1
      dg35_al(2*dgC*4)*6 +                      // stH,stV1,stV2,abh,abv1,abv2
      dg35_al(dgN*4)*2 + dg35_al((dgN+1)*4) +   // deg, cur, off
      dg35_al((dgG+1)*4) +                      // gs
      dg35_al((size_t)dgE*4) +                  // packed
      dg35_al(7*256*128*2)*4 +                  // Wt1h, Wt1l, Wt2h, Wt2l (bf16)
      dg35_al(256*4)*2;                         // bsum, boff
  int af = 0;
  size_t esz = 2;
  {
    size_t bigf = dg35_al((size_t)dgN*dgC*4)*2 + dg35_al((size_t)dgN*dgC2*4);
    if (bigf + fixed <= ws_size){ af = 1; esz = 4; }
  }

  char* base = (char*)d_ws;
  size_t o = 0;
  void* h  = (void*)(base + o); o += dg35_al((size_t)dgN*dgC*esz);
  void* hh = (void*)(base + o); o += dg35_al((size_t)dgN*dgC*esz);
  void* zb = (void*)(base + o); o += dg35_al((size_t)dgN*dgC2*esz);
  float* vn   = (float*)(base + o); o += dg35_al(dgG*dgC*4);
  float* vt   = (float*)(base + o); o += dg35_al(dgG*dgC*4);
  float* zv1  = (float*)(base + o); o += dg35_al(dgG*dgC*4);
  float* zv2  = (float*)(base + o); o += dg35_al(dgG*dgC*4);
  float* st1  = (float*)(base + o); o += dg35_al(2*dgC2*4);
  float* ab1  = (float*)(base + o); o += dg35_al(2*dgC2*4);
  float* stH  = (float*)(base + o); o += dg35_al(2*dgC*4);
  float* stV1 = (float*)(base + o); o += dg35_al(2*dgC*4);
  float* stV2 = (float*)(base + o); o += dg35_al(2*dgC*4);
  float* abh  = (float*)(base + o); o += dg35_al(2*dgC*4);
  float* abv1 = (float*)(base + o); o += dg35_al(2*dgC*4);
  float* abv2 = (float*)(base + o); o += dg35_al(2*dgC*4);
  int* deg = (int*)(base + o); o += dg35_al(dgN*4);
  int* cur = (int*)(base + o); o += dg35_al(dgN*4);
  int* off = (int*)(base + o); o += dg35_al((dgN+1)*4);
  int* gs  = (int*)(base + o); o += dg35_al((dgG+1)*4);
  dg35_u32* packed = (dg35_u32*)(base + o); o += dg35_al((size_t)dgE*4);
  short* Wt1h = (short*)(base + o); o += dg35_al(7*256*128*2);
  short* Wt1l = (short*)(base + o); o += dg35_al(7*256*128*2);
  short* Wt2h = (short*)(base + o); o += dg35_al(7*256*128*2);
  short* Wt2l = (short*)(base + o); o += dg35_al(7*256*128*2);
  int* bsum = (int*)(base + o); o += dg35_al(256*4);
  int* boff = (int*)(base + o); o += dg35_al(256*4);

  if (o > ws_size){
    hipMemsetAsync(d_out, 0x7F, (size_t)out_size*4, stream);  // ws too small sentinel
    return;
  }
  void* h2 = zb;   // [N, C]  — dead before z is written
  void* z  = zb;   // [N, 2C]

  // ---- per-call setup: CSR by dst, graph ranges, encoders, weight split ----
  hipMemsetAsync(deg, 0, sizeof(int)*dgN, stream);
  dg35_count  <<<(dgE+255)/256, 256, 0, stream>>>(eidx + dgE, deg, dgE);
  dg35_s1     <<<nsb, 256, 0, stream>>>(deg, bsum, dgN);
  dg35_s2     <<<1, 256, 0, stream>>>(bsum, boff, nsb);
  dg35_s3     <<<nsb, 256, 0, stream>>>(deg, boff, off, cur, dgN);
  dg35_scatter<<<(dgE+255)/256, 256, 0, stream>>>(eidx, eattr, cur, packed, dgE);
  dg35_gstart <<<(dgG+256)/256, 256, 0, stream>>>(batch, gs, dgN, dgG);
  dg35_atom   <<<dgN, dgC, 0, stream>>>(x, aemb, vne, h, af);
  dg35_vninit <<<(dgG*dgC)/256, 256, 0, stream>>>(vne, vn);
  dg35_wconv  <<<1792, 256, 0, stream>>>(cW1, cW2, Wt1h, Wt1l, Wt2h, Wt2l);

  const int gmx = (dgN + 127) / 128;  // 391 row-blocks for MFMA GEMM
  const int gx  = (dgN + 63) / 64;    // 782 row-blocks for VALU fallback
  for (int l = 0; l < 7; ++l){
    dg35_zero<<<1, 512, 0, stream>>>(st1, stH, stV1, stV2);
    const void* hin = h;
    if (l > 0){
      dg35_colstats<<<128, 256, 0, stream>>>(h, stH, dgN, dgC, af);
      dg35_fin<<<1, 256, 0, stream>>>(stH, ng + (l-1)*dgC, nb + (l-1)*dgC,
                                      abh, 1.f/dgN, dgC);
      dg35_h2<<<(dgN*dgC)/256, 256, 0, stream>>>(h, abh, h2, af);
      dg35_vt<<<dgG, dgC, 0, stream>>>(h2, vn, gs, vt, af);
      dg35_gemm_v<<<dim3(16,2), 256, 0, stream>>>(vt, vW1 + (l-1)*dgC*dgC,
                                                  vb1 + (l-1)*dgC, (const float*)0,
                                                  zv1, dgG, dgC, dgC, 0);
      dg35_colstats<<<64, 256, 0, stream>>>(zv1, stV1, dgG, dgC, 1);
      dg35_fin<<<1, 256, 0, stream>>>(stV1, vg1 + (l-1)*dgC, vbb1 + (l-1)*dgC,
                                      abv1, 1.f/dgG, dgC);
      dg35_gemm_v<<<dim3(16,2), 256, 0, stream>>>(zv1, vW2 + (l-1)*dgC*dgC,
                                                  vb2 + (l-1)*dgC, abv1,
                                                  zv2, dgG, dgC, dgC, 1);
      dg35_colstats<<<64, 256, 0, stream>>>(zv2, stV2, dgG, dgC, 1);
      dg35_fin<<<1, 256, 0, stream>>>(stV2, vg2 + (l-1)*dgC, vbb2 + (l-1)*dgC,
                                      abv2, 1.f/dgG, dgC);
      dg35_vnfin<<<(dgG*dgC)/256, 256, 0, stream>>>(zv2, abv2, vn);
      dg35_addvn<<<dgN, dgC, 0, stream>>>(h2, vn, batch, af);
      hin = h2;
    }
    dg35_gb<<<dgN, dgC, 0, stream>>>(hin, packed, off, bemb, hh, af);
    if (af){
      dg35_gemmx<<<dim3(gmx,4), 256, 0, stream>>>((const float*)hh,
                                                  Wt1h + l*32768, Wt1l + l*32768,
                                                  cb1 + l*dgC2, (const float*)0,
                                                  (const float*)0, (float*)z,
                                                  dgN, dgC, dgC2, 0, 0);
    } else {
      dg35_gemm_h<<<dim3(gx,4), 256, 0, stream>>>(hh, cW1 + l*dgC*dgC2,
                                                  cb1 + l*dgC2, (const float*)0,
                                                  (const void*)0, z,
                                                  dgN, dgC, dgC2, 0, 0, af);
    }
    dg35_colstats<<<128, 256, 0, stream>>>(z, st1, dgN, dgC2, af);
    dg35_fin<<<1, 256, 0, stream>>>(st1, cg1 + l*dgC2, cbb1 + l*dgC2,
                                    ab1, 1.f/dgN, dgC2);
    if (af){
      dg35_gemmx<<<dim3(gmx,2), 256, 0, stream>>>((const float*)z,
                                                  Wt2h + l*32768, Wt2l + l*32768,
                                                  cb2 + l*dgC, ab1,
                                                  (l==0) ? (const float*)0 : (const float*)h,
                                                  (float*)h, dgN, dgC2, dgC, 1, (l==0)?0:1);
    } else {
      dg35_gemm_h<<<dim3(gx,2), 256, 0, stream>>>(z, cW2 + l*dgC2*dgC,
                                                  cb2 + l*dgC, ab1, h, h,
                                                  dgN, dgC2, dgC, 1, (l==0)?0:1, af);
    }
  }
  // final BN + global_add_pool
  hipMemsetAsync(stH, 0, sizeof(float)*2*dgC, stream);
  dg35_colstats<<<128, 256, 0, stream>>>(h, stH, dgN, dgC, af);
  dg35_fin<<<1, 256, 0, stream>>>(stH, ng + 6*dgC, nb + 6*dgC, abh, 1.f/dgN, dgC);
  dg35_out<<<dgG, dgC, 0, stream>>>(h, abh, gs, out, af);
}

// Round 9
// 3197.440 us; speedup vs baseline: 1.1217x; 1.0379x over previous
//
#include <hip/hip_runtime.h>

typedef unsigned short dg35_u16;
typedef unsigned int   dg35_u32;

constexpr int dgN  = 50000;
constexpr int dgE  = 400000;
constexpr int dgG  = 1024;
constexpr int dgC  = 128;
constexpr int dgC2 = 256;

typedef __attribute__((ext_vector_type(8))) short dg35_s8v;   // 8 bf16 (4 VGPR)
typedef __attribute__((ext_vector_type(4))) float dg35_f4v;   // MFMA acc

__device__ __forceinline__ float dg35_bf2f(dg35_u16 u){
  return __uint_as_float(((dg35_u32)u) << 16);
}
__device__ __forceinline__ dg35_u16 dg35_f2bf(float f){
  dg35_u32 u = __float_as_uint(f);
  u += 0x7FFFu + ((u >> 16) & 1u);
  return (dg35_u16)(u >> 16);
}
// dual-precision big-buffer accessors: af=1 -> float, af=0 -> bf16(u16)
__device__ __forceinline__ float dg35_ldx(const void* p, size_t i, int af){
  return af ? ((const float*)p)[i] : dg35_bf2f(((const dg35_u16*)p)[i]);
}
__device__ __forceinline__ void dg35_stx(void* p, size_t i, int af, float v){
  if (af) ((float*)p)[i] = v; else ((dg35_u16*)p)[i] = dg35_f2bf(v);
}

// Symbol from the harness template; kept but never launched.
__global__ void DeeperGCN_35820027248884_kernel(){}

// ---------------- CSR build ----------------
__global__ void dg35_count(const int* __restrict__ dst, int* __restrict__ deg, int e){
  int j = blockIdx.x*256 + threadIdx.x;
  if (j < e) atomicAdd(&deg[dst[j]], 1);
}

__global__ void dg35_s1(const int* __restrict__ deg, int* __restrict__ bsum, int n){
  __shared__ int sm[256];
  int t = threadIdx.x, b = blockIdx.x;
  int idx = b*256 + t;
  sm[t] = (idx < n) ? deg[idx] : 0;
  __syncthreads();
  for (int s = 128; s > 0; s >>= 1){
    if (t < s) sm[t] += sm[t+s];
    __syncthreads();
  }
  if (t == 0) bsum[b] = sm[0];
}

__global__ void dg35_s2(const int* __restrict__ bsum, int* __restrict__ boff, int nb){
  __shared__ int sm[256];
  int t = threadIdx.x;
  int v = (t < nb) ? bsum[t] : 0;
  sm[t] = v;
  __syncthreads();
  for (int s = 1; s < 256; s <<= 1){
    int u = (t >= s) ? sm[t-s] : 0;
    __syncthreads();
    sm[t] += u;
    __syncthreads();
  }
  if (t < nb) boff[t] = sm[t] - v;   // exclusive
}

__global__ void dg35_s3(const int* __restrict__ deg, const int* __restrict__ boff,
                        int* __restrict__ off, int* __restrict__ cur, int n){
  __shared__ int sm[256];
  int t = threadIdx.x, b = blockIdx.x;
  int idx = b*256 + t;
  int v = (idx < n) ? deg[idx] : 0;
  sm[t] = v;
  __syncthreads();
  for (int s = 1; s < 256; s <<= 1){
    int u = (t >= s) ? sm[t-s] : 0;
    __syncthreads();
    sm[t] += u;
    __syncthreads();
  }
  if (idx < n){
    int e = boff[b] + sm[t] - v;
    off[idx] = e; cur[idx] = e;
  }
  if (idx == 0) off[n] = dgE;
}

__global__ void dg35_scatter(const int* __restrict__ ei, const int* __restrict__ ea,
                             int* __restrict__ cur, dg35_u32* __restrict__ packed, int e){
  int j = blockIdx.x*256 + threadIdx.x;
  if (j >= e) return;
  int s = ei[j], d = ei[e + j];
  dg35_u32 a0 = (dg35_u32)ea[3*j], a1 = (dg35_u32)ea[3*j+1], a2 = (dg35_u32)ea[3*j+2];
  int pos = atomicAdd(&cur[d], 1);
  packed[pos] = (dg35_u32)s | (a0<<17) | (a1<<20) | (a2<<23);
}

__global__ void dg35_gstart(const int* __restrict__ batch, int* __restrict__ gs, int n, int g){
  int i = blockIdx.x*256 + threadIdx.x;
  if (i > g) return;
  if (i == g){ gs[i] = n; return; }
  int lo = 0, hi = n;
  while (lo < hi){ int mid = (lo+hi)>>1; if (batch[mid] < i) lo = mid+1; else hi = mid; }
  gs[i] = lo;
}

// ---------------- encoders / weight prep ----------------
__global__ __launch_bounds__(128)
void dg35_atom(const int* __restrict__ x, const float* __restrict__ aemb,
               const float* __restrict__ vne, void* __restrict__ h, int af){
  int i = blockIdx.x, c = threadIdx.x;
  float acc = vne[c];
  #pragma unroll
  for (int f = 0; f < 9; ++f){
    int idx = x[i*9 + f];
    acc += aemb[(f*128 + idx)*dgC + c];
  }
  dg35_stx(h, (size_t)i*dgC + c, af, acc);
}

__global__ void dg35_vninit(const float* __restrict__ vne, float* __restrict__ vn){
  int i = blockIdx.x*256 + threadIdx.x;
  if (i < dgG*dgC) vn[i] = vne[i & (dgC-1)];
}

// transpose+convert conv weights to SPLIT bf16 (hi+lo) in [l][n][k] layout
__global__ void dg35_wconv(const float* __restrict__ W1, const float* __restrict__ W2,
                           short* __restrict__ Wt1h, short* __restrict__ Wt1l,
                           short* __restrict__ Wt2h, short* __restrict__ Wt2l){
  int i = blockIdx.x*256 + threadIdx.x;
  constexpr int per = 7*256*128;  // 229376
  float w;
  short* ph; short* pl; int oidx;
  if (i < per){
    int l = i >> 15;
    int rem = i & 32767;
    int n = rem >> 7;
    int k = rem & 127;
    w = W1[l*32768 + k*256 + n];
    ph = Wt1h; pl = Wt1l; oidx = i;
  } else {
    int j = i - per;
    int l = j >> 15;
    int rem = j & 32767;
    int n = rem >> 8;
    int k = rem & 255;
    w = W2[l*32768 + k*128 + n];
    ph = Wt2h; pl = Wt2l; oidx = j;
  }
  dg35_u16 hi = dg35_f2bf(w);
  float lo = w - dg35_bf2f(hi);
  ph[oidx] = (short)hi;
  pl[oidx] = (short)dg35_f2bf(lo);
}

__global__ void dg35_zero(float* a, float* b, float* c_, float* d){
  int t = threadIdx.x;
  if (t < 512) a[t] = 0.f;
  if (t < 256){ b[t]=0.f; c_[t]=0.f; d[t]=0.f; }
}

// ------------- GENConv softmax aggregation: 1 wave/node, 2 ch/lane, branchless -------------
__global__ __launch_bounds__(256)
void dg35_gb2(const float* __restrict__ hin, const dg35_u32* __restrict__ packed,
              const int* __restrict__ off, const float* __restrict__ bemb,
              float* __restrict__ hh){
  int i = blockIdx.x*4 + (threadIdx.x >> 6);
  if (i >= dgN) return;
  int c = (threadIdx.x & 63) * 2;
  int b0 = off[i], b1 = off[i+1];
  float2 self = *reinterpret_cast<const float2*>(hin + (size_t)i*dgC + c);
  float m0 = -3.0e38f, m1 = -3.0e38f;
  float s0 = 0.f, s1 = 0.f, w0 = 0.f, w1 = 0.f;
  for (int p = b0; p < b1; ++p){
    dg35_u32 pk = packed[p];
    int src = (int)(pk & 0x1FFFFu);
    float2 hv = *reinterpret_cast<const float2*>(hin + (size_t)src*dgC + c);
    float2 e0 = *reinterpret_cast<const float2*>(bemb + ((pk>>17)&7)*dgC + c);
    float2 e1 = *reinterpret_cast<const float2*>(bemb + (8+((pk>>20)&7))*dgC + c);
    float2 e2 = *reinterpret_cast<const float2*>(bemb + (16+((pk>>23)&7))*dgC + c);
    float msg0 = fmaxf(hv.x + e0.x + e1.x + e2.x, 0.f) + 1e-7f;
    float msg1 = fmaxf(hv.y + e0.y + e1.y + e2.y, 0.f) + 1e-7f;
    float mn0 = fmaxf(m0, msg0), mn1 = fmaxf(m1, msg1);
    float sc0 = __expf(m0 - mn0), t0 = __expf(msg0 - mn0);
    float sc1 = __expf(m1 - mn1), t1 = __expf(msg1 - mn1);
    s0 = s0*sc0 + t0;  w0 = w0*sc0 + msg0*t0;  m0 = mn0;
    s1 = s1*sc1 + t1;  w1 = w1*sc1 + msg1*t1;  m1 = mn1;
  }
  float2 o;
  o.x = self.x + ((b1 > b0) ? (w0 / (s0 + 1e-16f)) : 0.f);
  o.y = self.y + ((b1 > b0) ? (w1 / (s1 + 1e-16f)) : 0.f);
  *reinterpret_cast<float2*>(hh + (size_t)i*dgC + c) = o;
}

// ---- split-bf16 MFMA GEMM: Cout(f32) = act(A f32) @ W(f32 via hi+lo bf16) + bias (+res)
__global__ __launch_bounds__(256)
void dg35_gemmx(const float* __restrict__ A, const short* __restrict__ Whi,
                const short* __restrict__ Wlo,
                const float* __restrict__ bias, const float* __restrict__ ab,
                const float* __restrict__ res, float* __restrict__ Cout,
                int M, int K, int NC, int trans, int addres){
  __shared__ short Ahi[128*64];   // 16 KB
  __shared__ short Alo[128*64];   // 16 KB
  int tid = threadIdx.x;
  int bm = blockIdx.x * 128;
  int bn = blockIdx.y * 64;
  int lane = tid & 63;
  int wv = tid >> 6;
  int l15 = lane & 15;
  int l4  = lane >> 4;
  dg35_f4v acc[2][4] = {};

  int r = tid >> 1;
  int ch = tid & 1;
  int grow = bm + r;

  for (int k0 = 0; k0 < K; k0 += 64){
    {
      float xv[32];
      if (grow < M){
        const float* ap = A + (size_t)grow*K + k0 + ch*32;
        #pragma unroll
        for (int q = 0; q < 8; ++q){
          float4 v = *reinterpret_cast<const float4*>(ap + q*4);
          xv[q*4+0]=v.x; xv[q*4+1]=v.y; xv[q*4+2]=v.z; xv[q*4+3]=v.w;
        }
      } else {
        #pragma unroll
        for (int q = 0; q < 32; ++q) xv[q] = 0.f;
      }
      if (trans){
        #pragma unroll
        for (int q = 0; q < 32; ++q){
          int kk = k0 + ch*32 + q;
          xv[q] = fmaxf(xv[q]*ab[kk] + ab[K + kk], 0.f);
        }
      }
      #pragma unroll
      for (int g = 0; g < 4; ++g){
        uint4 wh, wl;
        unsigned* hp = (unsigned*)&wh;
        unsigned* lp = (unsigned*)&wl;
        #pragma unroll
        for (int d = 0; d < 4; ++d){
          float f0 = xv[g*8 + d*2], f1 = xv[g*8 + d*2 + 1];
          dg35_u16 h0 = dg35_f2bf(f0), h1 = dg35_f2bf(f1);
          dg35_u16 l0 = dg35_f2bf(f0 - dg35_bf2f(h0));
          dg35_u16 l1 = dg35_f2bf(f1 - dg35_bf2f(h1));
          hp[d] = (dg35_u32)h0 | ((dg35_u32)h1 << 16);
          lp[d] = (dg35_u32)l0 | ((dg35_u32)l1 << 16);
        }
        int slot = (ch*4 + g) ^ (r & 7);
        *reinterpret_cast<uint4*>(&Ahi[r*64 + slot*8]) = wh;
        *reinterpret_cast<uint4*>(&Alo[r*64 + slot*8]) = wl;
      }
    }
    __syncthreads();
    #pragma unroll
    for (int ks = 0; ks < 2; ++ks){
      dg35_s8v bh[4], bl[4];
      #pragma unroll
      for (int nf = 0; nf < 4; ++nf){
        int n = bn + nf*16 + l15;
        size_t wo = (size_t)n*K + k0 + ks*32 + l4*8;
        bh[nf] = *reinterpret_cast<const dg35_s8v*>(Whi + wo);
        bl[nf] = *reinterpret_cast<const dg35_s8v*>(Wlo + wo);
      }
      #pragma unroll
      for (int mf = 0; mf < 2; ++mf){
        int row = wv*32 + mf*16 + l15;
        int slot = (ks*4 + l4) ^ (row & 7);
        dg35_s8v ah = *reinterpret_cast<const dg35_s8v*>(&Ahi[row*64 + slot*8]);
        dg35_s8v al = *reinterpret_cast<const dg35_s8v*>(&Alo[row*64 + slot*8]);
        #pragma unroll
        for (int nf = 0; nf < 4; ++nf){
          acc[mf][nf] = __builtin_amdgcn_mfma_f32_16x16x32_bf16(ah, bh[nf], acc[mf][nf], 0, 0, 0);
          acc[mf][nf] = __builtin_amdgcn_mfma_f32_16x16x32_bf16(al, bh[nf], acc[mf][nf], 0, 0, 0);
          acc[mf][nf] = __builtin_amdgcn_mfma_f32_16x16x32_bf16(ah, bl[nf], acc[mf][nf], 0, 0, 0);
        }
      }
    }
    __syncthreads();
  }
  #pragma unroll
  for (int mf = 0; mf < 2; ++mf){
    #pragma unroll
    for (int e = 0; e < 4; ++e){
      int rr = bm + wv*32 + mf*16 + l4*4 + e;
      if (rr >= M) continue;
      #pragma unroll
      for (int nf = 0; nf < 4; ++nf){
        int cc = bn + nf*16 + l15;
        float v = acc[mf][nf][e] + bias[cc];
        size_t idx = (size_t)rr*NC + cc;
        if (addres) v += res[idx];
        Cout[idx] = v;
      }
    }
  }
}

// -------- VALU GEMM (dual-precision) — tier-B fallback only --------
__global__ __launch_bounds__(256)
void dg35_gemm_h(const void* __restrict__ A, const float* __restrict__ W,
                 const float* __restrict__ bias, const float* __restrict__ ab,
                 const void* __restrict__ res, void* __restrict__ Cout,
                 int M, int K, int NC, int trans, int addres, int af){
  __shared__ float At[32][65];
  __shared__ float Bt[32][64];
  int bm = blockIdx.x * 64;
  int bn = blockIdx.y * 64;
  int tid = threadIdx.x;
  int tx = tid & 15, ty = tid >> 4;
  float acc[4][4];
  #pragma unroll
  for (int i2 = 0; i2 < 4; ++i2)
    #pragma unroll
    for (int j2 = 0; j2 < 4; ++j2) acc[i2][j2] = 0.f;

  for (int k0 = 0; k0 < K; k0 += 32){
    int r = tid >> 3;
    int kq = (tid & 7) * 4;
    #pragma unroll
    for (int half = 0; half < 2; ++half){
      int rr = r + half*32;
      int grow = bm + rr;
      float vv[4] = {0.f, 0.f, 0.f, 0.f};
      if (grow < M){
        if (af){
          float4 v4 = *reinterpret_cast<const float4*>((const float*)A + (size_t)grow*K + k0 + kq);
          vv[0] = v4.x; vv[1] = v4.y; vv[2] = v4.z; vv[3] = v4.w;
        } else {
          ushort4 v4 = *reinterpret_cast<const ushort4*>((const dg35_u16*)A + (size_t)grow*K + k0 + kq);
          vv[0] = dg35_bf2f(v4.x); vv[1] = dg35_bf2f(v4.y);
          vv[2] = dg35_bf2f(v4.z); vv[3] = dg35_bf2f(v4.w);
        }
      }
      #pragma unroll
      for (int i2 = 0; i2 < 4; ++i2){
        float xv = vv[i2];
        if (trans){
          int kk = k0 + kq + i2;
          xv = fmaxf(xv*ab[kk] + ab[K + kk], 0.f);
        }
        At[kq + i2][rr] = xv;
      }
    }
    {
      int kr = tid >> 3;
      int cq = (tid & 7) * 8;
      const float* wp = W + (size_t)(k0 + kr)*NC + bn + cq;
      #pragma unroll
      for (int i2 = 0; i2 < 8; ++i2) Bt[kr][cq + i2] = wp[i2];
    }
    __syncthreads();
    #pragma unroll
    for (int kk = 0; kk < 32; ++kk){
      float a4[4], b4[4];
      #pragma unroll
      for (int i2 = 0; i2 < 4; ++i2) a4[i2] = At[kk][ty*4 + i2];
      #pragma unroll
      for (int j2 = 0; j2 < 4; ++j2) b4[j2] = Bt[kk][tx*4 + j2];
      #pragma unroll
      for (int i2 = 0; i2 < 4; ++i2)
        #pragma unroll
        for (int j2 = 0; j2 < 4; ++j2)
          acc[i2][j2] += a4[i2]*b4[j2];
    }
    __syncthreads();
  }
  #pragma unroll
  for (int i2 = 0; i2 < 4; ++i2){
    int rr = bm + ty*4 + i2;
    if (rr >= M) continue;
    #pragma unroll
    for (int j2 = 0; j2 < 4; ++j2){
      int cc = bn + tx*4 + j2;
      float v = acc[i2][j2] + bias[cc];
      size_t idx = (size_t)rr*NC + cc;
      if (addres) v += dg35_ldx(res, idx, af);
      dg35_stx(Cout, idx, af, v);
    }
  }
}

// -------- GEMM, A f32, W f32, f32 out (virtual-node MLP, M=1024) --------
__global__ __launch_bounds__(256)
void dg35_gemm_v(const float* __restrict__ A, const float* __restrict__ W,
                 const float* __restrict__ bias, const float* __restrict__ ab,
                 float* __restrict__ Cout, int M, int K, int NC, int trans){
  __shared__ float At[32][65];
  __shared__ float Bt[32][64];
  int bm = blockIdx.x * 64;
  int bn = blockIdx.y * 64;
  int tid = threadIdx.x;
  int tx = tid & 15, ty = tid >> 4;
  float acc[4][4];
  #pragma unroll
  for (int i2 = 0; i2 < 4; ++i2)
    #pragma unroll
    for (int j2 = 0; j2 < 4; ++j2) acc[i2][j2] = 0.f;

  for (int k0 = 0; k0 < K; k0 += 32){
    int r = tid >> 3;
    int kq = (tid & 7) * 4;
    #pragma unroll
    for (int half = 0; half < 2; ++half){
      int rr = r + half*32;
      int grow = bm + rr;
      float vv[4] = {0.f, 0.f, 0.f, 0.f};
      if (grow < M){
        float4 v4 = *reinterpret_cast<const float4*>(A + (size_t)grow*K + k0 + kq);
        vv[0] = v4.x; vv[1] = v4.y; vv[2] = v4.z; vv[3] = v4.w;
      }
      #pragma unroll
      for (int i2 = 0; i2 < 4; ++i2){
        float xv = vv[i2];
        if (trans){
          int kk = k0 + kq + i2;
          xv = fmaxf(xv*ab[kk] + ab[K + kk], 0.f);
        }
        At[kq + i2][rr] = xv;
      }
    }
    {
      int kr = tid >> 3;
      int cq = (tid & 7) * 8;
      const float* wp = W + (size_t)(k0 + kr)*NC + bn + cq;
      #pragma unroll
      for (int i2 = 0; i2 < 8; ++i2) Bt[kr][cq + i2] = wp[i2];
    }
    __syncthreads();
    #pragma unroll
    for (int kk = 0; kk < 32; ++kk){
      float a4[4], b4[4];
      #pragma unroll
      for (int i2 = 0; i2 < 4; ++i2) a4[i2] = At[kk][ty*4 + i2];
      #pragma unroll
      for (int j2 = 0; j2 < 4; ++j2) b4[j2] = Bt[kk][tx*4 + j2];
      #pragma unroll
      for (int i2 = 0; i2 < 4; ++i2)
        #pragma unroll
        for (int j2 = 0; j2 < 4; ++j2)
          acc[i2][j2] += a4[i2]*b4[j2];
    }
    __syncthreads();
  }
  #pragma unroll
  for (int i2 = 0; i2 < 4; ++i2){
    int rr = bm + ty*4 + i2;
    if (rr >= M) continue;
    #pragma unroll
    for (int j2 = 0; j2 < 4; ++j2){
      int cc = bn + tx*4 + j2;
      Cout[(size_t)rr*NC + cc] = acc[i2][j2] + bias[cc];
    }
  }
}

// ---------------- BN statistics — fast f32 path: float4/thread, high parallelism ----------------
__global__ __launch_bounds__(256)
void dg35_cs4(const float* __restrict__ Z, float* __restrict__ st, int n, int ncols){
  int t = threadIdx.x;
  int lpr = ncols >> 2;            // lanes per row: 32 (C=128) or 64 (C=256)
  int rl = t / lpr;                // row-lane
  int rpb = 256 / lpr;             // rows per block: 8 or 4
  int cq = (t - rl*lpr) * 4;
  float4 s = make_float4(0.f,0.f,0.f,0.f);
  float4 q = make_float4(0.f,0.f,0.f,0.f);
  for (int rr = blockIdx.x*rpb + rl; rr < n; rr += gridDim.x*rpb){
    float4 v = *reinterpret_cast<const float4*>(Z + (size_t)rr*ncols + cq);
    s.x += v.x; s.y += v.y; s.z += v.z; s.w += v.w;
    q.x += v.x*v.x; q.y += v.y*v.y; q.z += v.z*v.z; q.w += v.w*v.w;
  }
  __shared__ float sm[256*8];
  float* my = &sm[t*8];
  my[0]=s.x; my[1]=s.y; my[2]=s.z; my[3]=s.w;
  my[4]=q.x; my[5]=q.y; my[6]=q.z; my[7]=q.w;
  __syncthreads();
  if (rl == 0){
    float a[8];
    #pragma unroll
    for (int d = 0; d < 8; ++d) a[d] = my[d];
    for (int j = 1; j < rpb; ++j){
      const float* o = &sm[(t + j*lpr)*8];
      #pragma unroll
      for (int d = 0; d < 8; ++d) a[d] += o[d];
    }
    #pragma unroll
    for (int d = 0; d < 4; ++d) atomicAdd(&st[cq + d], a[d]);
    #pragma unroll
    for (int d = 0; d < 4; ++d) atomicAdd(&st[ncols + cq + d], a[4 + d]);
  }
}

// tier-B fallback colstats (dual precision)
__global__ void dg35_colstats(const void* __restrict__ Z, float* __restrict__ st,
                              int n, int ncols, int af){
  int tid = threadIdx.x;
  int c = tid & (ncols - 1);
  int rl = tid / ncols;
  int rpb = 256 / ncols;
  float s = 0.f, q = 0.f;
  for (int rr = blockIdx.x*rpb + rl; rr < n; rr += gridDim.x*rpb){
    float v = dg35_ldx(Z, (size_t)rr*ncols + c, af);
    s += v; q += v*v;
  }
  atomicAdd(&st[c], s);
  atomicAdd(&st[ncols + c], q);
}

__global__ void dg35_fin(const float* __restrict__ st, const float* __restrict__ g,
                         const float* __restrict__ b, float* __restrict__ ab,
                         float inv_n, int ncols){
  int c = threadIdx.x + blockIdx.x*256;
  if (c >= ncols) return;
  float m = st[c]*inv_n;
  float var = st[ncols + c]*inv_n - m*m;
  float rstd = rsqrtf(var + 1e-5f);
  float a = g[c]*rstd;
  ab[c] = a;
  ab[ncols + c] = b[c] - m*a;
}

// ---------------- elementwise / segment ops ----------------
__global__ void dg35_h2(const void* __restrict__ h, const float* __restrict__ ab,
                        void* __restrict__ h2, int af){
  int i = blockIdx.x*256 + threadIdx.x;
  int c = i & (dgC-1);
  dg35_stx(h2, i, af, fmaxf(dg35_ldx(h, i, af)*ab[c] + ab[dgC + c], 0.f));
}

// fast f32 vt: 4 rows parallel x float4, LDS reduce
__global__ __launch_bounds__(128)
void dg35_vt4(const float* __restrict__ h2, const float* __restrict__ vn,
              const int* __restrict__ gs, float* __restrict__ vt){
  int g = blockIdx.x, t = threadIdx.x;
  int rl = t >> 5, cl = t & 31;
  int cq = cl*4;
  int r0 = gs[g], r1 = gs[g+1];
  float4 s = make_float4(0.f,0.f,0.f,0.f);
  for (int rr = r0 + rl; rr < r1; rr += 4){
    float4 v = *reinterpret_cast<const float4*>(h2 + (size_t)rr*dgC + cq);
    s.x += v.x; s.y += v.y; s.z += v.z; s.w += v.w;
  }
  __shared__ float4 sm[128];
  sm[t] = s;
  __syncthreads();
  if (rl == 0){
    float4 a = sm[cl], b = sm[32+cl], c4 = sm[64+cl], d = sm[96+cl];
    float4 vb = *reinterpret_cast<const float4*>(vn + (size_t)g*dgC + cq);
    float4 o;
    o.x = a.x+b.x+c4.x+d.x + vb.x;
    o.y = a.y+b.y+c4.y+d.y + vb.y;
    o.z = a.z+b.z+c4.z+d.z + vb.z;
    o.w = a.w+b.w+c4.w+d.w + vb.w;
    *reinterpret_cast<float4*>(vt + (size_t)g*dgC + cq) = o;
  }
}

// tier-B fallback vt
__global__ __launch_bounds__(128)
void dg35_vt(const void* __restrict__ h2, const float* __restrict__ vn,
             const int* __restrict__ gs, float* __restrict__ vt, int af){
  int g = blockIdx.x, c = threadIdx.x;
  float s = 0.f;
  int r0 = gs[g], r1 = gs[g+1];
  for (int rr = r0; rr < r1; ++rr) s += dg35_ldx(h2, (size_t)rr*dgC + c, af);
  vt[g*dgC + c] = s + vn[g*dgC + c];
}

__global__ void dg35_vnfin(const float* __restrict__ z2, const float* __restrict__ ab,
                           float* __restrict__ vn){
  int i = blockIdx.x*256 + threadIdx.x;
  int c = i & (dgC-1);
  vn[i] = fmaxf(z2[i]*ab[c] + ab[dgC + c], 0.f);
}

__global__ __launch_bounds__(128)
void dg35_addvn(void* __restrict__ h2, const float* __restrict__ vn,
                const int* __restrict__ batch, int af){
  int i = blockIdx.x, c = threadIdx.x;
  size_t idx = (size_t)i*dgC + c;
  dg35_stx(h2, idx, af, dg35_ldx(h2, idx, af) + vn[batch[i]*dgC + c]);
}

// fast f32 out: Σ(a*h+b) = a*Σh + b*cnt, 4 rows parallel x float4
__global__ __launch_bounds__(128)
void dg35_out4(const float* __restrict__ h, const float* __restrict__ ab,
               const int* __restrict__ gs, float* __restrict__ out){
  int g = blockIdx.x, t = threadIdx.x;
  int rl = t >> 5, cl = t & 31;
  int cq = cl*4;
  int r0 = gs[g], r1 = gs[g+1];
  float4 s = make_float4(0.f,0.f,0.f,0.f);
  for (int rr = r0 + rl; rr < r1; rr += 4){
    float4 v = *reinterpret_cast<const float4*>(h + (size_t)rr*dgC + cq);
    s.x += v.x; s.y += v.y; s.z += v.z; s.w += v.w;
  }
  __shared__ float4 sm[128];
  sm[t] = s;
  __syncthreads();
  if (rl == 0){
    float4 a4 = sm[cl], b4 = sm[32+cl], c4 = sm[64+cl], d4 = sm[96+cl];
    float cnt = (float)(r1 - r0);
    float4 o;
    float S;
    S = a4.x+b4.x+c4.x+d4.x; o.x = ab[cq+0]*S + ab[dgC+cq+0]*cnt;
    S = a4.y+b4.y+c4.y+d4.y; o.y = ab[cq+1]*S + ab[dgC+cq+1]*cnt;
    S = a4.z+b4.z+c4.z+d4.z; o.z = ab[cq+2]*S + ab[dgC+cq+2]*cnt;
    S = a4.w+b4.w+c4.w+d4.w; o.w = ab[cq+3]*S + ab[dgC+cq+3]*cnt;
    *reinterpret_cast<float4*>(out + (size_t)g*dgC + cq) = o;
  }
}

// tier-B fallback pieces
__global__ __launch_bounds__(128)
void dg35_gb(const void* __restrict__ hin, const dg35_u32* __restrict__ packed,
             const int* __restrict__ off, const float* __restrict__ bemb,
             void* __restrict__ hh, int af){
  int i = blockIdx.x, c = threadIdx.x;
  int b0 = off[i], b1 = off[i+1];
  float m = -3.0e38f, s = 0.f, w = 0.f;
  for (int p = b0; p < b1; ++p){
    dg35_u32 pk = packed[p];
    int src = (int)(pk & 0x1FFFFu);
    float e = bemb[((pk>>17)&7)*dgC + c] + bemb[(8+((pk>>20)&7))*dgC + c]
            + bemb[(16+((pk>>23)&7))*dgC + c];
    float msg = fmaxf(dg35_ldx(hin, (size_t)src*dgC + c, af) + e, 0.f) + 1e-7f;
    float mn = fmaxf(m, msg);
    float sc = __expf(m - mn), t2 = __expf(msg - mn);
    s = s*sc + t2; w = w*sc + msg*t2; m = mn;
  }
  float agg = (b1 > b0) ? (w / (s + 1e-16f)) : 0.f;
  float self = dg35_ldx(hin, (size_t)i*dgC + c, af);
  dg35_stx(hh, (size_t)i*dgC + c, af, self + agg);
}

__global__ __launch_bounds__(128)
void dg35_out(const void* __restrict__ h, const float* __restrict__ ab,
              const int* __restrict__ gs, float* __restrict__ out, int af){
  int g = blockIdx.x, c = threadIdx.x;
  float a = ab[c], b = ab[dgC + c];
  float s = 0.f;
  int r0 = gs[g], r1 = gs[g+1];
  for (int rr = r0; rr < r1; ++rr) s += dg35_ldx(h, (size_t)rr*dgC + c, af)*a + b;
  out[g*dgC + c] = s;
}

static inline size_t dg35_al(size_t x){ return (x + 255) & ~(size_t)255; }

extern "C" void kernel_launch(void* const* d_in, const int* in_sizes, int n_in,
                              void* d_out, int out_size, void* d_ws, size_t ws_size,
                              hipStream_t stream)
{
  const int*   x     = (const int*)d_in[0];
  const int*   eattr = (const int*)d_in[1];
  const int*   eidx  = (const int*)d_in[2];
  const int*   batch = (const int*)d_in[3];
  const float* aemb  = (const float*)d_in[4];
  const float* bemb  = (const float*)d_in[5];
  const float* vne   = (const float*)d_in[6];
  const float* cW1   = (const float*)d_in[7];
  const float* cb1   = (const float*)d_in[8];
  const float* cg1   = (const float*)d_in[9];
  const float* cbb1  = (const float*)d_in[10];
  const float* cW2   = (const float*)d_in[11];
  const float* cb2   = (const float*)d_in[12];
  const float* ng    = (const float*)d_in[13];
  const float* nb    = (const float*)d_in[14];
  const float* vW1   = (const float*)d_in[15];
  const float* vb1   = (const float*)d_in[16];
  const float* vg1   = (const float*)d_in[17];
  const float* vbb1  = (const float*)d_in[18];
  const float* vW2   = (const float*)d_in[19];
  const float* vb2   = (const float*)d_in[20];
  const float* vg2   = (const float*)d_in[21];
  const float* vbb2  = (const float*)d_in[22];
  float* out = (float*)d_out;

  const int nsb = (dgN + 255) / 256;   // 196 scan blocks

  const size_t fixed =
      dg35_al(dgG*dgC*4)*4 +
      dg35_al(2*dgC2*4)*2 +
      dg35_al(2*dgC*4)*6 +
      dg35_al(dgN*4)*2 + dg35_al((dgN+1)*4) +
      dg35_al((dgG+1)*4) +
      dg35_al((size_t)dgE*4) +
      dg35_al(7*256*128*2)*4 +
      dg35_al(256*4)*2;
  int af = 0;
  size_t esz = 2;
  {
    size_t bigf = dg35_al((size_t)dgN*dgC*4)*2 + dg35_al((size_t)dgN*dgC2*4);
    if (bigf + fixed <= ws_size){ af = 1; esz = 4; }
  }

  char* base = (char*)d_ws;
  size_t o = 0;
  void* h  = (void*)(base + o); o += dg35_al((size_t)dgN*dgC*esz);
  void* hh = (void*)(base + o); o += dg35_al((size_t)dgN*dgC*esz);
  void* zb = (void*)(base + o); o += dg35_al((size_t)dgN*dgC2*esz);
  float* vn   = (float*)(base + o); o += dg35_al(dgG*dgC*4);
  float* vt   = (float*)(base + o); o += dg35_al(dgG*dgC*4);
  float* zv1  = (float*)(base + o); o += dg35_al(dgG*dgC*4);
  float* zv2  = (float*)(base + o); o += dg35_al(dgG*dgC*4);
  float* st1  = (float*)(base + o); o += dg35_al(2*dgC2*4);
  float* ab1  = (float*)(base + o); o += dg35_al(2*dgC2*4);
  float* stH  = (float*)(base + o); o += dg35_al(2*dgC*4);
  float* stV1 = (float*)(base + o); o += dg35_al(2*dgC*4);
  float* stV2 = (float*)(base + o); o += dg35_al(2*dgC*4);
  float* abh  = (float*)(base + o); o += dg35_al(2*dgC*4);
  float* abv1 = (float*)(base + o); o += dg35_al(2*dgC*4);
  float* abv2 = (float*)(base + o); o += dg35_al(2*dgC*4);
  int* deg = (int*)(base + o); o += dg35_al(dgN*4);
  int* cur = (int*)(base + o); o += dg35_al(dgN*4);
  int* off = (int*)(base + o); o += dg35_al((dgN+1)*4);
  int* gs  = (int*)(base + o); o += dg35_al((dgG+1)*4);
  dg35_u32* packed = (dg35_u32*)(base + o); o += dg35_al((size_t)dgE*4);
  short* Wt1h = (short*)(base + o); o += dg35_al(7*256*128*2);
  short* Wt1l = (short*)(base + o); o += dg35_al(7*256*128*2);
  short* Wt2h = (short*)(base + o); o += dg35_al(7*256*128*2);
  short* Wt2l = (short*)(base + o); o += dg35_al(7*256*128*2);
  int* bsum = (int*)(base + o); o += dg35_al(256*4);
  int* boff = (int*)(base + o); o += dg35_al(256*4);

  if (o > ws_size){
    hipMemsetAsync(d_out, 0x7F, (size_t)out_size*4, stream);
    return;
  }
  void* h2 = zb;
  void* z  = zb;

  // ---- per-call setup ----
  hipMemsetAsync(deg, 0, sizeof(int)*dgN, stream);
  dg35_count  <<<(dgE+255)/256, 256, 0, stream>>>(eidx + dgE, deg, dgE);
  dg35_s1     <<<nsb, 256, 0, stream>>>(deg, bsum, dgN);
  dg35_s2     <<<1, 256, 0, stream>>>(bsum, boff, nsb);
  dg35_s3     <<<nsb, 256, 0, stream>>>(deg, boff, off, cur, dgN);
  dg35_scatter<<<(dgE+255)/256, 256, 0, stream>>>(eidx, eattr, cur, packed, dgE);
  dg35_gstart <<<(dgG+256)/256, 256, 0, stream>>>(batch, gs, dgN, dgG);
  dg35_atom   <<<dgN, dgC, 0, stream>>>(x, aemb, vne, h, af);
  dg35_vninit <<<(dgG*dgC)/256, 256, 0, stream>>>(vne, vn);
  dg35_wconv  <<<1792, 256, 0, stream>>>(cW1, cW2, Wt1h, Wt1l, Wt2h, Wt2l);

  const int gmx = (dgN + 127) / 128;
  const int gx  = (dgN + 63) / 64;
  for (int l = 0; l < 7; ++l){
    dg35_zero<<<1, 512, 0, stream>>>(st1, stH, stV1, stV2);
    const void* hin = h;
    if (l > 0){
      if (af) dg35_cs4<<<768, 256, 0, stream>>>((const float*)h, stH, dgN, dgC);
      else    dg35_colstats<<<128, 256, 0, stream>>>(h, stH, dgN, dgC, af);
      dg35_fin<<<1, 256, 0, stream>>>(stH, ng + (l-1)*dgC, nb + (l-1)*dgC,
                                      abh, 1.f/dgN, dgC);
      dg35_h2<<<(dgN*dgC)/256, 256, 0, stream>>>(h, abh, h2, af);
      if (af) dg35_vt4<<<dgG, 128, 0, stream>>>((const float*)h2, vn, gs, vt);
      else    dg35_vt<<<dgG, dgC, 0, stream>>>(h2, vn, gs, vt, af);
      dg35_gemm_v<<<dim3(16,2), 256, 0, stream>>>(vt, vW1 + (l-1)*dgC*dgC,
                                                  vb1 + (l-1)*dgC, (const float*)0,
                                                  zv1, dgG, dgC, dgC, 0);
      dg35_cs4<<<64, 256, 0, stream>>>(zv1, stV1, dgG, dgC);
      dg35_fin<<<1, 256, 0, stream>>>(stV1, vg1 + (l-1)*dgC, vbb1 + (l-1)*dgC,
                                      abv1, 1.f/dgG, dgC);
      dg35_gemm_v<<<dim3(16,2), 256, 0, stream>>>(zv1, vW2 + (l-1)*dgC*dgC,
                                                  vb2 + (l-1)*dgC, abv1,
                                                  zv2, dgG, dgC, dgC, 1);
      dg35_cs4<<<64, 256, 0, stream>>>(zv2, stV2, dgG, dgC);
      dg35_fin<<<1, 256, 0, stream>>>(stV2, vg2 + (l-1)*dgC, vbb2 + (l-1)*dgC,
                                      abv2, 1.f/dgG, dgC);
      dg35_vnfin<<<(dgG*dgC)/256, 256, 0, stream>>>(zv2, abv2, vn);
      dg35_addvn<<<dgN, dgC, 0, stream>>>(h2, vn, batch, af);
      hin = h2;
    }
    if (af) dg35_gb2<<<(dgN+3)/4, 256, 0, stream>>>((const float*)hin, packed, off, bemb, (float*)hh);
    else    dg35_gb<<<dgN, dgC, 0, stream>>>(hin, packed, off, bemb, hh, af);
    if (af){
      dg35_gemmx<<<dim3(gmx,4), 256, 0, stream>>>((const float*)hh,
                                                  Wt1h + l*32768, Wt1l + l*32768,
                                                  cb1 + l*dgC2, (const float*)0,
                                                  (const float*)0, (float*)z,
                                                  dgN, dgC, dgC2, 0, 0);
      dg35_cs4<<<768, 256, 0, stream>>>((const float*)z, st1, dgN, dgC2);
    } else {
      dg35_gemm_h<<<dim3(gx,4), 256, 0, stream>>>(hh, cW1 + l*dgC*dgC2,
                                                  cb1 + l*dgC2, (const float*)0,
                                                  (const void*)0, z,
                                                  dgN, dgC, dgC2, 0, 0, af);
      dg35_colstats<<<128, 256, 0, stream>>>(z, st1, dgN, dgC2, af);
    }
    dg35_fin<<<1, 256, 0, stream>>>(st1, cg1 + l*dgC2, cbb1 + l*dgC2,
                                    ab1, 1.f/dgN, dgC2);
    if (af){
      dg35_gemmx<<<dim3(gmx,2), 256, 0, stream>>>((const float*)z,
                                                  Wt2h + l*32768, Wt2l + l*32768,
                                                  cb2 + l*dgC, ab1,
                                                  (l==0) ? (const float*)0 : (const float*)h,
                                                  (float*)h, dgN, dgC2, dgC, 1, (l==0)?0:1);
    } else {
      dg35_gemm_h<<<dim3(gx,2), 256, 0, stream>>>(z, cW2 + l*dgC2*dgC,
                                                  cb2 + l*dgC, ab1, h, h,
                                                  dgN, dgC2, dgC, 1, (l==0)?0:1, af);
    }
  }
  // final BN + global_add_pool
  hipMemsetAsync(stH, 0, sizeof(float)*2*dgC, stream);
  if (af) dg35_cs4<<<768, 256, 0, stream>>>((const float*)h, stH, dgN, dgC);
  else    dg35_colstats<<<128, 256, 0, stream>>>(h, stH, dgN, dgC, af);
  dg35_fin<<<1, 256, 0, stream>>>(stH, ng + 6*dgC, nb + 6*dgC, abh, 1.f/dgN, dgC);
  if (af) dg35_out4<<<dgG, 128, 0, stream>>>((const float*)h, abh, gs, out);
  else    dg35_out<<<dgG, dgC, 0, stream>>>(h, abh, gs, out, af);
}

// Round 10
// 2348.462 us; speedup vs baseline: 1.5271x; 1.3615x over previous
//
#include <hip/hip_runtime.h>

typedef unsigned short dg35_u16;
typedef unsigned int   dg35_u32;

constexpr int dgN  = 50000;
constexpr int dgE  = 400000;
constexpr int dgG  = 1024;
constexpr int dgC  = 128;
constexpr int dgC2 = 256;

typedef __attribute__((ext_vector_type(8))) short dg35_s8v;   // 8 bf16 (4 VGPR)
typedef __attribute__((ext_vector_type(4))) float dg35_f4v;   // MFMA acc

__device__ __forceinline__ float dg35_bf2f(dg35_u16 u){
  return __uint_as_float(((dg35_u32)u) << 16);
}
__device__ __forceinline__ dg35_u16 dg35_f2bf(float f){
  dg35_u32 u = __float_as_uint(f);
  u += 0x7FFFu + ((u >> 16) & 1u);
  return (dg35_u16)(u >> 16);
}
__device__ __forceinline__ float dg35_ldx(const void* p, size_t i, int af){
  return af ? ((const float*)p)[i] : dg35_bf2f(((const dg35_u16*)p)[i]);
}
__device__ __forceinline__ void dg35_stx(void* p, size_t i, int af, float v){
  if (af) ((float*)p)[i] = v; else ((dg35_u16*)p)[i] = dg35_f2bf(v);
}

// Symbol from the harness template; kept but never launched.
__global__ void DeeperGCN_35820027248884_kernel(){}

// ---------------- CSR build ----------------
__global__ void dg35_count(const int* __restrict__ dst, int* __restrict__ deg, int e){
  int j = blockIdx.x*256 + threadIdx.x;
  if (j < e) atomicAdd(&deg[dst[j]], 1);
}

__global__ void dg35_s1(const int* __restrict__ deg, int* __restrict__ bsum, int n){
  __shared__ int sm[256];
  int t = threadIdx.x, b = blockIdx.x;
  int idx = b*256 + t;
  sm[t] = (idx < n) ? deg[idx] : 0;
  __syncthreads();
  for (int s = 128; s > 0; s >>= 1){
    if (t < s) sm[t] += sm[t+s];
    __syncthreads();
  }
  if (t == 0) bsum[b] = sm[0];
}

__global__ void dg35_s2(const int* __restrict__ bsum, int* __restrict__ boff, int nb){
  __shared__ int sm[256];
  int t = threadIdx.x;
  int v = (t < nb) ? bsum[t] : 0;
  sm[t] = v;
  __syncthreads();
  for (int s = 1; s < 256; s <<= 1){
    int u = (t >= s) ? sm[t-s] : 0;
    __syncthreads();
    sm[t] += u;
    __syncthreads();
  }
  if (t < nb) boff[t] = sm[t] - v;
}

__global__ void dg35_s3(const int* __restrict__ deg, const int* __restrict__ boff,
                        int* __restrict__ off, int* __restrict__ cur, int n){
  __shared__ int sm[256];
  int t = threadIdx.x, b = blockIdx.x;
  int idx = b*256 + t;
  int v = (idx < n) ? deg[idx] : 0;
  sm[t] = v;
  __syncthreads();
  for (int s = 1; s < 256; s <<= 1){
    int u = (t >= s) ? sm[t-s] : 0;
    __syncthreads();
    sm[t] += u;
    __syncthreads();
  }
  if (idx < n){
    int e = boff[b] + sm[t] - v;
    off[idx] = e; cur[idx] = e;
  }
  if (idx == 0) off[n] = dgE;
}

__global__ void dg35_scatter(const int* __restrict__ ei, const int* __restrict__ ea,
                             int* __restrict__ cur, dg35_u32* __restrict__ packed, int e){
  int j = blockIdx.x*256 + threadIdx.x;
  if (j >= e) return;
  int s = ei[j], d = ei[e + j];
  dg35_u32 a0 = (dg35_u32)ea[3*j], a1 = (dg35_u32)ea[3*j+1], a2 = (dg35_u32)ea[3*j+2];
  int pos = atomicAdd(&cur[d], 1);
  packed[pos] = (dg35_u32)s | (a0<<17) | (a1<<20) | (a2<<23);
}

__global__ void dg35_gstart(const int* __restrict__ batch, int* __restrict__ gs, int n, int g){
  int i = blockIdx.x*256 + threadIdx.x;
  if (i > g) return;
  if (i == g){ gs[i] = n; return; }
  int lo = 0, hi = n;
  while (lo < hi){ int mid = (lo+hi)>>1; if (batch[mid] < i) lo = mid+1; else hi = mid; }
  gs[i] = lo;
}

// ---------------- encoders / weight prep ----------------
__global__ __launch_bounds__(128)
void dg35_atom(const int* __restrict__ x, const float* __restrict__ aemb,
               const float* __restrict__ vne, void* __restrict__ h, int af){
  int i = blockIdx.x, c = threadIdx.x;
  float acc = vne[c];
  #pragma unroll
  for (int f = 0; f < 9; ++f){
    int idx = x[i*9 + f];
    acc += aemb[(f*128 + idx)*dgC + c];
  }
  dg35_stx(h, (size_t)i*dgC + c, af, acc);
}

__global__ void dg35_vninit(const float* __restrict__ vne, float* __restrict__ vn){
  int i = blockIdx.x*256 + threadIdx.x;
  if (i < dgG*dgC) vn[i] = vne[i & (dgC-1)];
}

// transpose+convert conv weights to SPLIT bf16 (hi+lo) in [l][n][k] layout
__global__ void dg35_wconv(const float* __restrict__ W1, const float* __restrict__ W2,
                           short* __restrict__ Wt1h, short* __restrict__ Wt1l,
                           short* __restrict__ Wt2h, short* __restrict__ Wt2l){
  int i = blockIdx.x*256 + threadIdx.x;
  constexpr int per = 7*256*128;
  float w;
  short* ph; short* pl; int oidx;
  if (i < per){
    int l = i >> 15;
    int rem = i & 32767;
    int n = rem >> 7;
    int k = rem & 127;
    w = W1[l*32768 + k*256 + n];
    ph = Wt1h; pl = Wt1l; oidx = i;
  } else {
    int j = i - per;
    int l = j >> 15;
    int rem = j & 32767;
    int n = rem >> 8;
    int k = rem & 255;
    w = W2[l*32768 + k*128 + n];
    ph = Wt2h; pl = Wt2l; oidx = j;
  }
  dg35_u16 hi = dg35_f2bf(w);
  float lo = w - dg35_bf2f(hi);
  ph[oidx] = (short)hi;
  pl[oidx] = (short)dg35_f2bf(lo);
}

__global__ void dg35_zero(float* a, float* b, float* c_, float* d){
  int t = threadIdx.x;
  if (t < 512) a[t] = 0.f;
  if (t < 256){ b[t]=0.f; c_[t]=0.f; d[t]=0.f; }
}
__global__ void dg35_zero2(float* a, float* b, float* c_){
  int t = threadIdx.x;
  if (t < 512) a[t] = 0.f;
  if (t < 256){ b[t]=0.f; c_[t]=0.f; }
}

// ------------- GENConv softmax aggregation: 1 wave/node, 2 ch/lane, fused +vn -------------
__global__ __launch_bounds__(256)
void dg35_gb2(const float* __restrict__ hin, const dg35_u32* __restrict__ packed,
              const int* __restrict__ off, const float* __restrict__ bemb,
              const float* __restrict__ vnb, const int* __restrict__ batch,
              float* __restrict__ hh){
  int i = blockIdx.x*4 + (threadIdx.x >> 6);
  if (i >= dgN) return;
  int c = (threadIdx.x & 63) * 2;
  int b0 = off[i], b1 = off[i+1];
  float2 self = *reinterpret_cast<const float2*>(hin + (size_t)i*dgC + c);
  if (vnb){
    float2 va = *reinterpret_cast<const float2*>(vnb + (size_t)batch[i]*dgC + c);
    self.x += va.x; self.y += va.y;
  }
  float m0 = -3.0e38f, m1 = -3.0e38f;
  float s0 = 0.f, s1 = 0.f, w0 = 0.f, w1 = 0.f;
  for (int p = b0; p < b1; ++p){
    dg35_u32 pk = packed[p];
    int src = (int)(pk & 0x1FFFFu);
    float2 hv = *reinterpret_cast<const float2*>(hin + (size_t)src*dgC + c);
    if (vnb){
      float2 vb = *reinterpret_cast<const float2*>(vnb + (size_t)batch[src]*dgC + c);
      hv.x += vb.x; hv.y += vb.y;
    }
    float2 e0 = *reinterpret_cast<const float2*>(bemb + ((pk>>17)&7)*dgC + c);
    float2 e1 = *reinterpret_cast<const float2*>(bemb + (8+((pk>>20)&7))*dgC + c);
    float2 e2 = *reinterpret_cast<const float2*>(bemb + (16+((pk>>23)&7))*dgC + c);
    float msg0 = fmaxf(hv.x + e0.x + e1.x + e2.x, 0.f) + 1e-7f;
    float msg1 = fmaxf(hv.y + e0.y + e1.y + e2.y, 0.f) + 1e-7f;
    float mn0 = fmaxf(m0, msg0), mn1 = fmaxf(m1, msg1);
    float sc0 = __expf(m0 - mn0), t0 = __expf(msg0 - mn0);
    float sc1 = __expf(m1 - mn1), t1 = __expf(msg1 - mn1);
    s0 = s0*sc0 + t0;  w0 = w0*sc0 + msg0*t0;  m0 = mn0;
    s1 = s1*sc1 + t1;  w1 = w1*sc1 + msg1*t1;  m1 = mn1;
  }
  float2 o;
  o.x = self.x + ((b1 > b0) ? (w0 / (s0 + 1e-16f)) : 0.f);
  o.y = self.y + ((b1 > b0) ? (w1 / (s1 + 1e-16f)) : 0.f);
  *reinterpret_cast<float2*>(hh + (size_t)i*dgC + c) = o;
}

// ---- split-bf16 MFMA GEMM, BM=64, prefetch, fused column stats ----
// grid = dim3(NC/64, ceil(M/64)); per block 64x64 C tile, 4 waves x (16 rows x 64 cols).
// Cout = act(A) @ W + bias (+res); st accumulates column sum / sumsq (BN stats).
__global__ __launch_bounds__(256)
void dg35_gemmx(const float* __restrict__ A, const short* __restrict__ Whi,
                const short* __restrict__ Wlo, const float* __restrict__ bias,
                const float* __restrict__ ab, const float* __restrict__ res,
                float* __restrict__ Cout, float* __restrict__ st,
                int M, int K, int NC, int trans, int addres){
  __shared__ short Ahi[64*64];   // 8 KB
  __shared__ short Alo[64*64];   // 8 KB
  int tid = threadIdx.x;
  int bm = blockIdx.y * 64;
  int bn = blockIdx.x * 64;
  int lane = tid & 63;
  int wv = tid >> 6;
  int l15 = lane & 15;
  int l4  = lane >> 4;
  dg35_f4v acc[4] = {};

  int r = tid >> 2;            // staging row 0..63
  int cq = (tid & 3) * 16;     // 16 f32 per thread
  int grow = bm + r;
  int swbase = cq >> 3;        // first 16B slot index (0..7)

  float4 va[4];
  {
    const float* ap = A + (size_t)grow*K + cq;
    if (grow < M){
      #pragma unroll
      for (int q2 = 0; q2 < 4; ++q2) va[q2] = *reinterpret_cast<const float4*>(ap + q2*4);
    } else {
      #pragma unroll
      for (int q2 = 0; q2 < 4; ++q2) va[q2] = make_float4(0.f,0.f,0.f,0.f);
    }
  }

  for (int k0 = 0; k0 < K; k0 += 64){
    // convert current tile -> swizzled split-bf16 LDS
    {
      float xv[16];
      #pragma unroll
      for (int q2 = 0; q2 < 4; ++q2){
        xv[q2*4+0]=va[q2].x; xv[q2*4+1]=va[q2].y;
        xv[q2*4+2]=va[q2].z; xv[q2*4+3]=va[q2].w;
      }
      if (trans){
        #pragma unroll
        for (int q2 = 0; q2 < 16; ++q2){
          int kk = k0 + cq + q2;
          xv[q2] = fmaxf(xv[q2]*ab[kk] + ab[K + kk], 0.f);
        }
      }
      #pragma unroll
      for (int g = 0; g < 2; ++g){
        uint4 wh, wl;
        unsigned* hp = (unsigned*)&wh;
        unsigned* lp = (unsigned*)&wl;
        #pragma unroll
        for (int d = 0; d < 4; ++d){
          float f0 = xv[g*8 + d*2], f1 = xv[g*8 + d*2 + 1];
          dg35_u16 h0 = dg35_f2bf(f0), h1 = dg35_f2bf(f1);
          dg35_u16 l0 = dg35_f2bf(f0 - dg35_bf2f(h0));
          dg35_u16 l1 = dg35_f2bf(f1 - dg35_bf2f(h1));
          hp[d] = (dg35_u32)h0 | ((dg35_u32)h1 << 16);
          lp[d] = (dg35_u32)l0 | ((dg35_u32)l1 << 16);
        }
        int slot = (swbase + g) ^ (r & 7);
        *reinterpret_cast<uint4*>(&Ahi[r*64 + slot*8]) = wh;
        *reinterpret_cast<uint4*>(&Alo[r*64 + slot*8]) = wl;
      }
    }
    __syncthreads();
    // prefetch next tile (overlaps with MFMA below)
    if (k0 + 64 < K && grow < M){
      const float* ap = A + (size_t)grow*K + k0 + 64 + cq;
      #pragma unroll
      for (int q2 = 0; q2 < 4; ++q2) va[q2] = *reinterpret_cast<const float4*>(ap + q2*4);
    }
    // MFMA over 2 K-steps of 32
    #pragma unroll
    for (int ks = 0; ks < 2; ++ks){
      dg35_s8v bh[4], bl[4];
      #pragma unroll
      for (int nf = 0; nf < 4; ++nf){
        int n = bn + nf*16 + l15;
        size_t wo = (size_t)n*K + k0 + ks*32 + l4*8;
        bh[nf] = *reinterpret_cast<const dg35_s8v*>(Whi + wo);
        bl[nf] = *reinterpret_cast<const dg35_s8v*>(Wlo + wo);
      }
      int row = wv*16 + l15;
      int slot = (ks*4 + l4) ^ (row & 7);
      dg35_s8v ah = *reinterpret_cast<const dg35_s8v*>(&Ahi[row*64 + slot*8]);
      dg35_s8v al = *reinterpret_cast<const dg35_s8v*>(&Alo[row*64 + slot*8]);
      #pragma unroll
      for (int nf = 0; nf < 4; ++nf){
        acc[nf] = __builtin_amdgcn_mfma_f32_16x16x32_bf16(ah, bh[nf], acc[nf], 0, 0, 0);
        acc[nf] = __builtin_amdgcn_mfma_f32_16x16x32_bf16(al, bh[nf], acc[nf], 0, 0, 0);
        acc[nf] = __builtin_amdgcn_mfma_f32_16x16x32_bf16(ah, bl[nf], acc[nf], 0, 0, 0);
      }
    }
    __syncthreads();
  }
  // epilogue: write + per-lane col partial stats
  float s[4] = {0.f,0.f,0.f,0.f}, q[4] = {0.f,0.f,0.f,0.f};
  #pragma unroll
  for (int e = 0; e < 4; ++e){
    int rr = bm + wv*16 + l4*4 + e;
    if (rr >= M) continue;
    #pragma unroll
    for (int nf = 0; nf < 4; ++nf){
      int cc = bn + nf*16 + l15;
      float v = acc[nf][e] + bias[cc];
      size_t idx = (size_t)rr*NC + cc;
      if (addres) v += res[idx];
      Cout[idx] = v;
      s[nf] += v; q[nf] += v*v;
    }
  }
  // reduce over l4 (lanes xor 16, 32), then across waves via LDS, then 1 atomic/col
  #pragma unroll
  for (int nf = 0; nf < 4; ++nf){
    s[nf] += __shfl_xor(s[nf], 16); s[nf] += __shfl_xor(s[nf], 32);
    q[nf] += __shfl_xor(q[nf], 16); q[nf] += __shfl_xor(q[nf], 32);
  }
  __syncthreads();
  float* red = (float*)Ahi;   // 512 floats scratch
  if (l4 == 0){
    #pragma unroll
    for (int nf = 0; nf < 4; ++nf){
      red[wv*128 + nf*16 + l15] = s[nf];
      red[wv*128 + 64 + nf*16 + l15] = q[nf];
    }
  }
  __syncthreads();
  if (tid < 64){
    float S = red[tid] + red[128+tid] + red[256+tid] + red[384+tid];
    float Q = red[64+tid] + red[192+tid] + red[320+tid] + red[448+tid];
    atomicAdd(&st[bn + tid], S);
    atomicAdd(&st[NC + bn + tid], Q);
  }
}

// -------- VALU GEMM (dual-precision) — tier-B fallback only --------
__global__ __launch_bounds__(256)
void dg35_gemm_h(const void* __restrict__ A, const float* __restrict__ W,
                 const float* __restrict__ bias, const float* __restrict__ ab,
                 const void* __restrict__ res, void* __restrict__ Cout,
                 int M, int K, int NC, int trans, int addres, int af){
  __shared__ float At[32][65];
  __shared__ float Bt[32][64];
  int bm = blockIdx.x * 64;
  int bn = blockIdx.y * 64;
  int tid = threadIdx.x;
  int tx = tid & 15, ty = tid >> 4;
  float acc[4][4];
  #pragma unroll
  for (int i2 = 0; i2 < 4; ++i2)
    #pragma unroll
    for (int j2 = 0; j2 < 4; ++j2) acc[i2][j2] = 0.f;

  for (int k0 = 0; k0 < K; k0 += 32){
    int r = tid >> 3;
    int kq = (tid & 7) * 4;
    #pragma unroll
    for (int half = 0; half < 2; ++half){
      int rr = r + half*32;
      int grow = bm + rr;
      float vv[4] = {0.f, 0.f, 0.f, 0.f};
      if (grow < M){
        if (af){
          float4 v4 = *reinterpret_cast<const float4*>((const float*)A + (size_t)grow*K + k0 + kq);
          vv[0] = v4.x; vv[1] = v4.y; vv[2] = v4.z; vv[3] = v4.w;
        } else {
          ushort4 v4 = *reinterpret_cast<const ushort4*>((const dg35_u16*)A + (size_t)grow*K + k0 + kq);
          vv[0] = dg35_bf2f(v4.x); vv[1] = dg35_bf2f(v4.y);
          vv[2] = dg35_bf2f(v4.z); vv[3] = dg35_bf2f(v4.w);
        }
      }
      #pragma unroll
      for (int i2 = 0; i2 < 4; ++i2){
        float xv = vv[i2];
        if (trans){
          int kk = k0 + kq + i2;
          xv = fmaxf(xv*ab[kk] + ab[K + kk], 0.f);
        }
        At[kq + i2][rr] = xv;
      }
    }
    {
      int kr = tid >> 3;
      int cq = (tid & 7) * 8;
      const float* wp = W + (size_t)(k0 + kr)*NC + bn + cq;
      #pragma unroll
      for (int i2 = 0; i2 < 8; ++i2) Bt[kr][cq + i2] = wp[i2];
    }
    __syncthreads();
    #pragma unroll
    for (int kk = 0; kk < 32; ++kk){
      float a4[4], b4[4];
      #pragma unroll
      for (int i2 = 0; i2 < 4; ++i2) a4[i2] = At[kk][ty*4 + i2];
      #pragma unroll
      for (int j2 = 0; j2 < 4; ++j2) b4[j2] = Bt[kk][tx*4 + j2];
      #pragma unroll
      for (int i2 = 0; i2 < 4; ++i2)
        #pragma unroll
        for (int j2 = 0; j2 < 4; ++j2)
          acc[i2][j2] += a4[i2]*b4[j2];
    }
    __syncthreads();
  }
  #pragma unroll
  for (int i2 = 0; i2 < 4; ++i2){
    int rr = bm + ty*4 + i2;
    if (rr >= M) continue;
    #pragma unroll
    for (int j2 = 0; j2 < 4; ++j2){
      int cc = bn + tx*4 + j2;
      float v = acc[i2][j2] + bias[cc];
      size_t idx = (size_t)rr*NC + cc;
      if (addres) v += dg35_ldx(res, idx, af);
      dg35_stx(Cout, idx, af, v);
    }
  }
}

// -------- GEMM, A f32, W f32, f32 out (virtual-node MLP, M=1024) --------
__global__ __launch_bounds__(256)
void dg35_gemm_v(const float* __restrict__ A, const float* __restrict__ W,
                 const float* __restrict__ bias, const float* __restrict__ ab,
                 float* __restrict__ Cout, int M, int K, int NC, int trans){
  __shared__ float At[32][65];
  __shared__ float Bt[32][64];
  int bm = blockIdx.x * 64;
  int bn = blockIdx.y * 64;
  int tid = threadIdx.x;
  int tx = tid & 15, ty = tid >> 4;
  float acc[4][4];
  #pragma unroll
  for (int i2 = 0; i2 < 4; ++i2)
    #pragma unroll
    for (int j2 = 0; j2 < 4; ++j2) acc[i2][j2] = 0.f;

  for (int k0 = 0; k0 < K; k0 += 32){
    int r = tid >> 3;
    int kq = (tid & 7) * 4;
    #pragma unroll
    for (int half = 0; half < 2; ++half){
      int rr = r + half*32;
      int grow = bm + rr;
      float vv[4] = {0.f, 0.f, 0.f, 0.f};
      if (grow < M){
        float4 v4 = *reinterpret_cast<const float4*>(A + (size_t)grow*K + k0 + kq);
        vv[0] = v4.x; vv[1] = v4.y; vv[2] = v4.z; vv[3] = v4.w;
      }
      #pragma unroll
      for (int i2 = 0; i2 < 4; ++i2){
        float xv = vv[i2];
        if (trans){
          int kk = k0 + kq + i2;
          xv = fmaxf(xv*ab[kk] + ab[K + kk], 0.f);
        }
        At[kq + i2][rr] = xv;
      }
    }
    {
      int kr = tid >> 3;
      int cq = (tid & 7) * 8;
      const float* wp = W + (size_t)(k0 + kr)*NC + bn + cq;
      #pragma unroll
      for (int i2 = 0; i2 < 8; ++i2) Bt[kr][cq + i2] = wp[i2];
    }
    __syncthreads();
    #pragma unroll
    for (int kk = 0; kk < 32; ++kk){
      float a4[4], b4[4];
      #pragma unroll
      for (int i2 = 0; i2 < 4; ++i2) a4[i2] = At[kk][ty*4 + i2];
      #pragma unroll
      for (int j2 = 0; j2 < 4; ++j2) b4[j2] = Bt[kk][tx*4 + j2];
      #pragma unroll
      for (int i2 = 0; i2 < 4; ++i2)
        #pragma unroll
        for (int j2 = 0; j2 < 4; ++j2)
          acc[i2][j2] += a4[i2]*b4[j2];
    }
    __syncthreads();
  }
  #pragma unroll
  for (int i2 = 0; i2 < 4; ++i2){
    int rr = bm + ty*4 + i2;
    if (rr >= M) continue;
    #pragma unroll
    for (int j2 = 0; j2 < 4; ++j2){
      int cc = bn + tx*4 + j2;
      Cout[(size_t)rr*NC + cc] = acc[i2][j2] + bias[cc];
    }
  }
}

// ---------------- BN statistics (small f32 buffers: zv1/zv2) ----------------
__global__ __launch_bounds__(256)
void dg35_cs4(const float* __restrict__ Z, float* __restrict__ st, int n, int ncols){
  int t = threadIdx.x;
  int lpr = ncols >> 2;
  int rl = t / lpr;
  int rpb = 256 / lpr;
  int cq = (t - rl*lpr) * 4;
  float4 s = make_float4(0.f,0.f,0.f,0.f);
  float4 q = make_float4(0.f,0.f,0.f,0.f);
  for (int rr = blockIdx.x*rpb + rl; rr < n; rr += gridDim.x*rpb){
    float4 v = *reinterpret_cast<const float4*>(Z + (size_t)rr*ncols + cq);
    s.x += v.x; s.y += v.y; s.z += v.z; s.w += v.w;
    q.x += v.x*v.x; q.y += v.y*v.y; q.z += v.z*v.z; q.w += v.w*v.w;
  }
  __shared__ float sm[256*8];
  float* my = &sm[t*8];
  my[0]=s.x; my[1]=s.y; my[2]=s.z; my[3]=s.w;
  my[4]=q.x; my[5]=q.y; my[6]=q.z; my[7]=q.w;
  __syncthreads();
  if (rl == 0){
    float a[8];
    #pragma unroll
    for (int d = 0; d < 8; ++d) a[d] = my[d];
    for (int j = 1; j < rpb; ++j){
      const float* o2 = &sm[(t + j*lpr)*8];
      #pragma unroll
      for (int d = 0; d < 8; ++d) a[d] += o2[d];
    }
    #pragma unroll
    for (int d = 0; d < 4; ++d) atomicAdd(&st[cq + d], a[d]);
    #pragma unroll
    for (int d = 0; d < 4; ++d) atomicAdd(&st[ncols + cq + d], a[4 + d]);
  }
}

// tier-B fallback colstats
__global__ void dg35_colstats(const void* __restrict__ Z, float* __restrict__ st,
                              int n, int ncols, int af){
  int tid = threadIdx.x;
  int c = tid & (ncols - 1);
  int rl = tid / ncols;
  int rpb = 256 / ncols;
  float s = 0.f, q = 0.f;
  for (int rr = blockIdx.x*rpb + rl; rr < n; rr += gridDim.x*rpb){
    float v = dg35_ldx(Z, (size_t)rr*ncols + c, af);
    s += v; q += v*v;
  }
  atomicAdd(&st[c], s);
  atomicAdd(&st[ncols + c], q);
}

__global__ void dg35_fin(const float* __restrict__ st, const float* __restrict__ g,
                         const float* __restrict__ b, float* __restrict__ ab,
                         float inv_n, int ncols){
  int c = threadIdx.x + blockIdx.x*256;
  if (c >= ncols) return;
  float m = st[c]*inv_n;
  float var = st[ncols + c]*inv_n - m*m;
  float rstd = rsqrtf(var + 1e-5f);
  float a = g[c]*rstd;
  ab[c] = a;
  ab[ncols + c] = b[c] - m*a;
}

// ---------------- elementwise / segment ops ----------------
__global__ void dg35_h24(const float* __restrict__ h, const float* __restrict__ ab,
                         float* __restrict__ h2){
  int i = blockIdx.x*256 + threadIdx.x;     // float4 index
  int c = (i & 31) * 4;
  float4 v = reinterpret_cast<const float4*>(h)[i];
  v.x = fmaxf(v.x*ab[c+0] + ab[dgC+c+0], 0.f);
  v.y = fmaxf(v.y*ab[c+1] + ab[dgC+c+1], 0.f);
  v.z = fmaxf(v.z*ab[c+2] + ab[dgC+c+2], 0.f);
  v.w = fmaxf(v.w*ab[c+3] + ab[dgC+c+3], 0.f);
  reinterpret_cast<float4*>(h2)[i] = v;
}

__global__ void dg35_h2(const void* __restrict__ h, const float* __restrict__ ab,
                        void* __restrict__ h2, int af){
  int i = blockIdx.x*256 + threadIdx.x;
  int c = i & (dgC-1);
  dg35_stx(h2, i, af, fmaxf(dg35_ldx(h, i, af)*ab[c] + ab[dgC + c], 0.f));
}

__global__ __launch_bounds__(128)
void dg35_vt4(const float* __restrict__ h2, const float* __restrict__ vn,
              const int* __restrict__ gs, float* __restrict__ vt){
  int g = blockIdx.x, t = threadIdx.x;
  int rl = t >> 5, cl = t & 31;
  int cq = cl*4;
  int r0 = gs[g], r1 = gs[g+1];
  float4 s = make_float4(0.f,0.f,0.f,0.f);
  for (int rr = r0 + rl; rr < r1; rr += 4){
    float4 v = *reinterpret_cast<const float4*>(h2 + (size_t)rr*dgC + cq);
    s.x += v.x; s.y += v.y; s.z += v.z; s.w += v.w;
  }
  __shared__ float4 sm[128];
  sm[t] = s;
  __syncthreads();
  if (rl == 0){
    float4 a = sm[cl], b = sm[32+cl], c4 = sm[64+cl], d = sm[96+cl];
    float4 vb = *reinterpret_cast<const float4*>(vn + (size_t)g*dgC + cq);
    float4 o;
    o.x = a.x+b.x+c4.x+d.x + vb.x;
    o.y = a.y+b.y+c4.y+d.y + vb.y;
    o.z = a.z+b.z+c4.z+d.z + vb.z;
    o.w = a.w+b.w+c4.w+d.w + vb.w;
    *reinterpret_cast<float4*>(vt + (size_t)g*dgC + cq) = o;
  }
}

__global__ __launch_bounds__(128)
void dg35_vt(const void* __restrict__ h2, const float* __restrict__ vn,
             const int* __restrict__ gs, float* __restrict__ vt, int af){
  int g = blockIdx.x, c = threadIdx.x;
  float s = 0.f;
  int r0 = gs[g], r1 = gs[g+1];
  for (int rr = r0; rr < r1; ++rr) s += dg35_ldx(h2, (size_t)rr*dgC + c, af);
  vt[g*dgC + c] = s + vn[g*dgC + c];
}

__global__ void dg35_vnfin(const float* __restrict__ z2, const float* __restrict__ ab,
                           float* __restrict__ vn){
  int i = blockIdx.x*256 + threadIdx.x;
  int c = i & (dgC-1);
  vn[i] = fmaxf(z2[i]*ab[c] + ab[dgC + c], 0.f);
}

__global__ __launch_bounds__(128)
void dg35_addvn(void* __restrict__ h2, const float* __restrict__ vn,
                const int* __restrict__ batch, int af){
  int i = blockIdx.x, c = threadIdx.x;
  size_t idx = (size_t)i*dgC + c;
  dg35_stx(h2, idx, af, dg35_ldx(h2, idx, af) + vn[batch[i]*dgC + c]);
}

__global__ __launch_bounds__(128)
void dg35_out4(const float* __restrict__ h, const float* __restrict__ ab,
               const int* __restrict__ gs, float* __restrict__ out){
  int g = blockIdx.x, t = threadIdx.x;
  int rl = t >> 5, cl = t & 31;
  int cq = cl*4;
  int r0 = gs[g], r1 = gs[g+1];
  float4 s = make_float4(0.f,0.f,0.f,0.f);
  for (int rr = r0 + rl; rr < r1; rr += 4){
    float4 v = *reinterpret_cast<const float4*>(h + (size_t)rr*dgC + cq);
    s.x += v.x; s.y += v.y; s.z += v.z; s.w += v.w;
  }
  __shared__ float4 sm[128];
  sm[t] = s;
  __syncthreads();
  if (rl == 0){
    float4 a4 = sm[cl], b4 = sm[32+cl], c4 = sm[64+cl], d4 = sm[96+cl];
    float cnt = (float)(r1 - r0);
    float4 o;
    float S;
    S = a4.x+b4.x+c4.x+d4.x; o.x = ab[cq+0]*S + ab[dgC+cq+0]*cnt;
    S = a4.y+b4.y+c4.y+d4.y; o.y = ab[cq+1]*S + ab[dgC+cq+1]*cnt;
    S = a4.z+b4.z+c4.z+d4.z; o.z = ab[cq+2]*S + ab[dgC+cq+2]*cnt;
    S = a4.w+b4.w+c4.w+d4.w; o.w = ab[cq+3]*S + ab[dgC+cq+3]*cnt;
    *reinterpret_cast<float4*>(out + (size_t)g*dgC + cq) = o;
  }
}

// tier-B fallback pieces
__global__ __launch_bounds__(128)
void dg35_gb(const void* __restrict__ hin, const dg35_u32* __restrict__ packed,
             const int* __restrict__ off, const float* __restrict__ bemb,
             void* __restrict__ hh, int af){
  int i = blockIdx.x, c = threadIdx.x;
  int b0 = off[i], b1 = off[i+1];
  float m = -3.0e38f, s = 0.f, w = 0.f;
  for (int p = b0; p < b1; ++p){
    dg35_u32 pk = packed[p];
    int src = (int)(pk & 0x1FFFFu);
    float e = bemb[((pk>>17)&7)*dgC + c] + bemb[(8+((pk>>20)&7))*dgC + c]
            + bemb[(16+((pk>>23)&7))*dgC + c];
    float msg = fmaxf(dg35_ldx(hin, (size_t)src*dgC + c, af) + e, 0.f) + 1e-7f;
    float mn = fmaxf(m, msg);
    float sc = __expf(m - mn), t2 = __expf(msg - mn);
    s = s*sc + t2; w = w*sc + msg*t2; m = mn;
  }
  float agg = (b1 > b0) ? (w / (s + 1e-16f)) : 0.f;
  float self = dg35_ldx(hin, (size_t)i*dgC + c, af);
  dg35_stx(hh, (size_t)i*dgC + c, af, self + agg);
}

__global__ __launch_bounds__(128)
void dg35_out(const void* __restrict__ h, const float* __restrict__ ab,
              const int* __restrict__ gs, float* __restrict__ out, int af){
  int g = blockIdx.x, c = threadIdx.x;
  float a = ab[c], b = ab[dgC + c];
  float s = 0.f;
  int r0 = gs[g], r1 = gs[g+1];
  for (int rr = r0; rr < r1; ++rr) s += dg35_ldx(h, (size_t)rr*dgC + c, af)*a + b;
  out[g*dgC + c] = s;
}

static inline size_t dg35_al(size_t x){ return (x + 255) & ~(size_t)255; }

extern "C" void kernel_launch(void* const* d_in, const int* in_sizes, int n_in,
                              void* d_out, int out_size, void* d_ws, size_t ws_size,
                              hipStream_t stream)
{
  const int*   x     = (const int*)d_in[0];
  const int*   eattr = (const int*)d_in[1];
  const int*   eidx  = (const int*)d_in[2];
  const int*   batch = (const int*)d_in[3];
  const float* aemb  = (const float*)d_in[4];
  const float* bemb  = (const float*)d_in[5];
  const float* vne   = (const float*)d_in[6];
  const float* cW1   = (const float*)d_in[7];
  const float* cb1   = (const float*)d_in[8];
  const float* cg1   = (const float*)d_in[9];
  const float* cbb1  = (const float*)d_in[10];
  const float* cW2   = (const float*)d_in[11];
  const float* cb2   = (const float*)d_in[12];
  const float* ng    = (const float*)d_in[13];
  const float* nb    = (const float*)d_in[14];
  const float* vW1   = (const float*)d_in[15];
  const float* vb1   = (const float*)d_in[16];
  const float* vg1   = (const float*)d_in[17];
  const float* vbb1  = (const float*)d_in[18];
  const float* vW2   = (const float*)d_in[19];
  const float* vb2   = (const float*)d_in[20];
  const float* vg2   = (const float*)d_in[21];
  const float* vbb2  = (const float*)d_in[22];
  float* out = (float*)d_out;

  const int nsb = (dgN + 255) / 256;

  const size_t fixed =
      dg35_al(dgG*dgC*4)*4 +
      dg35_al(2*dgC2*4)*2 +
      dg35_al(2*dgC*4)*6 +
      dg35_al(dgN*4)*2 + dg35_al((dgN+1)*4) +
      dg35_al((dgG+1)*4) +
      dg35_al((size_t)dgE*4) +
      dg35_al(7*256*128*2)*4 +
      dg35_al(256*4)*2;
  int af = 0;
  size_t esz = 2;
  {
    size_t bigf = dg35_al((size_t)dgN*dgC*4)*2 + dg35_al((size_t)dgN*dgC2*4);
    if (bigf + fixed <= ws_size){ af = 1; esz = 4; }
  }

  char* base = (char*)d_ws;
  size_t o = 0;
  void* h  = (void*)(base + o); o += dg35_al((size_t)dgN*dgC*esz);
  void* hh = (void*)(base + o); o += dg35_al((size_t)dgN*dgC*esz);
  void* zb = (void*)(base + o); o += dg35_al((size_t)dgN*dgC2*esz);
  float* vn   = (float*)(base + o); o += dg35_al(dgG*dgC*4);
  float* vt   = (float*)(base + o); o += dg35_al(dgG*dgC*4);
  float* zv1  = (float*)(base + o); o += dg35_al(dgG*dgC*4);
  float* zv2  = (float*)(base + o); o += dg35_al(dgG*dgC*4);
  float* st1  = (float*)(base + o); o += dg35_al(2*dgC2*4);
  float* ab1  = (float*)(base + o); o += dg35_al(2*dgC2*4);
  float* stH  = (float*)(base + o); o += dg35_al(2*dgC*4);
  float* stV1 = (float*)(base + o); o += dg35_al(2*dgC*4);
  float* stV2 = (float*)(base + o); o += dg35_al(2*dgC*4);
  float* abh  = (float*)(base + o); o += dg35_al(2*dgC*4);
  float* abv1 = (float*)(base + o); o += dg35_al(2*dgC*4);
  float* abv2 = (float*)(base + o); o += dg35_al(2*dgC*4);
  int* deg = (int*)(base + o); o += dg35_al(dgN*4);
  int* cur = (int*)(base + o); o += dg35_al(dgN*4);
  int* off = (int*)(base + o); o += dg35_al((dgN+1)*4);
  int* gs  = (int*)(base + o); o += dg35_al((dgG+1)*4);
  dg35_u32* packed = (dg35_u32*)(base + o); o += dg35_al((size_t)dgE*4);
  short* Wt1h = (short*)(base + o); o += dg35_al(7*256*128*2);
  short* Wt1l = (short*)(base + o); o += dg35_al(7*256*128*2);
  short* Wt2h = (short*)(base + o); o += dg35_al(7*256*128*2);
  short* Wt2l = (short*)(base + o); o += dg35_al(7*256*128*2);
  int* bsum = (int*)(base + o); o += dg35_al(256*4);
  int* boff = (int*)(base + o); o += dg35_al(256*4);

  if (o > ws_size){
    hipMemsetAsync(d_out, 0x7F, (size_t)out_size*4, stream);
    return;
  }
  void* h2 = zb;
  void* z  = zb;

  // ---- per-call setup ----
  hipMemsetAsync(deg, 0, sizeof(int)*dgN, stream);
  dg35_count  <<<(dgE+255)/256, 256, 0, stream>>>(eidx + dgE, deg, dgE);
  dg35_s1     <<<nsb, 256, 0, stream>>>(deg, bsum, dgN);
  dg35_s2     <<<1, 256, 0, stream>>>(bsum, boff, nsb);
  dg35_s3     <<<nsb, 256, 0, stream>>>(deg, boff, off, cur, dgN);
  dg35_scatter<<<(dgE+255)/256, 256, 0, stream>>>(eidx, eattr, cur, packed, dgE);
  dg35_gstart <<<(dgG+256)/256, 256, 0, stream>>>(batch, gs, dgN, dgG);
  dg35_atom   <<<dgN, dgC, 0, stream>>>(x, aemb, vne, h, af);
  dg35_vninit <<<(dgG*dgC)/256, 256, 0, stream>>>(vne, vn);
  dg35_wconv  <<<1792, 256, 0, stream>>>(cW1, cW2, Wt1h, Wt1l, Wt2h, Wt2l);

  if (af){
    const int grb = (dgN + 63) / 64;   // 782 row-blocks
    for (int l = 0; l < 7; ++l){
      const float* hin = (const float*)h;
      const float* vnb = nullptr;
      if (l > 0){
        // stH was accumulated by previous layer's gemm2
        dg35_fin<<<1, 256, 0, stream>>>(stH, ng + (l-1)*dgC, nb + (l-1)*dgC,
                                        abh, 1.f/dgN, dgC);
        dg35_zero2<<<1, 512, 0, stream>>>(st1, stV1, stV2);
        dg35_h24<<<(dgN*dgC/4)/256, 256, 0, stream>>>((const float*)h, abh, (float*)h2);
        dg35_vt4<<<dgG, 128, 0, stream>>>((const float*)h2, vn, gs, vt);
        dg35_gemm_v<<<dim3(16,2), 256, 0, stream>>>(vt, vW1 + (l-1)*dgC*dgC,
                                                    vb1 + (l-1)*dgC, (const float*)0,
                                                    zv1, dgG, dgC, dgC, 0);
        dg35_cs4<<<64, 256, 0, stream>>>(zv1, stV1, dgG, dgC);
        dg35_fin<<<1, 256, 0, stream>>>(stV1, vg1 + (l-1)*dgC, vbb1 + (l-1)*dgC,
                                        abv1, 1.f/dgG, dgC);
        dg35_gemm_v<<<dim3(16,2), 256, 0, stream>>>(zv1, vW2 + (l-1)*dgC*dgC,
                                                    vb2 + (l-1)*dgC, abv1,
                                                    zv2, dgG, dgC, dgC, 1);
        dg35_cs4<<<64, 256, 0, stream>>>(zv2, stV2, dgG, dgC);
        dg35_fin<<<1, 256, 0, stream>>>(stV2, vg2 + (l-1)*dgC, vbb2 + (l-1)*dgC,
                                        abv2, 1.f/dgG, dgC);
        dg35_vnfin<<<(dgG*dgC)/256, 256, 0, stream>>>(zv2, abv2, vn);
        hin = (const float*)h2;
        vnb = vn;   // +vn fused into gb2
      } else {
        dg35_zero2<<<1, 512, 0, stream>>>(st1, stV1, stV2);
      }
      dg35_gb2<<<(dgN+3)/4, 256, 0, stream>>>(hin, packed, off, bemb, vnb, batch, (float*)hh);
      dg35_gemmx<<<dim3(4, grb), 256, 0, stream>>>((const float*)hh,
                                                   Wt1h + l*32768, Wt1l + l*32768,
                                                   cb1 + l*dgC2, (const float*)0,
                                                   (const float*)0, (float*)z, st1,
                                                   dgN, dgC, dgC2, 0, 0);
      dg35_fin<<<1, 256, 0, stream>>>(st1, cg1 + l*dgC2, cbb1 + l*dgC2,
                                      ab1, 1.f/dgN, dgC2);
      hipMemsetAsync(stH, 0, sizeof(float)*2*dgC, stream);
      dg35_gemmx<<<dim3(2, grb), 256, 0, stream>>>((const float*)z,
                                                   Wt2h + l*32768, Wt2l + l*32768,
                                                   cb2 + l*dgC, ab1,
                                                   (l==0) ? (const float*)0 : (const float*)h,
                                                   (float*)h, stH,
                                                   dgN, dgC2, dgC, 1, (l==0)?0:1);
    }
    // final BN (stats already in stH from last gemm2) + global_add_pool
    dg35_fin<<<1, 256, 0, stream>>>(stH, ng + 6*dgC, nb + 6*dgC, abh, 1.f/dgN, dgC);
    dg35_out4<<<dgG, 128, 0, stream>>>((const float*)h, abh, gs, out);
  } else {
    // tier-B fallback (bf16 storage, VALU GEMM) — unchanged round-5 flow
    const int gx = (dgN + 63) / 64;
    for (int l = 0; l < 7; ++l){
      dg35_zero<<<1, 512, 0, stream>>>(st1, stH, stV1, stV2);
      const void* hin = h;
      if (l > 0){
        dg35_colstats<<<128, 256, 0, stream>>>(h, stH, dgN, dgC, af);
        dg35_fin<<<1, 256, 0, stream>>>(stH, ng + (l-1)*dgC, nb + (l-1)*dgC,
                                        abh, 1.f/dgN, dgC);
        dg35_h2<<<(dgN*dgC)/256, 256, 0, stream>>>(h, abh, h2, af);
        dg35_vt<<<dgG, dgC, 0, stream>>>(h2, vn, gs, vt, af);
        dg35_gemm_v<<<dim3(16,2), 256, 0, stream>>>(vt, vW1 + (l-1)*dgC*dgC,
                                                    vb1 + (l-1)*dgC, (const float*)0,
                                                    zv1, dgG, dgC, dgC, 0);
        dg35_cs4<<<64, 256, 0, stream>>>(zv1, stV1, dgG, dgC);
        dg35_fin<<<1, 256, 0, stream>>>(stV1, vg1 + (l-1)*dgC, vbb1 + (l-1)*dgC,
                                        abv1, 1.f/dgG, dgC);
        dg35_gemm_v<<<dim3(16,2), 256, 0, stream>>>(zv1, vW2 + (l-1)*dgC*dgC,
                                                    vb2 + (l-1)*dgC, abv1,
                                                    zv2, dgG, dgC, dgC, 1);
        dg35_cs4<<<64, 256, 0, stream>>>(zv2, stV2, dgG, dgC);
        dg35_fin<<<1, 256, 0, stream>>>(stV2, vg2 + (l-1)*dgC, vbb2 + (l-1)*dgC,
                                        abv2, 1.f/dgG, dgC);
        dg35_vnfin<<<(dgG*dgC)/256, 256, 0, stream>>>(zv2, abv2, vn);
        dg35_addvn<<<dgN, dgC, 0, stream>>>(h2, vn, batch, af);
        hin = h2;
      }
      dg35_gb<<<dgN, dgC, 0, stream>>>(hin, packed, off, bemb, hh, af);
      dg35_gemm_h<<<dim3(gx,4), 256, 0, stream>>>(hh, cW1 + l*dgC*dgC2,
                                                  cb1 + l*dgC2, (const float*)0,
                                                  (const void*)0, z,
                                                  dgN, dgC, dgC2, 0, 0, af);
      dg35_colstats<<<128, 256, 0, stream>>>(z, st1, dgN, dgC2, af);
      dg35_fin<<<1, 256, 0, stream>>>(st1, cg1 + l*dgC2, cbb1 + l*dgC2,
                                      ab1, 1.f/dgN, dgC2);
      dg35_gemm_h<<<dim3(gx,2), 256, 0, stream>>>(z, cW2 + l*dgC2*dgC,
                                                  cb2 + l*dgC, ab1, h, h,
                                                  dgN, dgC2, dgC, 1, (l==0)?0:1, af);
    }
    hipMemsetAsync(stH, 0, sizeof(float)*2*dgC, stream);
    dg35_colstats<<<128, 256, 0, stream>>>(h, stH, dgN, dgC, af);
    dg35_fin<<<1, 256, 0, stream>>>(stH, ng + 6*dgC, nb + 6*dgC, abh, 1.f/dgN, dgC);
    dg35_out<<<dgG, dgC, 0, stream>>>(h, abh, gs, out, af);
  }
}

// Round 11
// 2019.224 us; speedup vs baseline: 1.7762x; 1.1631x over previous
//
#include <hip/hip_runtime.h>

typedef unsigned short dg35_u16;
typedef unsigned int   dg35_u32;

constexpr int dgN  = 50000;
constexpr int dgE  = 400000;
constexpr int dgG  = 1024;
constexpr int dgC  = 128;
constexpr int dgC2 = 256;

typedef __attribute__((ext_vector_type(8))) short dg35_s8v;   // 8 bf16 (4 VGPR)
typedef __attribute__((ext_vector_type(4))) float dg35_f4v;   // MFMA acc

__device__ __forceinline__ float dg35_bf2f(dg35_u16 u){
  return __uint_as_float(((dg35_u32)u) << 16);
}
__device__ __forceinline__ dg35_u16 dg35_f2bf(float f){
  dg35_u32 u = __float_as_uint(f);
  u += 0x7FFFu + ((u >> 16) & 1u);
  return (dg35_u16)(u >> 16);
}
__device__ __forceinline__ float dg35_ldx(const void* p, size_t i, int af){
  return af ? ((const float*)p)[i] : dg35_bf2f(((const dg35_u16*)p)[i]);
}
__device__ __forceinline__ void dg35_stx(void* p, size_t i, int af, float v){
  if (af) ((float*)p)[i] = v; else ((dg35_u16*)p)[i] = dg35_f2bf(v);
}

// Symbol from the harness template; kept but never launched.
__global__ void DeeperGCN_35820027248884_kernel(){}

// ---------------- CSR build ----------------
__global__ void dg35_count(const int* __restrict__ dst, int* __restrict__ deg, int e){
  int j = blockIdx.x*256 + threadIdx.x;
  if (j < e) atomicAdd(&deg[dst[j]], 1);
}

__global__ void dg35_s1(const int* __restrict__ deg, int* __restrict__ bsum, int n){
  __shared__ int sm[256];
  int t = threadIdx.x, b = blockIdx.x;
  int idx = b*256 + t;
  sm[t] = (idx < n) ? deg[idx] : 0;
  __syncthreads();
  for (int s = 128; s > 0; s >>= 1){
    if (t < s) sm[t] += sm[t+s];
    __syncthreads();
  }
  if (t == 0) bsum[b] = sm[0];
}

__global__ void dg35_s2(const int* __restrict__ bsum, int* __restrict__ boff, int nb){
  __shared__ int sm[256];
  int t = threadIdx.x;
  int v = (t < nb) ? bsum[t] : 0;
  sm[t] = v;
  __syncthreads();
  for (int s = 1; s < 256; s <<= 1){
    int u = (t >= s) ? sm[t-s] : 0;
    __syncthreads();
    sm[t] += u;
    __syncthreads();
  }
  if (t < nb) boff[t] = sm[t] - v;
}

__global__ void dg35_s3(const int* __restrict__ deg, const int* __restrict__ boff,
                        int* __restrict__ off, int* __restrict__ cur, int n){
  __shared__ int sm[256];
  int t = threadIdx.x, b = blockIdx.x;
  int idx = b*256 + t;
  int v = (idx < n) ? deg[idx] : 0;
  sm[t] = v;
  __syncthreads();
  for (int s = 1; s < 256; s <<= 1){
    int u = (t >= s) ? sm[t-s] : 0;
    __syncthreads();
    sm[t] += u;
    __syncthreads();
  }
  if (idx < n){
    int e = boff[b] + sm[t] - v;
    off[idx] = e; cur[idx] = e;
  }
  if (idx == 0) off[n] = dgE;
}

__global__ void dg35_scatter(const int* __restrict__ ei, const int* __restrict__ ea,
                             int* __restrict__ cur, dg35_u32* __restrict__ packed, int e){
  int j = blockIdx.x*256 + threadIdx.x;
  if (j >= e) return;
  int s = ei[j], d = ei[e + j];
  dg35_u32 a0 = (dg35_u32)ea[3*j], a1 = (dg35_u32)ea[3*j+1], a2 = (dg35_u32)ea[3*j+2];
  int pos = atomicAdd(&cur[d], 1);
  packed[pos] = (dg35_u32)s | (a0<<17) | (a1<<20) | (a2<<23);
}

__global__ void dg35_gstart(const int* __restrict__ batch, int* __restrict__ gs, int n, int g){
  int i = blockIdx.x*256 + threadIdx.x;
  if (i > g) return;
  if (i == g){ gs[i] = n; return; }
  int lo = 0, hi = n;
  while (lo < hi){ int mid = (lo+hi)>>1; if (batch[mid] < i) lo = mid+1; else hi = mid; }
  gs[i] = lo;
}

// ---------------- encoders / weight prep ----------------
__global__ __launch_bounds__(128)
void dg35_atom(const int* __restrict__ x, const float* __restrict__ aemb,
               const float* __restrict__ vne, void* __restrict__ h, int af){
  int i = blockIdx.x, c = threadIdx.x;
  float acc = vne[c];
  #pragma unroll
  for (int f = 0; f < 9; ++f){
    int idx = x[i*9 + f];
    acc += aemb[(f*128 + idx)*dgC + c];
  }
  dg35_stx(h, (size_t)i*dgC + c, af, acc);
}

__global__ void dg35_vninit(const float* __restrict__ vne, float* __restrict__ vn){
  int i = blockIdx.x*256 + threadIdx.x;
  if (i < dgG*dgC) vn[i] = vne[i & (dgC-1)];
}

// combo table: ecomb[c9][c] = bemb[a0][c] + bemb[8+a1][c] + bemb[16+a2][c]
__global__ __launch_bounds__(128)
void dg35_ecomb(const float* __restrict__ bemb, float* __restrict__ ecomb){
  int c9 = blockIdx.x, t = threadIdx.x;
  int a0 = c9 & 7, a1 = (c9 >> 3) & 7, a2 = (c9 >> 6) & 7;
  ecomb[c9*dgC + t] = bemb[a0*dgC + t] + bemb[(8+a1)*dgC + t] + bemb[(16+a2)*dgC + t];
}

// transpose+convert conv weights to SPLIT bf16 (hi+lo) in [l][n][k] layout
__global__ void dg35_wconv(const float* __restrict__ W1, const float* __restrict__ W2,
                           short* __restrict__ Wt1h, short* __restrict__ Wt1l,
                           short* __restrict__ Wt2h, short* __restrict__ Wt2l){
  int i = blockIdx.x*256 + threadIdx.x;
  constexpr int per = 7*256*128;
  float w;
  short* ph; short* pl; int oidx;
  if (i < per){
    int l = i >> 15;
    int rem = i & 32767;
    int n = rem >> 7;
    int k = rem & 127;
    w = W1[l*32768 + k*256 + n];
    ph = Wt1h; pl = Wt1l; oidx = i;
  } else {
    int j = i - per;
    int l = j >> 15;
    int rem = j & 32767;
    int n = rem >> 8;
    int k = rem & 255;
    w = W2[l*32768 + k*128 + n];
    ph = Wt2h; pl = Wt2l; oidx = j;
  }
  dg35_u16 hi = dg35_f2bf(w);
  float lo = w - dg35_bf2f(hi);
  ph[oidx] = (short)hi;
  pl[oidx] = (short)dg35_f2bf(lo);
}

__global__ void dg35_zero(float* a, float* b, float* c_, float* d){
  int t = threadIdx.x;
  if (t < 512) a[t] = 0.f;
  if (t < 256){ b[t]=0.f; c_[t]=0.f; d[t]=0.f; }
}
__global__ void dg35_zero2(float* a, float* b, float* c_){
  int t = threadIdx.x;
  if (t < 512) a[t] = 0.f;
  if (t < 256){ b[t]=0.f; c_[t]=0.f; }
}

// ------------- GENConv softmax aggr: 1 wave/node, 2 ch/lane, 2 edge streams, 1-exp update
__device__ __forceinline__ void dg35_osm(float& m, float& s, float& w, float msg){
  float d = msg - m;
  float e = __expf(-fabsf(d));
  bool gt = d > 0.f;
  s = gt ? s*e + 1.f   : s + e;
  w = gt ? w*e + msg   : w + msg*e;
  m = gt ? msg         : m;
}

__global__ __launch_bounds__(256)
void dg35_gb2(const float* __restrict__ hin, const dg35_u32* __restrict__ packed,
              const int* __restrict__ off, const float* __restrict__ ecomb,
              float* __restrict__ hh){
  int i = blockIdx.x*4 + (threadIdx.x >> 6);
  if (i >= dgN) return;
  int c = (threadIdx.x & 63) * 2;
  int b0 = off[i], b1 = off[i+1];
  float2 self = *reinterpret_cast<const float2*>(hin + (size_t)i*dgC + c);
  // stream A / stream B accumulators, 2 channels each
  float mA0=-3.0e38f, sA0=0.f, wA0=0.f, mA1=-3.0e38f, sA1=0.f, wA1=0.f;
  float mB0=-3.0e38f, sB0=0.f, wB0=0.f, mB1=-3.0e38f, sB1=0.f, wB1=0.f;
  int p = b0;
  for (; p + 1 < b1; p += 2){
    dg35_u32 pkA = packed[p], pkB = packed[p+1];
    int srcA = (int)(pkA & 0x1FFFFu), srcB = (int)(pkB & 0x1FFFFu);
    float2 hA = *reinterpret_cast<const float2*>(hin + (size_t)srcA*dgC + c);
    float2 hB = *reinterpret_cast<const float2*>(hin + (size_t)srcB*dgC + c);
    float2 eA = *reinterpret_cast<const float2*>(ecomb + (size_t)(pkA>>17)*dgC + c);
    float2 eB = *reinterpret_cast<const float2*>(ecomb + (size_t)(pkB>>17)*dgC + c);
    float msgA0 = fmaxf(hA.x + eA.x, 0.f) + 1e-7f;
    float msgA1 = fmaxf(hA.y + eA.y, 0.f) + 1e-7f;
    float msgB0 = fmaxf(hB.x + eB.x, 0.f) + 1e-7f;
    float msgB1 = fmaxf(hB.y + eB.y, 0.f) + 1e-7f;
    dg35_osm(mA0, sA0, wA0, msgA0);
    dg35_osm(mA1, sA1, wA1, msgA1);
    dg35_osm(mB0, sB0, wB0, msgB0);
    dg35_osm(mB1, sB1, wB1, msgB1);
  }
  if (p < b1){
    dg35_u32 pkA = packed[p];
    int srcA = (int)(pkA & 0x1FFFFu);
    float2 hA = *reinterpret_cast<const float2*>(hin + (size_t)srcA*dgC + c);
    float2 eA = *reinterpret_cast<const float2*>(ecomb + (size_t)(pkA>>17)*dgC + c);
    dg35_osm(mA0, sA0, wA0, fmaxf(hA.x + eA.x, 0.f) + 1e-7f);
    dg35_osm(mA1, sA1, wA1, fmaxf(hA.y + eA.y, 0.f) + 1e-7f);
  }
  // merge B into A (exp(-3e38 - finite) underflows to 0 -> empty streams are no-ops)
  float mn0 = fmaxf(mA0, mB0);
  float fA0 = __expf(mA0 - mn0), fB0 = __expf(mB0 - mn0);
  float s0 = sA0*fA0 + sB0*fB0, w0 = wA0*fA0 + wB0*fB0;
  float mn1 = fmaxf(mA1, mB1);
  float fA1 = __expf(mA1 - mn1), fB1 = __expf(mB1 - mn1);
  float s1 = sA1*fA1 + sB1*fB1, w1 = wA1*fA1 + wB1*fB1;
  float2 o;
  o.x = self.x + ((b1 > b0) ? (w0 / (s0 + 1e-16f)) : 0.f);
  o.y = self.y + ((b1 > b0) ? (w1 / (s1 + 1e-16f)) : 0.f);
  *reinterpret_cast<float2*>(hh + (size_t)i*dgC + c) = o;
}

// ---- split-bf16 MFMA GEMM, BM=64, prefetch, fused column stats, XCD chunk swizzle ----
__global__ __launch_bounds__(256)
void dg35_gemmx(const float* __restrict__ A, const short* __restrict__ Whi,
                const short* __restrict__ Wlo, const float* __restrict__ bias,
                const float* __restrict__ ab, const float* __restrict__ res,
                float* __restrict__ Cout, float* __restrict__ st,
                int M, int K, int NC, int trans, int addres){
  __shared__ short Ahi[64*64];   // 8 KB
  __shared__ short Alo[64*64];   // 8 KB
  int tid = threadIdx.x;
  // bijective XCD chunk swizzle (m204): HW round-robins lin%8 across XCDs;
  // remap so each XCD owns a contiguous row-block chunk (A-panel L2 locality).
  int nwg = gridDim.x * gridDim.y;
  int lin = blockIdx.y * gridDim.x + blockIdx.x;
  int q8 = nwg >> 3, r8 = nwg & 7;
  int xcd = lin & 7, pos = lin >> 3;
  int wg = (xcd < r8) ? (xcd*(q8+1) + pos) : (r8*(q8+1) + (xcd-r8)*q8 + pos);
  int bn = (wg % gridDim.x) * 64;
  int bm = (wg / gridDim.x) * 64;
  int lane = tid & 63;
  int wv = tid >> 6;
  int l15 = lane & 15;
  int l4  = lane >> 4;
  dg35_f4v acc[4] = {};

  int r = tid >> 2;
  int cq = (tid & 3) * 16;
  int grow = bm + r;
  int swbase = cq >> 3;

  float4 va[4];
  {
    const float* ap = A + (size_t)grow*K + cq;
    if (grow < M){
      #pragma unroll
      for (int q2 = 0; q2 < 4; ++q2) va[q2] = *reinterpret_cast<const float4*>(ap + q2*4);
    } else {
      #pragma unroll
      for (int q2 = 0; q2 < 4; ++q2) va[q2] = make_float4(0.f,0.f,0.f,0.f);
    }
  }

  for (int k0 = 0; k0 < K; k0 += 64){
    {
      float xv[16];
      #pragma unroll
      for (int q2 = 0; q2 < 4; ++q2){
        xv[q2*4+0]=va[q2].x; xv[q2*4+1]=va[q2].y;
        xv[q2*4+2]=va[q2].z; xv[q2*4+3]=va[q2].w;
      }
      if (trans){
        #pragma unroll
        for (int q2 = 0; q2 < 16; ++q2){
          int kk = k0 + cq + q2;
          xv[q2] = fmaxf(xv[q2]*ab[kk] + ab[K + kk], 0.f);
        }
      }
      #pragma unroll
      for (int g = 0; g < 2; ++g){
        uint4 wh, wl;
        unsigned* hp = (unsigned*)&wh;
        unsigned* lp = (unsigned*)&wl;
        #pragma unroll
        for (int d = 0; d < 4; ++d){
          float f0 = xv[g*8 + d*2], f1 = xv[g*8 + d*2 + 1];
          dg35_u16 h0 = dg35_f2bf(f0), h1 = dg35_f2bf(f1);
          dg35_u16 l0 = dg35_f2bf(f0 - dg35_bf2f(h0));
          dg35_u16 l1 = dg35_f2bf(f1 - dg35_bf2f(h1));
          hp[d] = (dg35_u32)h0 | ((dg35_u32)h1 << 16);
          lp[d] = (dg35_u32)l0 | ((dg35_u32)l1 << 16);
        }
        int slot = (swbase + g) ^ (r & 7);
        *reinterpret_cast<uint4*>(&Ahi[r*64 + slot*8]) = wh;
        *reinterpret_cast<uint4*>(&Alo[r*64 + slot*8]) = wl;
      }
    }
    __syncthreads();
    if (k0 + 64 < K && grow < M){
      const float* ap = A + (size_t)grow*K + k0 + 64 + cq;
      #pragma unroll
      for (int q2 = 0; q2 < 4; ++q2) va[q2] = *reinterpret_cast<const float4*>(ap + q2*4);
    }
    #pragma unroll
    for (int ks = 0; ks < 2; ++ks){
      dg35_s8v bh[4], bl[4];
      #pragma unroll
      for (int nf = 0; nf < 4; ++nf){
        int n = bn + nf*16 + l15;
        size_t wo = (size_t)n*K + k0 + ks*32 + l4*8;
        bh[nf] = *reinterpret_cast<const dg35_s8v*>(Whi + wo);
        bl[nf] = *reinterpret_cast<const dg35_s8v*>(Wlo + wo);
      }
      int row = wv*16 + l15;
      int slot = (ks*4 + l4) ^ (row & 7);
      dg35_s8v ah = *reinterpret_cast<const dg35_s8v*>(&Ahi[row*64 + slot*8]);
      dg35_s8v al = *reinterpret_cast<const dg35_s8v*>(&Alo[row*64 + slot*8]);
      #pragma unroll
      for (int nf = 0; nf < 4; ++nf){
        acc[nf] = __builtin_amdgcn_mfma_f32_16x16x32_bf16(ah, bh[nf], acc[nf], 0, 0, 0);
        acc[nf] = __builtin_amdgcn_mfma_f32_16x16x32_bf16(al, bh[nf], acc[nf], 0, 0, 0);
        acc[nf] = __builtin_amdgcn_mfma_f32_16x16x32_bf16(ah, bl[nf], acc[nf], 0, 0, 0);
      }
    }
    __syncthreads();
  }
  float s[4] = {0.f,0.f,0.f,0.f}, q[4] = {0.f,0.f,0.f,0.f};
  #pragma unroll
  for (int e = 0; e < 4; ++e){
    int rr = bm + wv*16 + l4*4 + e;
    if (rr >= M) continue;
    #pragma unroll
    for (int nf = 0; nf < 4; ++nf){
      int cc = bn + nf*16 + l15;
      float v = acc[nf][e] + bias[cc];
      size_t idx = (size_t)rr*NC + cc;
      if (addres) v += res[idx];
      Cout[idx] = v;
      s[nf] += v; q[nf] += v*v;
    }
  }
  #pragma unroll
  for (int nf = 0; nf < 4; ++nf){
    s[nf] += __shfl_xor(s[nf], 16); s[nf] += __shfl_xor(s[nf], 32);
    q[nf] += __shfl_xor(q[nf], 16); q[nf] += __shfl_xor(q[nf], 32);
  }
  __syncthreads();
  float* red = (float*)Ahi;
  if (l4 == 0){
    #pragma unroll
    for (int nf = 0; nf < 4; ++nf){
      red[wv*128 + nf*16 + l15] = s[nf];
      red[wv*128 + 64 + nf*16 + l15] = q[nf];
    }
  }
  __syncthreads();
  if (tid < 64){
    float S = red[tid] + red[128+tid] + red[256+tid] + red[384+tid];
    float Q = red[64+tid] + red[192+tid] + red[320+tid] + red[448+tid];
    atomicAdd(&st[bn + tid], S);
    atomicAdd(&st[NC + bn + tid], Q);
  }
}

// -------- VALU GEMM (dual-precision) — tier-B fallback only --------
__global__ __launch_bounds__(256)
void dg35_gemm_h(const void* __restrict__ A, const float* __restrict__ W,
                 const float* __restrict__ bias, const float* __restrict__ ab,
                 const void* __restrict__ res, void* __restrict__ Cout,
                 int M, int K, int NC, int trans, int addres, int af){
  __shared__ float At[32][65];
  __shared__ float Bt[32][64];
  int bm = blockIdx.x * 64;
  int bn = blockIdx.y * 64;
  int tid = threadIdx.x;
  int tx = tid & 15, ty = tid >> 4;
  float acc[4][4];
  #pragma unroll
  for (int i2 = 0; i2 < 4; ++i2)
    #pragma unroll
    for (int j2 = 0; j2 < 4; ++j2) acc[i2][j2] = 0.f;

  for (int k0 = 0; k0 < K; k0 += 32){
    int r = tid >> 3;
    int kq = (tid & 7) * 4;
    #pragma unroll
    for (int half = 0; half < 2; ++half){
      int rr = r + half*32;
      int grow = bm + rr;
      float vv[4] = {0.f, 0.f, 0.f, 0.f};
      if (grow < M){
        if (af){
          float4 v4 = *reinterpret_cast<const float4*>((const float*)A + (size_t)grow*K + k0 + kq);
          vv[0] = v4.x; vv[1] = v4.y; vv[2] = v4.z; vv[3] = v4.w;
        } else {
          ushort4 v4 = *reinterpret_cast<const ushort4*>((const dg35_u16*)A + (size_t)grow*K + k0 + kq);
          vv[0] = dg35_bf2f(v4.x); vv[1] = dg35_bf2f(v4.y);
          vv[2] = dg35_bf2f(v4.z); vv[3] = dg35_bf2f(v4.w);
        }
      }
      #pragma unroll
      for (int i2 = 0; i2 < 4; ++i2){
        float xv = vv[i2];
        if (trans){
          int kk = k0 + kq + i2;
          xv = fmaxf(xv*ab[kk] + ab[K + kk], 0.f);
        }
        At[kq + i2][rr] = xv;
      }
    }
    {
      int kr = tid >> 3;
      int cq = (tid & 7) * 8;
      const float* wp = W + (size_t)(k0 + kr)*NC + bn + cq;
      #pragma unroll
      for (int i2 = 0; i2 < 8; ++i2) Bt[kr][cq + i2] = wp[i2];
    }
    __syncthreads();
    #pragma unroll
    for (int kk = 0; kk < 32; ++kk){
      float a4[4], b4[4];
      #pragma unroll
      for (int i2 = 0; i2 < 4; ++i2) a4[i2] = At[kk][ty*4 + i2];
      #pragma unroll
      for (int j2 = 0; j2 < 4; ++j2) b4[j2] = Bt[kk][tx*4 + j2];
      #pragma unroll
      for (int i2 = 0; i2 < 4; ++i2)
        #pragma unroll
        for (int j2 = 0; j2 < 4; ++j2)
          acc[i2][j2] += a4[i2]*b4[j2];
    }
    __syncthreads();
  }
  #pragma unroll
  for (int i2 = 0; i2 < 4; ++i2){
    int rr = bm + ty*4 + i2;
    if (rr >= M) continue;
    #pragma unroll
    for (int j2 = 0; j2 < 4; ++j2){
      int cc = bn + tx*4 + j2;
      float v = acc[i2][j2] + bias[cc];
      size_t idx = (size_t)rr*NC + cc;
      if (addres) v += dg35_ldx(res, idx, af);
      dg35_stx(Cout, idx, af, v);
    }
  }
}

// -------- GEMM, A f32, W f32, f32 out (virtual-node MLP, M=1024) --------
__global__ __launch_bounds__(256)
void dg35_gemm_v(const float* __restrict__ A, const float* __restrict__ W,
                 const float* __restrict__ bias, const float* __restrict__ ab,
                 float* __restrict__ Cout, int M, int K, int NC, int trans){
  __shared__ float At[32][65];
  __shared__ float Bt[32][64];
  int bm = blockIdx.x * 64;
  int bn = blockIdx.y * 64;
  int tid = threadIdx.x;
  int tx = tid & 15, ty = tid >> 4;
  float acc[4][4];
  #pragma unroll
  for (int i2 = 0; i2 < 4; ++i2)
    #pragma unroll
    for (int j2 = 0; j2 < 4; ++j2) acc[i2][j2] = 0.f;

  for (int k0 = 0; k0 < K; k0 += 32){
    int r = tid >> 3;
    int kq = (tid & 7) * 4;
    #pragma unroll
    for (int half = 0; half < 2; ++half){
      int rr = r + half*32;
      int grow = bm + rr;
      float vv[4] = {0.f, 0.f, 0.f, 0.f};
      if (grow < M){
        float4 v4 = *reinterpret_cast<const float4*>(A + (size_t)grow*K + k0 + kq);
        vv[0] = v4.x; vv[1] = v4.y; vv[2] = v4.z; vv[3] = v4.w;
      }
      #pragma unroll
      for (int i2 = 0; i2 < 4; ++i2){
        float xv = vv[i2];
        if (trans){
          int kk = k0 + kq + i2;
          xv = fmaxf(xv*ab[kk] + ab[K + kk], 0.f);
        }
        At[kq + i2][rr] = xv;
      }
    }
    {
      int kr = tid >> 3;
      int cq = (tid & 7) * 8;
      const float* wp = W + (size_t)(k0 + kr)*NC + bn + cq;
      #pragma unroll
      for (int i2 = 0; i2 < 8; ++i2) Bt[kr][cq + i2] = wp[i2];
    }
    __syncthreads();
    #pragma unroll
    for (int kk = 0; kk < 32; ++kk){
      float a4[4], b4[4];
      #pragma unroll
      for (int i2 = 0; i2 < 4; ++i2) a4[i2] = At[kk][ty*4 + i2];
      #pragma unroll
      for (int j2 = 0; j2 < 4; ++j2) b4[j2] = Bt[kk][tx*4 + j2];
      #pragma unroll
      for (int i2 = 0; i2 < 4; ++i2)
        #pragma unroll
        for (int j2 = 0; j2 < 4; ++j2)
          acc[i2][j2] += a4[i2]*b4[j2];
    }
    __syncthreads();
  }
  #pragma unroll
  for (int i2 = 0; i2 < 4; ++i2){
    int rr = bm + ty*4 + i2;
    if (rr >= M) continue;
    #pragma unroll
    for (int j2 = 0; j2 < 4; ++j2){
      int cc = bn + tx*4 + j2;
      Cout[(size_t)rr*NC + cc] = acc[i2][j2] + bias[cc];
    }
  }
}

// ---------------- BN statistics (small f32 buffers: zv1/zv2) ----------------
__global__ __launch_bounds__(256)
void dg35_cs4(const float* __restrict__ Z, float* __restrict__ st, int n, int ncols){
  int t = threadIdx.x;
  int lpr = ncols >> 2;
  int rl = t / lpr;
  int rpb = 256 / lpr;
  int cq = (t - rl*lpr) * 4;
  float4 s = make_float4(0.f,0.f,0.f,0.f);
  float4 q = make_float4(0.f,0.f,0.f,0.f);
  for (int rr = blockIdx.x*rpb + rl; rr < n; rr += gridDim.x*rpb){
    float4 v = *reinterpret_cast<const float4*>(Z + (size_t)rr*ncols + cq);
    s.x += v.x; s.y += v.y; s.z += v.z; s.w += v.w;
    q.x += v.x*v.x; q.y += v.y*v.y; q.z += v.z*v.z; q.w += v.w*v.w;
  }
  __shared__ float sm[256*8];
  float* my = &sm[t*8];
  my[0]=s.x; my[1]=s.y; my[2]=s.z; my[3]=s.w;
  my[4]=q.x; my[5]=q.y; my[6]=q.z; my[7]=q.w;
  __syncthreads();
  if (rl == 0){
    float a[8];
    #pragma unroll
    for (int d = 0; d < 8; ++d) a[d] = my[d];
    for (int j = 1; j < rpb; ++j){
      const float* o2 = &sm[(t + j*lpr)*8];
      #pragma unroll
      for (int d = 0; d < 8; ++d) a[d] += o2[d];
    }
    #pragma unroll
    for (int d = 0; d < 4; ++d) atomicAdd(&st[cq + d], a[d]);
    #pragma unroll
    for (int d = 0; d < 4; ++d) atomicAdd(&st[ncols + cq + d], a[4 + d]);
  }
}

// tier-B fallback colstats
__global__ void dg35_colstats(const void* __restrict__ Z, float* __restrict__ st,
                              int n, int ncols, int af){
  int tid = threadIdx.x;
  int c = tid & (ncols - 1);
  int rl = tid / ncols;
  int rpb = 256 / ncols;
  float s = 0.f, q = 0.f;
  for (int rr = blockIdx.x*rpb + rl; rr < n; rr += gridDim.x*rpb){
    float v = dg35_ldx(Z, (size_t)rr*ncols + c, af);
    s += v; q += v*v;
  }
  atomicAdd(&st[c], s);
  atomicAdd(&st[ncols + c], q);
}

__global__ void dg35_fin(const float* __restrict__ st, const float* __restrict__ g,
                         const float* __restrict__ b, float* __restrict__ ab,
                         float inv_n, int ncols){
  int c = threadIdx.x + blockIdx.x*256;
  if (c >= ncols) return;
  float m = st[c]*inv_n;
  float var = st[ncols + c]*inv_n - m*m;
  float rstd = rsqrtf(var + 1e-5f);
  float a = g[c]*rstd;
  ab[c] = a;
  ab[ncols + c] = b[c] - m*a;
}

// ---------------- elementwise / segment ops ----------------
__global__ void dg35_h24(const float* __restrict__ h, const float* __restrict__ ab,
                         float* __restrict__ h2){
  int i = blockIdx.x*256 + threadIdx.x;
  int c = (i & 31) * 4;
  float4 v = reinterpret_cast<const float4*>(h)[i];
  v.x = fmaxf(v.x*ab[c+0] + ab[dgC+c+0], 0.f);
  v.y = fmaxf(v.y*ab[c+1] + ab[dgC+c+1], 0.f);
  v.z = fmaxf(v.z*ab[c+2] + ab[dgC+c+2], 0.f);
  v.w = fmaxf(v.w*ab[c+3] + ab[dgC+c+3], 0.f);
  reinterpret_cast<float4*>(h2)[i] = v;
}

__global__ void dg35_h2(const void* __restrict__ h, const float* __restrict__ ab,
                        void* __restrict__ h2, int af){
  int i = blockIdx.x*256 + threadIdx.x;
  int c = i & (dgC-1);
  dg35_stx(h2, i, af, fmaxf(dg35_ldx(h, i, af)*ab[c] + ab[dgC + c], 0.f));
}

__global__ __launch_bounds__(128)
void dg35_vt4(const float* __restrict__ h2, const float* __restrict__ vn,
              const int* __restrict__ gs, float* __restrict__ vt){
  int g = blockIdx.x, t = threadIdx.x;
  int rl = t >> 5, cl = t & 31;
  int cq = cl*4;
  int r0 = gs[g], r1 = gs[g+1];
  float4 s = make_float4(0.f,0.f,0.f,0.f);
  for (int rr = r0 + rl; rr < r1; rr += 4){
    float4 v = *reinterpret_cast<const float4*>(h2 + (size_t)rr*dgC + cq);
    s.x += v.x; s.y += v.y; s.z += v.z; s.w += v.w;
  }
  __shared__ float4 sm[128];
  sm[t] = s;
  __syncthreads();
  if (rl == 0){
    float4 a = sm[cl], b = sm[32+cl], c4 = sm[64+cl], d = sm[96+cl];
    float4 vb = *reinterpret_cast<const float4*>(vn + (size_t)g*dgC + cq);
    float4 o;
    o.x = a.x+b.x+c4.x+d.x + vb.x;
    o.y = a.y+b.y+c4.y+d.y + vb.y;
    o.z = a.z+b.z+c4.z+d.z + vb.z;
    o.w = a.w+b.w+c4.w+d.w + vb.w;
    *reinterpret_cast<float4*>(vt + (size_t)g*dgC + cq) = o;
  }
}

__global__ __launch_bounds__(128)
void dg35_vt(const void* __restrict__ h2, const float* __restrict__ vn,
             const int* __restrict__ gs, float* __restrict__ vt, int af){
  int g = blockIdx.x, c = threadIdx.x;
  float s = 0.f;
  int r0 = gs[g], r1 = gs[g+1];
  for (int rr = r0; rr < r1; ++rr) s += dg35_ldx(h2, (size_t)rr*dgC + c, af);
  vt[g*dgC + c] = s + vn[g*dgC + c];
}

__global__ void dg35_vnfin(const float* __restrict__ z2, const float* __restrict__ ab,
                           float* __restrict__ vn){
  int i = blockIdx.x*256 + threadIdx.x;
  int c = i & (dgC-1);
  vn[i] = fmaxf(z2[i]*ab[c] + ab[dgC + c], 0.f);
}

// float4 vectorized h2 += vn[batch]
__global__ void dg35_addvn4(float* __restrict__ h2, const float* __restrict__ vn,
                            const int* __restrict__ batch){
  int i = blockIdx.x*256 + threadIdx.x;     // float4 index
  int row = i >> 5;
  int cl = i & 31;
  float4 v = reinterpret_cast<float4*>(h2)[i];
  float4 a = reinterpret_cast<const float4*>(vn)[batch[row]*32 + cl];
  v.x += a.x; v.y += a.y; v.z += a.z; v.w += a.w;
  reinterpret_cast<float4*>(h2)[i] = v;
}

__global__ __launch_bounds__(128)
void dg35_addvn(void* __restrict__ h2, const float* __restrict__ vn,
                const int* __restrict__ batch, int af){
  int i = blockIdx.x, c = threadIdx.x;
  size_t idx = (size_t)i*dgC + c;
  dg35_stx(h2, idx, af, dg35_ldx(h2, idx, af) + vn[batch[i]*dgC + c]);
}

__global__ __launch_bounds__(128)
void dg35_out4(const float* __restrict__ h, const float* __restrict__ ab,
               const int* __restrict__ gs, float* __restrict__ out){
  int g = blockIdx.x, t = threadIdx.x;
  int rl = t >> 5, cl = t & 31;
  int cq = cl*4;
  int r0 = gs[g], r1 = gs[g+1];
  float4 s = make_float4(0.f,0.f,0.f,0.f);
  for (int rr = r0 + rl; rr < r1; rr += 4){
    float4 v = *reinterpret_cast<const float4*>(h + (size_t)rr*dgC + cq);
    s.x += v.x; s.y += v.y; s.z += v.z; s.w += v.w;
  }
  __shared__ float4 sm[128];
  sm[t] = s;
  __syncthreads();
  if (rl == 0){
    float4 a4 = sm[cl], b4 = sm[32+cl], c4 = sm[64+cl], d4 = sm[96+cl];
    float cnt = (float)(r1 - r0);
    float4 o;
    float S;
    S = a4.x+b4.x+c4.x+d4.x; o.x = ab[cq+0]*S + ab[dgC+cq+0]*cnt;
    S = a4.y+b4.y+c4.y+d4.y; o.y = ab[cq+1]*S + ab[dgC+cq+1]*cnt;
    S = a4.z+b4.z+c4.z+d4.z; o.z = ab[cq+2]*S + ab[dgC+cq+2]*cnt;
    S = a4.w+b4.w+c4.w+d4.w; o.w = ab[cq+3]*S + ab[dgC+cq+3]*cnt;
    *reinterpret_cast<float4*>(out + (size_t)g*dgC + cq) = o;
  }
}

// tier-B fallback pieces
__global__ __launch_bounds__(128)
void dg35_gb(const void* __restrict__ hin, const dg35_u32* __restrict__ packed,
             const int* __restrict__ off, const float* __restrict__ bemb,
             void* __restrict__ hh, int af){
  int i = blockIdx.x, c = threadIdx.x;
  int b0 = off[i], b1 = off[i+1];
  float m = -3.0e38f, s = 0.f, w = 0.f;
  for (int p = b0; p < b1; ++p){
    dg35_u32 pk = packed[p];
    int src = (int)(pk & 0x1FFFFu);
    float e = bemb[((pk>>17)&7)*dgC + c] + bemb[(8+((pk>>20)&7))*dgC + c]
            + bemb[(16+((pk>>23)&7))*dgC + c];
    float msg = fmaxf(dg35_ldx(hin, (size_t)src*dgC + c, af) + e, 0.f) + 1e-7f;
    float mn = fmaxf(m, msg);
    float sc = __expf(m - mn), t2 = __expf(msg - mn);
    s = s*sc + t2; w = w*sc + msg*t2; m = mn;
  }
  float agg = (b1 > b0) ? (w / (s + 1e-16f)) : 0.f;
  float self = dg35_ldx(hin, (size_t)i*dgC + c, af);
  dg35_stx(hh, (size_t)i*dgC + c, af, self + agg);
}

__global__ __launch_bounds__(128)
void dg35_out(const void* __restrict__ h, const float* __restrict__ ab,
              const int* __restrict__ gs, float* __restrict__ out, int af){
  int g = blockIdx.x, c = threadIdx.x;
  float a = ab[c], b = ab[dgC + c];
  float s = 0.f;
  int r0 = gs[g], r1 = gs[g+1];
  for (int rr = r0; rr < r1; ++rr) s += dg35_ldx(h, (size_t)rr*dgC + c, af)*a + b;
  out[g*dgC + c] = s;
}

static inline size_t dg35_al(size_t x){ return (x + 255) & ~(size_t)255; }

extern "C" void kernel_launch(void* const* d_in, const int* in_sizes, int n_in,
                              void* d_out, int out_size, void* d_ws, size_t ws_size,
                              hipStream_t stream)
{
  const int*   x     = (const int*)d_in[0];
  const int*   eattr = (const int*)d_in[1];
  const int*   eidx  = (const int*)d_in[2];
  const int*   batch = (const int*)d_in[3];
  const float* aemb  = (const float*)d_in[4];
  const float* bemb  = (const float*)d_in[5];
  const float* vne   = (const float*)d_in[6];
  const float* cW1   = (const float*)d_in[7];
  const float* cb1   = (const float*)d_in[8];
  const float* cg1   = (const float*)d_in[9];
  const float* cbb1  = (const float*)d_in[10];
  const float* cW2   = (const float*)d_in[11];
  const float* cb2   = (const float*)d_in[12];
  const float* ng    = (const float*)d_in[13];
  const float* nb    = (const float*)d_in[14];
  const float* vW1   = (const float*)d_in[15];
  const float* vb1   = (const float*)d_in[16];
  const float* vg1   = (const float*)d_in[17];
  const float* vbb1  = (const float*)d_in[18];
  const float* vW2   = (const float*)d_in[19];
  const float* vb2   = (const float*)d_in[20];
  const float* vg2   = (const float*)d_in[21];
  const float* vbb2  = (const float*)d_in[22];
  float* out = (float*)d_out;

  const int nsb = (dgN + 255) / 256;

  const size_t fixed =
      dg35_al(dgG*dgC*4)*4 +
      dg35_al(2*dgC2*4)*2 +
      dg35_al(2*dgC*4)*6 +
      dg35_al(dgN*4)*2 + dg35_al((dgN+1)*4) +
      dg35_al((dgG+1)*4) +
      dg35_al((size_t)dgE*4) +
      dg35_al(7*256*128*2)*4 +
      dg35_al(512*dgC*4) +                      // ecomb
      dg35_al(256*4)*2;
  int af = 0;
  size_t esz = 2;
  {
    size_t bigf = dg35_al((size_t)dgN*dgC*4)*2 + dg35_al((size_t)dgN*dgC2*4);
    if (bigf + fixed <= ws_size){ af = 1; esz = 4; }
  }

  char* base = (char*)d_ws;
  size_t o = 0;
  void* h  = (void*)(base + o); o += dg35_al((size_t)dgN*dgC*esz);
  void* hh = (void*)(base + o); o += dg35_al((size_t)dgN*dgC*esz);
  void* zb = (void*)(base + o); o += dg35_al((size_t)dgN*dgC2*esz);
  float* vn   = (float*)(base + o); o += dg35_al(dgG*dgC*4);
  float* vt   = (float*)(base + o); o += dg35_al(dgG*dgC*4);
  float* zv1  = (float*)(base + o); o += dg35_al(dgG*dgC*4);
  float* zv2  = (float*)(base + o); o += dg35_al(dgG*dgC*4);
  float* st1  = (float*)(base + o); o += dg35_al(2*dgC2*4);
  float* ab1  = (float*)(base + o); o += dg35_al(2*dgC2*4);
  float* stH  = (float*)(base + o); o += dg35_al(2*dgC*4);
  float* stV1 = (float*)(base + o); o += dg35_al(2*dgC*4);
  float* stV2 = (float*)(base + o); o += dg35_al(2*dgC*4);
  float* abh  = (float*)(base + o); o += dg35_al(2*dgC*4);
  float* abv1 = (float*)(base + o); o += dg35_al(2*dgC*4);
  float* abv2 = (float*)(base + o); o += dg35_al(2*dgC*4);
  int* deg = (int*)(base + o); o += dg35_al(dgN*4);
  int* cur = (int*)(base + o); o += dg35_al(dgN*4);
  int* off = (int*)(base + o); o += dg35_al((dgN+1)*4);
  int* gs  = (int*)(base + o); o += dg35_al((dgG+1)*4);
  dg35_u32* packed = (dg35_u32*)(base + o); o += dg35_al((size_t)dgE*4);
  short* Wt1h = (short*)(base + o); o += dg35_al(7*256*128*2);
  short* Wt1l = (short*)(base + o); o += dg35_al(7*256*128*2);
  short* Wt2h = (short*)(base + o); o += dg35_al(7*256*128*2);
  short* Wt2l = (short*)(base + o); o += dg35_al(7*256*128*2);
  float* ecomb = (float*)(base + o); o += dg35_al(512*dgC*4);
  int* bsum = (int*)(base + o); o += dg35_al(256*4);
  int* boff = (int*)(base + o); o += dg35_al(256*4);

  if (o > ws_size){
    hipMemsetAsync(d_out, 0x7F, (size_t)out_size*4, stream);
    return;
  }
  void* h2 = zb;
  void* z  = zb;

  // ---- per-call setup ----
  hipMemsetAsync(deg, 0, sizeof(int)*dgN, stream);
  dg35_count  <<<(dgE+255)/256, 256, 0, stream>>>(eidx + dgE, deg, dgE);
  dg35_s1     <<<nsb, 256, 0, stream>>>(deg, bsum, dgN);
  dg35_s2     <<<1, 256, 0, stream>>>(bsum, boff, nsb);
  dg35_s3     <<<nsb, 256, 0, stream>>>(deg, boff, off, cur, dgN);
  dg35_scatter<<<(dgE+255)/256, 256, 0, stream>>>(eidx, eattr, cur, packed, dgE);
  dg35_gstart <<<(dgG+256)/256, 256, 0, stream>>>(batch, gs, dgN, dgG);
  dg35_atom   <<<dgN, dgC, 0, stream>>>(x, aemb, vne, h, af);
  dg35_vninit <<<(dgG*dgC)/256, 256, 0, stream>>>(vne, vn);
  dg35_wconv  <<<1792, 256, 0, stream>>>(cW1, cW2, Wt1h, Wt1l, Wt2h, Wt2l);
  dg35_ecomb  <<<512, 128, 0, stream>>>(bemb, ecomb);

  if (af){
    const int grb = (dgN + 63) / 64;   // 782 row-blocks
    for (int l = 0; l < 7; ++l){
      const float* hin = (const float*)h;
      if (l > 0){
        // stH was accumulated by previous layer's gemm2
        dg35_fin<<<1, 256, 0, stream>>>(stH, ng + (l-1)*dgC, nb + (l-1)*dgC,
                                        abh, 1.f/dgN, dgC);
        dg35_zero2<<<1, 512, 0, stream>>>(st1, stV1, stV2);
        dg35_h24<<<(dgN*dgC/4)/256, 256, 0, stream>>>((const float*)h, abh, (float*)h2);
        dg35_vt4<<<dgG, 128, 0, stream>>>((const float*)h2, vn, gs, vt);
        dg35_gemm_v<<<dim3(16,2), 256, 0, stream>>>(vt, vW1 + (l-1)*dgC*dgC,
                                                    vb1 + (l-1)*dgC, (const float*)0,
                                                    zv1, dgG, dgC, dgC, 0);
        dg35_cs4<<<64, 256, 0, stream>>>(zv1, stV1, dgG, dgC);
        dg35_fin<<<1, 256, 0, stream>>>(stV1, vg1 + (l-1)*dgC, vbb1 + (l-1)*dgC,
                                        abv1, 1.f/dgG, dgC);
        dg35_gemm_v<<<dim3(16,2), 256, 0, stream>>>(zv1, vW2 + (l-1)*dgC*dgC,
                                                    vb2 + (l-1)*dgC, abv1,
                                                    zv2, dgG, dgC, dgC, 1);
        dg35_cs4<<<64, 256, 0, stream>>>(zv2, stV2, dgG, dgC);
        dg35_fin<<<1, 256, 0, stream>>>(stV2, vg2 + (l-1)*dgC, vbb2 + (l-1)*dgC,
                                        abv2, 1.f/dgG, dgC);
        dg35_vnfin<<<(dgG*dgC)/256, 256, 0, stream>>>(zv2, abv2, vn);
        dg35_addvn4<<<(dgN*dgC/4)/256, 256, 0, stream>>>((float*)h2, vn, batch);
        hin = (const float*)h2;
      } else {
        dg35_zero2<<<1, 512, 0, stream>>>(st1, stV1, stV2);
      }
      dg35_gb2<<<(dgN+3)/4, 256, 0, stream>>>(hin, packed, off, ecomb, (float*)hh);
      dg35_gemmx<<<dim3(4, grb), 256, 0, stream>>>((const float*)hh,
                                                   Wt1h + l*32768, Wt1l + l*32768,
                                                   cb1 + l*dgC2, (const float*)0,
                                                   (const float*)0, (float*)z, st1,
                                                   dgN, dgC, dgC2, 0, 0);
      dg35_fin<<<1, 256, 0, stream>>>(st1, cg1 + l*dgC2, cbb1 + l*dgC2,
                                      ab1, 1.f/dgN, dgC2);
      hipMemsetAsync(stH, 0, sizeof(float)*2*dgC, stream);
      dg35_gemmx<<<dim3(2, grb), 256, 0, stream>>>((const float*)z,
                                                   Wt2h + l*32768, Wt2l + l*32768,
                                                   cb2 + l*dgC, ab1,
                                                   (l==0) ? (const float*)0 : (const float*)h,
                                                   (float*)h, stH,
                                                   dgN, dgC2, dgC, 1, (l==0)?0:1);
    }
    // final BN (stats already in stH from last gemm2) + global_add_pool
    dg35_fin<<<1, 256, 0, stream>>>(stH, ng + 6*dgC, nb + 6*dgC, abh, 1.f/dgN, dgC);
    dg35_out4<<<dgG, 128, 0, stream>>>((const float*)h, abh, gs, out);
  } else {
    // tier-B fallback (bf16 storage, VALU GEMM)
    const int gx = (dgN + 63) / 64;
    for (int l = 0; l < 7; ++l){
      dg35_zero<<<1, 512, 0, stream>>>(st1, stH, stV1, stV2);
      const void* hin = h;
      if (l > 0){
        dg35_colstats<<<128, 256, 0, stream>>>(h, stH, dgN, dgC, af);
        dg35_fin<<<1, 256, 0, stream>>>(stH, ng + (l-1)*dgC, nb + (l-1)*dgC,
                                        abh, 1.f/dgN, dgC);
        dg35_h2<<<(dgN*dgC)/256, 256, 0, stream>>>(h, abh, h2, af);
        dg35_vt<<<dgG, dgC, 0, stream>>>(h2, vn, gs, vt, af);
        dg35_gemm_v<<<dim3(16,2), 256, 0, stream>>>(vt, vW1 + (l-1)*dgC*dgC,
                                                    vb1 + (l-1)*dgC, (const float*)0,
                                                    zv1, dgG, dgC, dgC, 0);
        dg35_cs4<<<64, 256, 0, stream>>>(zv1, stV1, dgG, dgC);
        dg35_fin<<<1, 256, 0, stream>>>(stV1, vg1 + (l-1)*dgC, vbb1 + (l-1)*dgC,
                                        abv1, 1.f/dgG, dgC);
        dg35_gemm_v<<<dim3(16,2), 256, 0, stream>>>(zv1, vW2 + (l-1)*dgC*dgC,
                                                    vb2 + (l-1)*dgC, abv1,
                                                    zv2, dgG, dgC, dgC, 1);
        dg35_cs4<<<64, 256, 0, stream>>>(zv2, stV2, dgG, dgC);
        dg35_fin<<<1, 256, 0, stream>>>(stV2, vg2 + (l-1)*dgC, vbb2 + (l-1)*dgC,
                                        abv2, 1.f/dgG, dgC);
        dg35_vnfin<<<(dgG*dgC)/256, 256, 0, stream>>>(zv2, abv2, vn);
        dg35_addvn<<<dgN, dgC, 0, stream>>>(h2, vn, batch, af);
        hin = h2;
      }
      dg35_gb<<<dgN, dgC, 0, stream>>>(hin, packed, off, bemb, hh, af);
      dg35_gemm_h<<<dim3(gx,4), 256, 0, stream>>>(hh, cW1 + l*dgC*dgC2,
                                                  cb1 + l*dgC2, (const float*)0,
                                                  (const void*)0, z,
                                                  dgN, dgC, dgC2, 0, 0, af);
      dg35_colstats<<<128, 256, 0, stream>>>(z, st1, dgN, dgC2, af);
      dg35_fin<<<1, 256, 0, stream>>>(st1, cg1 + l*dgC2, cbb1 + l*dgC2,
                                      ab1, 1.f/dgN, dgC2);
      dg35_gemm_h<<<dim3(gx,2), 256, 0, stream>>>(z, cW2 + l*dgC2*dgC,
                                                  cb2 + l*dgC, ab1, h, h,
                                                  dgN, dgC2, dgC, 1, (l==0)?0:1, af);
    }
    hipMemsetAsync(stH, 0, sizeof(float)*2*dgC, stream);
    dg35_colstats<<<128, 256, 0, stream>>>(h, stH, dgN, dgC, af);
    dg35_fin<<<1, 256, 0, stream>>>(stH, ng + 6*dgC, nb + 6*dgC, abh, 1.f/dgN, dgC);
    dg35_out<<<dgG, dgC, 0, stream>>>(h, abh, gs, out, af);
  }
}

// Round 12
// 1422.171 us; speedup vs baseline: 2.5218x; 1.4198x over previous
//
#include <hip/hip_runtime.h>

typedef unsigned short dg35_u16;
typedef unsigned int   dg35_u32;

constexpr int dgN  = 50000;
constexpr int dgE  = 400000;
constexpr int dgG  = 1024;
constexpr int dgC  = 128;
constexpr int dgC2 = 256;

typedef __attribute__((ext_vector_type(8))) short dg35_s8v;   // 8 bf16 (4 VGPR)
typedef __attribute__((ext_vector_type(4))) float dg35_f4v;   // MFMA acc

__device__ __forceinline__ float dg35_bf2f(dg35_u16 u){
  return __uint_as_float(((dg35_u32)u) << 16);
}
__device__ __forceinline__ dg35_u16 dg35_f2bf(float f){
  dg35_u32 u = __float_as_uint(f);
  u += 0x7FFFu + ((u >> 16) & 1u);
  return (dg35_u16)(u >> 16);
}
__device__ __forceinline__ float dg35_ldx(const void* p, size_t i, int af){
  return af ? ((const float*)p)[i] : dg35_bf2f(((const dg35_u16*)p)[i]);
}
__device__ __forceinline__ void dg35_stx(void* p, size_t i, int af, float v){
  if (af) ((float*)p)[i] = v; else ((dg35_u16*)p)[i] = dg35_f2bf(v);
}

// Symbol from the harness template; kept but never launched.
__global__ void DeeperGCN_35820027248884_kernel(){}

// ---------------- CSR build ----------------
__global__ void dg35_count(const int* __restrict__ dst, int* __restrict__ deg, int e){
  int j = blockIdx.x*256 + threadIdx.x;
  if (j < e) atomicAdd(&deg[dst[j]], 1);
}

__global__ void dg35_s1(const int* __restrict__ deg, int* __restrict__ bsum, int n){
  __shared__ int sm[256];
  int t = threadIdx.x, b = blockIdx.x;
  int idx = b*256 + t;
  sm[t] = (idx < n) ? deg[idx] : 0;
  __syncthreads();
  for (int s = 128; s > 0; s >>= 1){
    if (t < s) sm[t] += sm[t+s];
    __syncthreads();
  }
  if (t == 0) bsum[b] = sm[0];
}

__global__ void dg35_s2(const int* __restrict__ bsum, int* __restrict__ boff, int nb){
  __shared__ int sm[256];
  int t = threadIdx.x;
  int v = (t < nb) ? bsum[t] : 0;
  sm[t] = v;
  __syncthreads();
  for (int s = 1; s < 256; s <<= 1){
    int u = (t >= s) ? sm[t-s] : 0;
    __syncthreads();
    sm[t] += u;
    __syncthreads();
  }
  if (t < nb) boff[t] = sm[t] - v;
}

__global__ void dg35_s3(const int* __restrict__ deg, const int* __restrict__ boff,
                        int* __restrict__ off, int* __restrict__ cur, int n){
  __shared__ int sm[256];
  int t = threadIdx.x, b = blockIdx.x;
  int idx = b*256 + t;
  int v = (idx < n) ? deg[idx] : 0;
  sm[t] = v;
  __syncthreads();
  for (int s = 1; s < 256; s <<= 1){
    int u = (t >= s) ? sm[t-s] : 0;
    __syncthreads();
    sm[t] += u;
    __syncthreads();
  }
  if (idx < n){
    int e = boff[b] + sm[t] - v;
    off[idx] = e; cur[idx] = e;
  }
  if (idx == 0) off[n] = dgE;
}

__global__ void dg35_scatter(const int* __restrict__ ei, const int* __restrict__ ea,
                             int* __restrict__ cur, dg35_u32* __restrict__ packed, int e){
  int j = blockIdx.x*256 + threadIdx.x;
  if (j >= e) return;
  int s = ei[j], d = ei[e + j];
  dg35_u32 a0 = (dg35_u32)ea[3*j], a1 = (dg35_u32)ea[3*j+1], a2 = (dg35_u32)ea[3*j+2];
  int pos = atomicAdd(&cur[d], 1);
  packed[pos] = (dg35_u32)s | (a0<<17) | (a1<<20) | (a2<<23);
}

__global__ void dg35_gstart(const int* __restrict__ batch, int* __restrict__ gs, int n, int g){
  int i = blockIdx.x*256 + threadIdx.x;
  if (i > g) return;
  if (i == g){ gs[i] = n; return; }
  int lo = 0, hi = n;
  while (lo < hi){ int mid = (lo+hi)>>1; if (batch[mid] < i) lo = mid+1; else hi = mid; }
  gs[i] = lo;
}

// ---------------- encoders / weight prep ----------------
__global__ __launch_bounds__(128)
void dg35_atom(const int* __restrict__ x, const float* __restrict__ aemb,
               const float* __restrict__ vne, void* __restrict__ h, int af){
  int i = blockIdx.x, c = threadIdx.x;
  float acc = vne[c];
  #pragma unroll
  for (int f = 0; f < 9; ++f){
    int idx = x[i*9 + f];
    acc += aemb[(f*128 + idx)*dgC + c];
  }
  dg35_stx(h, (size_t)i*dgC + c, af, acc);
}

__global__ void dg35_vninit(const float* __restrict__ vne, float* __restrict__ vn){
  int i = blockIdx.x*256 + threadIdx.x;
  if (i < dgG*dgC) vn[i] = vne[i & (dgC-1)];
}

// combo table: ecomb[c9][c] = bemb[a0][c] + bemb[8+a1][c] + bemb[16+a2][c]
__global__ __launch_bounds__(128)
void dg35_ecomb(const float* __restrict__ bemb, float* __restrict__ ecomb){
  int c9 = blockIdx.x, t = threadIdx.x;
  int a0 = c9 & 7, a1 = (c9 >> 3) & 7, a2 = (c9 >> 6) & 7;
  ecomb[c9*dgC + t] = bemb[a0*dgC + t] + bemb[(8+a1)*dgC + t] + bemb[(16+a2)*dgC + t];
}

// transpose+convert conv weights to SPLIT bf16 (hi+lo) in [l][n][k] layout
__global__ void dg35_wconv(const float* __restrict__ W1, const float* __restrict__ W2,
                           short* __restrict__ Wt1h, short* __restrict__ Wt1l,
                           short* __restrict__ Wt2h, short* __restrict__ Wt2l){
  int i = blockIdx.x*256 + threadIdx.x;
  constexpr int per = 7*256*128;
  float w;
  short* ph; short* pl; int oidx;
  if (i < per){
    int l = i >> 15;
    int rem = i & 32767;
    int n = rem >> 7;
    int k = rem & 127;
    w = W1[l*32768 + k*256 + n];
    ph = Wt1h; pl = Wt1l; oidx = i;
  } else {
    int j = i - per;
    int l = j >> 15;
    int rem = j & 32767;
    int n = rem >> 8;
    int k = rem & 255;
    w = W2[l*32768 + k*128 + n];
    ph = Wt2h; pl = Wt2l; oidx = j;
  }
  dg35_u16 hi = dg35_f2bf(w);
  float lo = w - dg35_bf2f(hi);
  ph[oidx] = (short)hi;
  pl[oidx] = (short)dg35_f2bf(lo);
}

__global__ void dg35_zero(float* a, float* b, float* c_, float* d){
  int t = threadIdx.x;
  if (t < 512) a[t] = 0.f;
  if (t < 256){ b[t]=0.f; c_[t]=0.f; d[t]=0.f; }
}

// ------------- GENConv softmax aggr: 1 wave/node, 2 ch/lane, 2 edge streams, 1-exp update
__device__ __forceinline__ void dg35_osm(float& m, float& s, float& w, float msg){
  float d = msg - m;
  float e = __expf(-fabsf(d));
  bool gt = d > 0.f;
  s = gt ? s*e + 1.f   : s + e;
  w = gt ? w*e + msg   : w + msg*e;
  m = gt ? msg         : m;
}

__global__ __launch_bounds__(256)
void dg35_gb2(const float* __restrict__ hin, const dg35_u32* __restrict__ packed,
              const int* __restrict__ off, const float* __restrict__ ecomb,
              float* __restrict__ hh){
  int i = blockIdx.x*4 + (threadIdx.x >> 6);
  if (i >= dgN) return;
  int c = (threadIdx.x & 63) * 2;
  int b0 = off[i], b1 = off[i+1];
  float2 self = *reinterpret_cast<const float2*>(hin + (size_t)i*dgC + c);
  float mA0=-3.0e38f, sA0=0.f, wA0=0.f, mA1=-3.0e38f, sA1=0.f, wA1=0.f;
  float mB0=-3.0e38f, sB0=0.f, wB0=0.f, mB1=-3.0e38f, sB1=0.f, wB1=0.f;
  int p = b0;
  for (; p + 1 < b1; p += 2){
    dg35_u32 pkA = packed[p], pkB = packed[p+1];
    int srcA = (int)(pkA & 0x1FFFFu), srcB = (int)(pkB & 0x1FFFFu);
    float2 hA = *reinterpret_cast<const float2*>(hin + (size_t)srcA*dgC + c);
    float2 hB = *reinterpret_cast<const float2*>(hin + (size_t)srcB*dgC + c);
    float2 eA = *reinterpret_cast<const float2*>(ecomb + (size_t)(pkA>>17)*dgC + c);
    float2 eB = *reinterpret_cast<const float2*>(ecomb + (size_t)(pkB>>17)*dgC + c);
    float msgA0 = fmaxf(hA.x + eA.x, 0.f) + 1e-7f;
    float msgA1 = fmaxf(hA.y + eA.y, 0.f) + 1e-7f;
    float msgB0 = fmaxf(hB.x + eB.x, 0.f) + 1e-7f;
    float msgB1 = fmaxf(hB.y + eB.y, 0.f) + 1e-7f;
    dg35_osm(mA0, sA0, wA0, msgA0);
    dg35_osm(mA1, sA1, wA1, msgA1);
    dg35_osm(mB0, sB0, wB0, msgB0);
    dg35_osm(mB1, sB1, wB1, msgB1);
  }
  if (p < b1){
    dg35_u32 pkA = packed[p];
    int srcA = (int)(pkA & 0x1FFFFu);
    float2 hA = *reinterpret_cast<const float2*>(hin + (size_t)srcA*dgC + c);
    float2 eA = *reinterpret_cast<const float2*>(ecomb + (size_t)(pkA>>17)*dgC + c);
    dg35_osm(mA0, sA0, wA0, fmaxf(hA.x + eA.x, 0.f) + 1e-7f);
    dg35_osm(mA1, sA1, wA1, fmaxf(hA.y + eA.y, 0.f) + 1e-7f);
  }
  float mn0 = fmaxf(mA0, mB0);
  float fA0 = __expf(mA0 - mn0), fB0 = __expf(mB0 - mn0);
  float s0 = sA0*fA0 + sB0*fB0, w0 = wA0*fA0 + wB0*fB0;
  float mn1 = fmaxf(mA1, mB1);
  float fA1 = __expf(mA1 - mn1), fB1 = __expf(mB1 - mn1);
  float s1 = sA1*fA1 + sB1*fB1, w1 = wA1*fA1 + wB1*fB1;
  float2 o;
  o.x = self.x + ((b1 > b0) ? (w0 / (s0 + 1e-16f)) : 0.f);
  o.y = self.y + ((b1 > b0) ? (w1 / (s1 + 1e-16f)) : 0.f);
  *reinterpret_cast<float2*>(hh + (size_t)i*dgC + c) = o;
}

// ---- split-bf16 MFMA GEMM, BM=64, A+B both LDS-staged (swizzled), prefetch,
//      fused column stats with 8-way replicated accumulators, XCD chunk swizzle ----
__global__ __launch_bounds__(256)
void dg35_gemmx(const float* __restrict__ A, const short* __restrict__ Whi,
                const short* __restrict__ Wlo, const float* __restrict__ bias,
                const float* __restrict__ ab, const float* __restrict__ res,
                float* __restrict__ Cout, float* __restrict__ st,
                int M, int K, int NC, int trans, int addres){
  __shared__ short Ahi[64*64];   // 8 KB
  __shared__ short Alo[64*64];   // 8 KB
  __shared__ short Bhs[64*64];   // 8 KB  (weight hi, swizzled)
  __shared__ short Bls[64*64];   // 8 KB  (weight lo, swizzled)
  int tid = threadIdx.x;
  // bijective XCD chunk swizzle (m204)
  int nwg = gridDim.x * gridDim.y;
  int lin = blockIdx.y * gridDim.x + blockIdx.x;
  int q8 = nwg >> 3, r8 = nwg & 7;
  int xcd = lin & 7, pos = lin >> 3;
  int wg = (xcd < r8) ? (xcd*(q8+1) + pos) : (r8*(q8+1) + (xcd-r8)*q8 + pos);
  int bn = (wg % gridDim.x) * 64;
  int bm = (wg / gridDim.x) * 64;
  float* stc = st + (size_t)(wg & 7) * 2 * NC;   // replicated stats copy
  int lane = tid & 63;
  int wv = tid >> 6;
  int l15 = lane & 15;
  int l4  = lane >> 4;
  dg35_f4v acc[4] = {};

  int r = tid >> 2;            // A staging row 0..63
  int cq = (tid & 3) * 16;     // 16 f32 per thread
  int grow = bm + r;
  int swbase = cq >> 3;
  // B staging coords: row nB = tid>>2 (0..63), 16 shorts at (tid&3)*16
  int nB = tid >> 2;
  int kqB = (tid & 3) * 16;
  const short* wbase_h = Whi + (size_t)(bn + nB)*K + kqB;
  const short* wbase_l = Wlo + (size_t)(bn + nB)*K + kqB;

  float4 va[4];
  {
    const float* ap = A + (size_t)grow*K + cq;
    if (grow < M){
      #pragma unroll
      for (int q2 = 0; q2 < 4; ++q2) va[q2] = *reinterpret_cast<const float4*>(ap + q2*4);
    } else {
      #pragma unroll
      for (int q2 = 0; q2 < 4; ++q2) va[q2] = make_float4(0.f,0.f,0.f,0.f);
    }
  }

  for (int k0 = 0; k0 < K; k0 += 64){
    // issue B loads for this k0 (latency overlaps the A conversion below)
    uint4 bth[2], btl[2];
    #pragma unroll
    for (int j = 0; j < 2; ++j){
      bth[j] = *reinterpret_cast<const uint4*>(wbase_h + k0 + j*8);
      btl[j] = *reinterpret_cast<const uint4*>(wbase_l + k0 + j*8);
    }
    // convert current A tile -> swizzled split-bf16 LDS
    {
      float xv[16];
      #pragma unroll
      for (int q2 = 0; q2 < 4; ++q2){
        xv[q2*4+0]=va[q2].x; xv[q2*4+1]=va[q2].y;
        xv[q2*4+2]=va[q2].z; xv[q2*4+3]=va[q2].w;
      }
      if (trans){
        #pragma unroll
        for (int q2 = 0; q2 < 16; ++q2){
          int kk = k0 + cq + q2;
          xv[q2] = fmaxf(xv[q2]*ab[kk] + ab[K + kk], 0.f);
        }
      }
      #pragma unroll
      for (int g = 0; g < 2; ++g){
        uint4 wh, wl;
        unsigned* hp = (unsigned*)&wh;
        unsigned* lp = (unsigned*)&wl;
        #pragma unroll
        for (int d = 0; d < 4; ++d){
          float f0 = xv[g*8 + d*2], f1 = xv[g*8 + d*2 + 1];
          dg35_u16 h0 = dg35_f2bf(f0), h1 = dg35_f2bf(f1);
          dg35_u16 l0 = dg35_f2bf(f0 - dg35_bf2f(h0));
          dg35_u16 l1 = dg35_f2bf(f1 - dg35_bf2f(h1));
          hp[d] = (dg35_u32)h0 | ((dg35_u32)h1 << 16);
          lp[d] = (dg35_u32)l0 | ((dg35_u32)l1 << 16);
        }
        int slot = (swbase + g) ^ (r & 7);
        *reinterpret_cast<uint4*>(&Ahi[r*64 + slot*8]) = wh;
        *reinterpret_cast<uint4*>(&Alo[r*64 + slot*8]) = wl;
      }
    }
    // write B to swizzled LDS
    #pragma unroll
    for (int j = 0; j < 2; ++j){
      int slot = ((kqB >> 3) + j) ^ (nB & 7);
      *reinterpret_cast<uint4*>(&Bhs[nB*64 + slot*8]) = bth[j];
      *reinterpret_cast<uint4*>(&Bls[nB*64 + slot*8]) = btl[j];
    }
    __syncthreads();
    // prefetch next A tile (overlaps MFMA below)
    if (k0 + 64 < K && grow < M){
      const float* ap = A + (size_t)grow*K + k0 + 64 + cq;
      #pragma unroll
      for (int q2 = 0; q2 < 4; ++q2) va[q2] = *reinterpret_cast<const float4*>(ap + q2*4);
    }
    // MFMA over 2 K-steps of 32, A and B both from LDS
    #pragma unroll
    for (int ks = 0; ks < 2; ++ks){
      dg35_s8v bh[4], bl[4];
      #pragma unroll
      for (int nf = 0; nf < 4; ++nf){
        int n = nf*16 + l15;
        int slot = (ks*4 + l4) ^ (n & 7);
        bh[nf] = *reinterpret_cast<const dg35_s8v*>(&Bhs[n*64 + slot*8]);
        bl[nf] = *reinterpret_cast<const dg35_s8v*>(&Bls[n*64 + slot*8]);
      }
      int row = wv*16 + l15;
      int slotA = (ks*4 + l4) ^ (row & 7);
      dg35_s8v ah = *reinterpret_cast<const dg35_s8v*>(&Ahi[row*64 + slotA*8]);
      dg35_s8v al = *reinterpret_cast<const dg35_s8v*>(&Alo[row*64 + slotA*8]);
      #pragma unroll
      for (int nf = 0; nf < 4; ++nf){
        acc[nf] = __builtin_amdgcn_mfma_f32_16x16x32_bf16(ah, bh[nf], acc[nf], 0, 0, 0);
        acc[nf] = __builtin_amdgcn_mfma_f32_16x16x32_bf16(al, bh[nf], acc[nf], 0, 0, 0);
        acc[nf] = __builtin_amdgcn_mfma_f32_16x16x32_bf16(ah, bl[nf], acc[nf], 0, 0, 0);
      }
    }
    __syncthreads();
  }
  // epilogue: write + per-lane col partial stats
  float s[4] = {0.f,0.f,0.f,0.f}, q[4] = {0.f,0.f,0.f,0.f};
  #pragma unroll
  for (int e = 0; e < 4; ++e){
    int rr = bm + wv*16 + l4*4 + e;
    if (rr >= M) continue;
    #pragma unroll
    for (int nf = 0; nf < 4; ++nf){
      int cc = bn + nf*16 + l15;
      float v = acc[nf][e] + bias[cc];
      size_t idx = (size_t)rr*NC + cc;
      if (addres) v += res[idx];
      Cout[idx] = v;
      s[nf] += v; q[nf] += v*v;
    }
  }
  #pragma unroll
  for (int nf = 0; nf < 4; ++nf){
    s[nf] += __shfl_xor(s[nf], 16); s[nf] += __shfl_xor(s[nf], 32);
    q[nf] += __shfl_xor(q[nf], 16); q[nf] += __shfl_xor(q[nf], 32);
  }
  __syncthreads();
  float* red = (float*)Ahi;
  if (l4 == 0){
    #pragma unroll
    for (int nf = 0; nf < 4; ++nf){
      red[wv*128 + nf*16 + l15] = s[nf];
      red[wv*128 + 64 + nf*16 + l15] = q[nf];
    }
  }
  __syncthreads();
  if (tid < 64){
    float S = red[tid] + red[128+tid] + red[256+tid] + red[384+tid];
    float Q = red[64+tid] + red[192+tid] + red[320+tid] + red[448+tid];
    atomicAdd(&stc[bn + tid], S);
    atomicAdd(&stc[NC + bn + tid], Q);
  }
}

// -------- VALU GEMM (dual-precision) — tier-B fallback only --------
__global__ __launch_bounds__(256)
void dg35_gemm_h(const void* __restrict__ A, const float* __restrict__ W,
                 const float* __restrict__ bias, const float* __restrict__ ab,
                 const void* __restrict__ res, void* __restrict__ Cout,
                 int M, int K, int NC, int trans, int addres, int af){
  __shared__ float At[32][65];
  __shared__ float Bt[32][64];
  int bm = blockIdx.x * 64;
  int bn = blockIdx.y * 64;
  int tid = threadIdx.x;
  int tx = tid & 15, ty = tid >> 4;
  float acc[4][4];
  #pragma unroll
  for (int i2 = 0; i2 < 4; ++i2)
    #pragma unroll
    for (int j2 = 0; j2 < 4; ++j2) acc[i2][j2] = 0.f;

  for (int k0 = 0; k0 < K; k0 += 32){
    int r = tid >> 3;
    int kq = (tid & 7) * 4;
    #pragma unroll
    for (int half = 0; half < 2; ++half){
      int rr = r + half*32;
      int grow = bm + rr;
      float vv[4] = {0.f, 0.f, 0.f, 0.f};
      if (grow < M){
        if (af){
          float4 v4 = *reinterpret_cast<const float4*>((const float*)A + (size_t)grow*K + k0 + kq);
          vv[0] = v4.x; vv[1] = v4.y; vv[2] = v4.z; vv[3] = v4.w;
        } else {
          ushort4 v4 = *reinterpret_cast<const ushort4*>((const dg35_u16*)A + (size_t)grow*K + k0 + kq);
          vv[0] = dg35_bf2f(v4.x); vv[1] = dg35_bf2f(v4.y);
          vv[2] = dg35_bf2f(v4.z); vv[3] = dg35_bf2f(v4.w);
        }
      }
      #pragma unroll
      for (int i2 = 0; i2 < 4; ++i2){
        float xv = vv[i2];
        if (trans){
          int kk = k0 + kq + i2;
          xv = fmaxf(xv*ab[kk] + ab[K + kk], 0.f);
        }
        At[kq + i2][rr] = xv;
      }
    }
    {
      int kr = tid >> 3;
      int cq = (tid & 7) * 8;
      const float* wp = W + (size_t)(k0 + kr)*NC + bn + cq;
      #pragma unroll
      for (int i2 = 0; i2 < 8; ++i2) Bt[kr][cq + i2] = wp[i2];
    }
    __syncthreads();
    #pragma unroll
    for (int kk = 0; kk < 32; ++kk){
      float a4[4], b4[4];
      #pragma unroll
      for (int i2 = 0; i2 < 4; ++i2) a4[i2] = At[kk][ty*4 + i2];
      #pragma unroll
      for (int j2 = 0; j2 < 4; ++j2) b4[j2] = Bt[kk][tx*4 + j2];
      #pragma unroll
      for (int i2 = 0; i2 < 4; ++i2)
        #pragma unroll
        for (int j2 = 0; j2 < 4; ++j2)
          acc[i2][j2] += a4[i2]*b4[j2];
    }
    __syncthreads();
  }
  #pragma unroll
  for (int i2 = 0; i2 < 4; ++i2){
    int rr = bm + ty*4 + i2;
    if (rr >= M) continue;
    #pragma unroll
    for (int j2 = 0; j2 < 4; ++j2){
      int cc = bn + tx*4 + j2;
      float v = acc[i2][j2] + bias[cc];
      size_t idx = (size_t)rr*NC + cc;
      if (addres) v += dg35_ldx(res, idx, af);
      dg35_stx(Cout, idx, af, v);
    }
  }
}

// -------- GEMM, A f32, W f32, f32 out (virtual-node MLP, M=1024) --------
__global__ __launch_bounds__(256)
void dg35_gemm_v(const float* __restrict__ A, const float* __restrict__ W,
                 const float* __restrict__ bias, const float* __restrict__ ab,
                 float* __restrict__ Cout, int M, int K, int NC, int trans){
  __shared__ float At[32][65];
  __shared__ float Bt[32][64];
  int bm = blockIdx.x * 64;
  int bn = blockIdx.y * 64;
  int tid = threadIdx.x;
  int tx = tid & 15, ty = tid >> 4;
  float acc[4][4];
  #pragma unroll
  for (int i2 = 0; i2 < 4; ++i2)
    #pragma unroll
    for (int j2 = 0; j2 < 4; ++j2) acc[i2][j2] = 0.f;

  for (int k0 = 0; k0 < K; k0 += 32){
    int r = tid >> 3;
    int kq = (tid & 7) * 4;
    #pragma unroll
    for (int half = 0; half < 2; ++half){
      int rr = r + half*32;
      int grow = bm + rr;
      float vv[4] = {0.f, 0.f, 0.f, 0.f};
      if (grow < M){
        float4 v4 = *reinterpret_cast<const float4*>(A + (size_t)grow*K + k0 + kq);
        vv[0] = v4.x; vv[1] = v4.y; vv[2] = v4.z; vv[3] = v4.w;
      }
      #pragma unroll
      for (int i2 = 0; i2 < 4; ++i2){
        float xv = vv[i2];
        if (trans){
          int kk = k0 + kq + i2;
          xv = fmaxf(xv*ab[kk] + ab[K + kk], 0.f);
        }
        At[kq + i2][rr] = xv;
      }
    }
    {
      int kr = tid >> 3;
      int cq = (tid & 7) * 8;
      const float* wp = W + (size_t)(k0 + kr)*NC + bn + cq;
      #pragma unroll
      for (int i2 = 0; i2 < 8; ++i2) Bt[kr][cq + i2] = wp[i2];
    }
    __syncthreads();
    #pragma unroll
    for (int kk = 0; kk < 32; ++kk){
      float a4[4], b4[4];
      #pragma unroll
      for (int i2 = 0; i2 < 4; ++i2) a4[i2] = At[kk][ty*4 + i2];
      #pragma unroll
      for (int j2 = 0; j2 < 4; ++j2) b4[j2] = Bt[kk][tx*4 + j2];
      #pragma unroll
      for (int i2 = 0; i2 < 4; ++i2)
        #pragma unroll
        for (int j2 = 0; j2 < 4; ++j2)
          acc[i2][j2] += a4[i2]*b4[j2];
    }
    __syncthreads();
  }
  #pragma unroll
  for (int i2 = 0; i2 < 4; ++i2){
    int rr = bm + ty*4 + i2;
    if (rr >= M) continue;
    #pragma unroll
    for (int j2 = 0; j2 < 4; ++j2){
      int cc = bn + tx*4 + j2;
      Cout[(size_t)rr*NC + cc] = acc[i2][j2] + bias[cc];
    }
  }
}

// ---------------- BN statistics (small f32 buffers: zv1/zv2) ----------------
__global__ __launch_bounds__(256)
void dg35_cs4(const float* __restrict__ Z, float* __restrict__ st, int n, int ncols){
  int t = threadIdx.x;
  int lpr = ncols >> 2;
  int rl = t / lpr;
  int rpb = 256 / lpr;
  int cq = (t - rl*lpr) * 4;
  float4 s = make_float4(0.f,0.f,0.f,0.f);
  float4 q = make_float4(0.f,0.f,0.f,0.f);
  for (int rr = blockIdx.x*rpb + rl; rr < n; rr += gridDim.x*rpb){
    float4 v = *reinterpret_cast<const float4*>(Z + (size_t)rr*ncols + cq);
    s.x += v.x; s.y += v.y; s.z += v.z; s.w += v.w;
    q.x += v.x*v.x; q.y += v.y*v.y; q.z += v.z*v.z; q.w += v.w*v.w;
  }
  __shared__ float sm[256*8];
  float* my = &sm[t*8];
  my[0]=s.x; my[1]=s.y; my[2]=s.z; my[3]=s.w;
  my[4]=q.x; my[5]=q.y; my[6]=q.z; my[7]=q.w;
  __syncthreads();
  if (rl == 0){
    float a[8];
    #pragma unroll
    for (int d = 0; d < 8; ++d) a[d] = my[d];
    for (int j = 1; j < rpb; ++j){
      const float* o2 = &sm[(t + j*lpr)*8];
      #pragma unroll
      for (int d = 0; d < 8; ++d) a[d] += o2[d];
    }
    #pragma unroll
    for (int d = 0; d < 4; ++d) atomicAdd(&st[cq + d], a[d]);
    #pragma unroll
    for (int d = 0; d < 4; ++d) atomicAdd(&st[ncols + cq + d], a[4 + d]);
  }
}

// tier-B fallback colstats
__global__ void dg35_colstats(const void* __restrict__ Z, float* __restrict__ st,
                              int n, int ncols, int af){
  int tid = threadIdx.x;
  int c = tid & (ncols - 1);
  int rl = tid / ncols;
  int rpb = 256 / ncols;
  float s = 0.f, q = 0.f;
  for (int rr = blockIdx.x*rpb + rl; rr < n; rr += gridDim.x*rpb){
    float v = dg35_ldx(Z, (size_t)rr*ncols + c, af);
    s += v; q += v*v;
  }
  atomicAdd(&st[c], s);
  atomicAdd(&st[ncols + c], q);
}

// finalize BN affine from (possibly replicated) stats
__global__ void dg35_fin(const float* __restrict__ st, const float* __restrict__ g,
                         const float* __restrict__ b, float* __restrict__ ab,
                         float inv_n, int ncols, int ncopy){
  int c = threadIdx.x + blockIdx.x*256;
  if (c >= ncols) return;
  float m = 0.f, q = 0.f;
  for (int k = 0; k < ncopy; ++k){
    m += st[(size_t)k*2*ncols + c];
    q += st[(size_t)k*2*ncols + ncols + c];
  }
  m *= inv_n;
  float var = q*inv_n - m*m;
  float rstd = rsqrtf(var + 1e-5f);
  float a = g[c]*rstd;
  ab[c] = a;
  ab[ncols + c] = b[c] - m*a;
}

// ---------------- elementwise / segment ops ----------------
__global__ void dg35_h24(const float* __restrict__ h, const float* __restrict__ ab,
                         float* __restrict__ h2){
  int i = blockIdx.x*256 + threadIdx.x;
  int c = (i & 31) * 4;
  float4 v = reinterpret_cast<const float4*>(h)[i];
  v.x = fmaxf(v.x*ab[c+0] + ab[dgC+c+0], 0.f);
  v.y = fmaxf(v.y*ab[c+1] + ab[dgC+c+1], 0.f);
  v.z = fmaxf(v.z*ab[c+2] + ab[dgC+c+2], 0.f);
  v.w = fmaxf(v.w*ab[c+3] + ab[dgC+c+3], 0.f);
  reinterpret_cast<float4*>(h2)[i] = v;
}

__global__ void dg35_h2(const void* __restrict__ h, const float* __restrict__ ab,
                        void* __restrict__ h2, int af){
  int i = blockIdx.x*256 + threadIdx.x;
  int c = i & (dgC-1);
  dg35_stx(h2, i, af, fmaxf(dg35_ldx(h, i, af)*ab[c] + ab[dgC + c], 0.f));
}

__global__ __launch_bounds__(128)
void dg35_vt4(const float* __restrict__ h2, const float* __restrict__ vn,
              const int* __restrict__ gs, float* __restrict__ vt){
  int g = blockIdx.x, t = threadIdx.x;
  int rl = t >> 5, cl = t & 31;
  int cq = cl*4;
  int r0 = gs[g], r1 = gs[g+1];
  float4 s = make_float4(0.f,0.f,0.f,0.f);
  for (int rr = r0 + rl; rr < r1; rr += 4){
    float4 v = *reinterpret_cast<const float4*>(h2 + (size_t)rr*dgC + cq);
    s.x += v.x; s.y += v.y; s.z += v.z; s.w += v.w;
  }
  __shared__ float4 sm[128];
  sm[t] = s;
  __syncthreads();
  if (rl == 0){
    float4 a = sm[cl], b = sm[32+cl], c4 = sm[64+cl], d = sm[96+cl];
    float4 vb = *reinterpret_cast<const float4*>(vn + (size_t)g*dgC + cq);
    float4 o;
    o.x = a.x+b.x+c4.x+d.x + vb.x;
    o.y = a.y+b.y+c4.y+d.y + vb.y;
    o.z = a.z+b.z+c4.z+d.z + vb.z;
    o.w = a.w+b.w+c4.w+d.w + vb.w;
    *reinterpret_cast<float4*>(vt + (size_t)g*dgC + cq) = o;
  }
}

__global__ __launch_bounds__(128)
void dg35_vt(const void* __restrict__ h2, const float* __restrict__ vn,
             const int* __restrict__ gs, float* __restrict__ vt, int af){
  int g = blockIdx.x, c = threadIdx.x;
  float s = 0.f;
  int r0 = gs[g], r1 = gs[g+1];
  for (int rr = r0; rr < r1; ++rr) s += dg35_ldx(h2, (size_t)rr*dgC + c, af);
  vt[g*dgC + c] = s + vn[g*dgC + c];
}

__global__ void dg35_vnfin(const float* __restrict__ z2, const float* __restrict__ ab,
                           float* __restrict__ vn){
  int i = blockIdx.x*256 + threadIdx.x;
  int c = i & (dgC-1);
  vn[i] = fmaxf(z2[i]*ab[c] + ab[dgC + c], 0.f);
}

__global__ void dg35_addvn4(float* __restrict__ h2, const float* __restrict__ vn,
                            const int* __restrict__ batch){
  int i = blockIdx.x*256 + threadIdx.x;
  int row = i >> 5;
  int cl = i & 31;
  float4 v = reinterpret_cast<float4*>(h2)[i];
  float4 a = reinterpret_cast<const float4*>(vn)[batch[row]*32 + cl];
  v.x += a.x; v.y += a.y; v.z += a.z; v.w += a.w;
  reinterpret_cast<float4*>(h2)[i] = v;
}

__global__ __launch_bounds__(128)
void dg35_addvn(void* __restrict__ h2, const float* __restrict__ vn,
                const int* __restrict__ batch, int af){
  int i = blockIdx.x, c = threadIdx.x;
  size_t idx = (size_t)i*dgC + c;
  dg35_stx(h2, idx, af, dg35_ldx(h2, idx, af) + vn[batch[i]*dgC + c]);
}

__global__ __launch_bounds__(128)
void dg35_out4(const float* __restrict__ h, const float* __restrict__ ab,
               const int* __restrict__ gs, float* __restrict__ out){
  int g = blockIdx.x, t = threadIdx.x;
  int rl = t >> 5, cl = t & 31;
  int cq = cl*4;
  int r0 = gs[g], r1 = gs[g+1];
  float4 s = make_float4(0.f,0.f,0.f,0.f);
  for (int rr = r0 + rl; rr < r1; rr += 4){
    float4 v = *reinterpret_cast<const float4*>(h + (size_t)rr*dgC + cq);
    s.x += v.x; s.y += v.y; s.z += v.z; s.w += v.w;
  }
  __shared__ float4 sm[128];
  sm[t] = s;
  __syncthreads();
  if (rl == 0){
    float4 a4 = sm[cl], b4 = sm[32+cl], c4 = sm[64+cl], d4 = sm[96+cl];
    float cnt = (float)(r1 - r0);
    float4 o;
    float S;
    S = a4.x+b4.x+c4.x+d4.x; o.x = ab[cq+0]*S + ab[dgC+cq+0]*cnt;
    S = a4.y+b4.y+c4.y+d4.y; o.y = ab[cq+1]*S + ab[dgC+cq+1]*cnt;
    S = a4.z+b4.z+c4.z+d4.z; o.z = ab[cq+2]*S + ab[dgC+cq+2]*cnt;
    S = a4.w+b4.w+c4.w+d4.w; o.w = ab[cq+3]*S + ab[dgC+cq+3]*cnt;
    *reinterpret_cast<float4*>(out + (size_t)g*dgC + cq) = o;
  }
}

// tier-B fallback pieces
__global__ __launch_bounds__(128)
void dg35_gb(const void* __restrict__ hin, const dg35_u32* __restrict__ packed,
             const int* __restrict__ off, const float* __restrict__ bemb,
             void* __restrict__ hh, int af){
  int i = blockIdx.x, c = threadIdx.x;
  int b0 = off[i], b1 = off[i+1];
  float m = -3.0e38f, s = 0.f, w = 0.f;
  for (int p = b0; p < b1; ++p){
    dg35_u32 pk = packed[p];
    int src = (int)(pk & 0x1FFFFu);
    float e = bemb[((pk>>17)&7)*dgC + c] + bemb[(8+((pk>>20)&7))*dgC + c]
            + bemb[(16+((pk>>23)&7))*dgC + c];
    float msg = fmaxf(dg35_ldx(hin, (size_t)src*dgC + c, af) + e, 0.f) + 1e-7f;
    float mn = fmaxf(m, msg);
    float sc = __expf(m - mn), t2 = __expf(msg - mn);
    s = s*sc + t2; w = w*sc + msg*t2; m = mn;
  }
  float agg = (b1 > b0) ? (w / (s + 1e-16f)) : 0.f;
  float self = dg35_ldx(hin, (size_t)i*dgC + c, af);
  dg35_stx(hh, (size_t)i*dgC + c, af, self + agg);
}

__global__ __launch_bounds__(128)
void dg35_out(const void* __restrict__ h, const float* __restrict__ ab,
              const int* __restrict__ gs, float* __restrict__ out, int af){
  int g = blockIdx.x, c = threadIdx.x;
  float a = ab[c], b = ab[dgC + c];
  float s = 0.f;
  int r0 = gs[g], r1 = gs[g+1];
  for (int rr = r0; rr < r1; ++rr) s += dg35_ldx(h, (size_t)rr*dgC + c, af)*a + b;
  out[g*dgC + c] = s;
}

static inline size_t dg35_al(size_t x){ return (x + 255) & ~(size_t)255; }

extern "C" void kernel_launch(void* const* d_in, const int* in_sizes, int n_in,
                              void* d_out, int out_size, void* d_ws, size_t ws_size,
                              hipStream_t stream)
{
  const int*   x     = (const int*)d_in[0];
  const int*   eattr = (const int*)d_in[1];
  const int*   eidx  = (const int*)d_in[2];
  const int*   batch = (const int*)d_in[3];
  const float* aemb  = (const float*)d_in[4];
  const float* bemb  = (const float*)d_in[5];
  const float* vne   = (const float*)d_in[6];
  const float* cW1   = (const float*)d_in[7];
  const float* cb1   = (const float*)d_in[8];
  const float* cg1   = (const float*)d_in[9];
  const float* cbb1  = (const float*)d_in[10];
  const float* cW2   = (const float*)d_in[11];
  const float* cb2   = (const float*)d_in[12];
  const float* ng    = (const float*)d_in[13];
  const float* nb    = (const float*)d_in[14];
  const float* vW1   = (const float*)d_in[15];
  const float* vb1   = (const float*)d_in[16];
  const float* vg1   = (const float*)d_in[17];
  const float* vbb1  = (const float*)d_in[18];
  const float* vW2   = (const float*)d_in[19];
  const float* vb2   = (const float*)d_in[20];
  const float* vg2   = (const float*)d_in[21];
  const float* vbb2  = (const float*)d_in[22];
  float* out = (float*)d_out;

  const int nsb = (dgN + 255) / 256;

  const size_t fixed =
      dg35_al(dgG*dgC*4)*4 +
      dg35_al(8*2*dgC2*4) + dg35_al(2*dgC2*4) +          // st1 (8 copies), ab1
      dg35_al(8*2*dgC*4) +                               // stH (8 copies)
      dg35_al(4*dgC*4) +                                 // stVV (stV1+stV2)
      dg35_al(2*dgC*4)*3 +                               // abh, abv1, abv2
      dg35_al(dgN*4)*2 + dg35_al((dgN+1)*4) +
      dg35_al((dgG+1)*4) +
      dg35_al((size_t)dgE*4) +
      dg35_al(7*256*128*2)*4 +
      dg35_al(512*dgC*4) +
      dg35_al(256*4)*2;
  int af = 0;
  size_t esz = 2;
  {
    size_t bigf = dg35_al((size_t)dgN*dgC*4)*2 + dg35_al((size_t)dgN*dgC2*4);
    if (bigf + fixed <= ws_size){ af = 1; esz = 4; }
  }

  char* base = (char*)d_ws;
  size_t o = 0;
  void* h  = (void*)(base + o); o += dg35_al((size_t)dgN*dgC*esz);
  void* hh = (void*)(base + o); o += dg35_al((size_t)dgN*dgC*esz);
  void* zb = (void*)(base + o); o += dg35_al((size_t)dgN*dgC2*esz);
  float* vn   = (float*)(base + o); o += dg35_al(dgG*dgC*4);
  float* vt   = (float*)(base + o); o += dg35_al(dgG*dgC*4);
  float* zv1  = (float*)(base + o); o += dg35_al(dgG*dgC*4);
  float* zv2  = (float*)(base + o); o += dg35_al(dgG*dgC*4);
  float* st1  = (float*)(base + o); o += dg35_al(8*2*dgC2*4);
  float* ab1  = (float*)(base + o); o += dg35_al(2*dgC2*4);
  float* stH  = (float*)(base + o); o += dg35_al(8*2*dgC*4);
  float* stVV = (float*)(base + o); o += dg35_al(4*dgC*4);
  float* abh  = (float*)(base + o); o += dg35_al(2*dgC*4);
  float* abv1 = (float*)(base + o); o += dg35_al(2*dgC*4);
  float* abv2 = (float*)(base + o); o += dg35_al(2*dgC*4);
  int* deg = (int*)(base + o); o += dg35_al(dgN*4);
  int* cur = (int*)(base + o); o += dg35_al(dgN*4);
  int* off = (int*)(base + o); o += dg35_al((dgN+1)*4);
  int* gs  = (int*)(base + o); o += dg35_al((dgG+1)*4);
  dg35_u32* packed = (dg35_u32*)(base + o); o += dg35_al((size_t)dgE*4);
  short* Wt1h = (short*)(base + o); o += dg35_al(7*256*128*2);
  short* Wt1l = (short*)(base + o); o += dg35_al(7*256*128*2);
  short* Wt2h = (short*)(base + o); o += dg35_al(7*256*128*2);
  short* Wt2l = (short*)(base + o); o += dg35_al(7*256*128*2);
  float* ecomb = (float*)(base + o); o += dg35_al(512*dgC*4);
  int* bsum = (int*)(base + o); o += dg35_al(256*4);
  int* boff = (int*)(base + o); o += dg35_al(256*4);

  if (o > ws_size){
    hipMemsetAsync(d_out, 0x7F, (size_t)out_size*4, stream);
    return;
  }
  float* stV1 = stVV;
  float* stV2 = stVV + 2*dgC;
  void* h2 = zb;
  void* z  = zb;

  // ---- per-call setup ----
  hipMemsetAsync(deg, 0, sizeof(int)*dgN, stream);
  dg35_count  <<<(dgE+255)/256, 256, 0, stream>>>(eidx + dgE, deg, dgE);
  dg35_s1     <<<nsb, 256, 0, stream>>>(deg, bsum, dgN);
  dg35_s2     <<<1, 256, 0, stream>>>(bsum, boff, nsb);
  dg35_s3     <<<nsb, 256, 0, stream>>>(deg, boff, off, cur, dgN);
  dg35_scatter<<<(dgE+255)/256, 256, 0, stream>>>(eidx, eattr, cur, packed, dgE);
  dg35_gstart <<<(dgG+256)/256, 256, 0, stream>>>(batch, gs, dgN, dgG);
  dg35_atom   <<<dgN, dgC, 0, stream>>>(x, aemb, vne, h, af);
  dg35_vninit <<<(dgG*dgC)/256, 256, 0, stream>>>(vne, vn);
  dg35_wconv  <<<1792, 256, 0, stream>>>(cW1, cW2, Wt1h, Wt1l, Wt2h, Wt2l);
  dg35_ecomb  <<<512, 128, 0, stream>>>(bemb, ecomb);

  if (af){
    const int grb = (dgN + 63) / 64;   // 782 row-blocks
    for (int l = 0; l < 7; ++l){
      const float* hin = (const float*)h;
      hipMemsetAsync(st1, 0, 8*2*dgC2*sizeof(float), stream);
      if (l > 0){
        // stH was accumulated by previous layer's gemm2 (8 copies)
        dg35_fin<<<1, 256, 0, stream>>>(stH, ng + (l-1)*dgC, nb + (l-1)*dgC,
                                        abh, 1.f/dgN, dgC, 8);
        hipMemsetAsync(stVV, 0, 4*dgC*sizeof(float), stream);
        dg35_h24<<<(dgN*dgC/4)/256, 256, 0, stream>>>((const float*)h, abh, (float*)h2);
        dg35_vt4<<<dgG, 128, 0, stream>>>((const float*)h2, vn, gs, vt);
        dg35_gemm_v<<<dim3(16,2), 256, 0, stream>>>(vt, vW1 + (l-1)*dgC*dgC,
                                                    vb1 + (l-1)*dgC, (const float*)0,
                                                    zv1, dgG, dgC, dgC, 0);
        dg35_cs4<<<64, 256, 0, stream>>>(zv1, stV1, dgG, dgC);
        dg35_fin<<<1, 256, 0, stream>>>(stV1, vg1 + (l-1)*dgC, vbb1 + (l-1)*dgC,
                                        abv1, 1.f/dgG, dgC, 1);
        dg35_gemm_v<<<dim3(16,2), 256, 0, stream>>>(zv1, vW2 + (l-1)*dgC*dgC,
                                                    vb2 + (l-1)*dgC, abv1,
                                                    zv2, dgG, dgC, dgC, 1);
        dg35_cs4<<<64, 256, 0, stream>>>(zv2, stV2, dgG, dgC);
        dg35_fin<<<1, 256, 0, stream>>>(stV2, vg2 + (l-1)*dgC, vbb2 + (l-1)*dgC,
                                        abv2, 1.f/dgG, dgC, 1);
        dg35_vnfin<<<(dgG*dgC)/256, 256, 0, stream>>>(zv2, abv2, vn);
        dg35_addvn4<<<(dgN*dgC/4)/256, 256, 0, stream>>>((float*)h2, vn, batch);
        hin = (const float*)h2;
      }
      dg35_gb2<<<(dgN+3)/4, 256, 0, stream>>>(hin, packed, off, ecomb, (float*)hh);
      dg35_gemmx<<<dim3(4, grb), 256, 0, stream>>>((const float*)hh,
                                                   Wt1h + l*32768, Wt1l + l*32768,
                                                   cb1 + l*dgC2, (const float*)0,
                                                   (const float*)0, (float*)z, st1,
                                                   dgN, dgC, dgC2, 0, 0);
      dg35_fin<<<1, 256, 0, stream>>>(st1, cg1 + l*dgC2, cbb1 + l*dgC2,
                                      ab1, 1.f/dgN, dgC2, 8);
      hipMemsetAsync(stH, 0, 8*2*dgC*sizeof(float), stream);
      dg35_gemmx<<<dim3(2, grb), 256, 0, stream>>>((const float*)z,
                                                   Wt2h + l*32768, Wt2l + l*32768,
                                                   cb2 + l*dgC, ab1,
                                                   (l==0) ? (const float*)0 : (const float*)h,
                                                   (float*)h, stH,
                                                   dgN, dgC2, dgC, 1, (l==0)?0:1);
    }
    // final BN (stats already in stH from last gemm2, 8 copies) + global_add_pool
    dg35_fin<<<1, 256, 0, stream>>>(stH, ng + 6*dgC, nb + 6*dgC, abh, 1.f/dgN, dgC, 8);
    dg35_out4<<<dgG, 128, 0, stream>>>((const float*)h, abh, gs, out);
  } else {
    // tier-B fallback (bf16 storage, VALU GEMM)
    const int gx = (dgN + 63) / 64;
    for (int l = 0; l < 7; ++l){
      dg35_zero<<<1, 512, 0, stream>>>(st1, stH, stV1, stV2);
      const void* hin = h;
      if (l > 0){
        dg35_colstats<<<128, 256, 0, stream>>>(h, stH, dgN, dgC, af);
        dg35_fin<<<1, 256, 0, stream>>>(stH, ng + (l-1)*dgC, nb + (l-1)*dgC,
                                        abh, 1.f/dgN, dgC, 1);
        dg35_h2<<<(dgN*dgC)/256, 256, 0, stream>>>(h, abh, h2, af);
        dg35_vt<<<dgG, dgC, 0, stream>>>(h2, vn, gs, vt, af);
        dg35_gemm_v<<<dim3(16,2), 256, 0, stream>>>(vt, vW1 + (l-1)*dgC*dgC,
                                                    vb1 + (l-1)*dgC, (const float*)0,
                                                    zv1, dgG, dgC, dgC, 0);
        dg35_cs4<<<64, 256, 0, stream>>>(zv1, stV1, dgG, dgC);
        dg35_fin<<<1, 256, 0, stream>>>(stV1, vg1 + (l-1)*dgC, vbb1 + (l-1)*dgC,
                                        abv1, 1.f/dgG, dgC, 1);
        dg35_gemm_v<<<dim3(16,2), 256, 0, stream>>>(zv1, vW2 + (l-1)*dgC*dgC,
                                                    vb2 + (l-1)*dgC, abv1,
                                                    zv2, dgG, dgC, dgC, 1);
        dg35_cs4<<<64, 256, 0, stream>>>(zv2, stV2, dgG, dgC);
        dg35_fin<<<1, 256, 0, stream>>>(stV2, vg2 + (l-1)*dgC, vbb2 + (l-1)*dgC,
                                        abv2, 1.f/dgG, dgC, 1);
        dg35_vnfin<<<(dgG*dgC)/256, 256, 0, stream>>>(zv2, abv2, vn);
        dg35_addvn<<<dgN, dgC, 0, stream>>>(h2, vn, batch, af);
        hin = h2;
      }
      dg35_gb<<<dgN, dgC, 0, stream>>>(hin, packed, off, bemb, hh, af);
      dg35_gemm_h<<<dim3(gx,4), 256, 0, stream>>>(hh, cW1 + l*dgC*dgC2,
                                                  cb1 + l*dgC2, (const float*)0,
                                                  (const void*)0, z,
                                                  dgN, dgC, dgC2, 0, 0, af);
      dg35_colstats<<<128, 256, 0, stream>>>(z, st1, dgN, dgC2, af);
      dg35_fin<<<1, 256, 0, stream>>>(st1, cg1 + l*dgC2, cbb1 + l*dgC2,
                                      ab1, 1.f/dgN, dgC2, 1);
      dg35_gemm_h<<<dim3(gx,2), 256, 0, stream>>>(z, cW2 + l*dgC2*dgC,
                                                  cb2 + l*dgC, ab1, h, h,
                                                  dgN, dgC2, dgC, 1, (l==0)?0:1, af);
    }
    hipMemsetAsync(stH, 0, sizeof(float)*2*dgC, stream);
    dg35_colstats<<<128, 256, 0, stream>>>(h, stH, dgN, dgC, af);
    dg35_fin<<<1, 256, 0, stream>>>(stH, ng + 6*dgC, nb + 6*dgC, abh, 1.f/dgN, dgC, 1);
    dg35_out<<<dgG, dgC, 0, stream>>>(h, abh, gs, out, af);
  }
}